// Round 14
// baseline (1246.255 us; speedup 1.0000x reference)
//
#include <hip/hip_runtime.h>
#include <hip/hip_bf16.h>
#include <math.h>

namespace {

constexpr int B_ = 256, H_ = 64, L0_ = 640, L1_ = 320, L2_ = 160;
constexpr int N2_ = 32, NL_ = 8, NM_ = 3;

typedef __attribute__((ext_vector_type(8))) short bf16x8;
typedef __attribute__((ext_vector_type(4))) float f32x4;

__device__ __forceinline__ unsigned short f2bf(float x) {
  __hip_bfloat16 h = __float2bfloat16(x);
  unsigned short u;
  __builtin_memcpy(&u, &h, 2);
  return u;
}
__device__ __forceinline__ float bf2f(unsigned short h) {
  return __uint_as_float(((unsigned int)h) << 16);
}
__device__ __forceinline__ float gelu_f(float x) {
  const float t = 0.7978845608028654f * (x + 0.044715f * x * x * x);
  return x / (1.f + __expf(-2.f * t));
}
__device__ __forceinline__ void split8(const float* v, bf16x8& hi, bf16x8& lo) {
#pragma unroll
  for (int i = 0; i < 8; ++i) {
    const unsigned short hh = f2bf(v[i]);
    hi[i] = (short)hh;
    lo[i] = (short)f2bf(v[i] - bf2f(hh));
  }
}

// ---------------------------------------------------------------------------
// K + Toeplitz-fragment precompute (spill-free). One block per (m, layer, h).
// ---------------------------------------------------------------------------
__global__ __launch_bounds__(256) void k_compute_K_tt(
    const float* __restrict__ log_dt, const float* __restrict__ C,
    const float* __restrict__ logA, const float* __restrict__ Aim,
    unsigned short* __restrict__ TtG) {
  const int bid = blockIdx.x;
  const int m = bid / (NL_ * H_);
  const int rest = bid % (NL_ * H_);
  const int li = rest / H_;
  const int h = rest % H_;
  const int ph = (m * NL_ + li) * H_ + h;
  __shared__ float qkr[7][N2_], qki[7][N2_];
  __shared__ float sCr[N2_], sCi[N2_];
  __shared__ float Ksh[L0_];
  const int tid = threadIdx.x;
  if (tid < N2_) {
    const int n = tid;
    const float dt = expf(log_dt[ph]);
    const float Are = -expf(logA[(size_t)ph * N2_ + n]);
    const float Ai = Aim[(size_t)ph * N2_ + n];
    const float ar = dt * Are, ai = dt * Ai;
    const float er = expf(ar);
    float sn, cs;
    sincosf(ai, &sn, &cs);
    const float mr = er * cs - 1.f;
    const float mi = er * sn;
    const float den = Are * Are + Ai * Ai;
    const float qr_ = (mr * Are + mi * Ai) / den;
    const float qi_ = (mi * Are - mr * Ai) / den;
    const float C0 = C[((size_t)ph * N2_ + n) * 2 + 0];
    const float C1 = C[((size_t)ph * N2_ + n) * 2 + 1];
    sCr[n] = C0 * qr_ - C1 * qi_;
    sCi[n] = C0 * qi_ + C1 * qr_;
    float qr = er * cs, qi = er * sn;
#pragma unroll
    for (int k = 0; k < 7; ++k) {
      qkr[k][n] = qr;
      qki[k][n] = qi;
      const float nr = qr * qr - qi * qi;
      qi = 2.f * qr * qi;
      qr = nr;
    }
  }
  __syncthreads();
  const int Lm = (m == 0) ? L2_ : (m == 1) ? L1_ : L0_;
  const int NT = Lm / 16;

  const int l0 = tid >> 2;
  const int g = tid & 3;
  float pr[8], pi[8];
#pragma unroll
  for (int j = 0; j < 8; ++j) { pr[j] = 1.f; pi[j] = 0.f; }
#pragma unroll
  for (int k = 0; k < 6; ++k) {
    if ((l0 >> k) & 1) {
#pragma unroll
      for (int j = 0; j < 8; ++j) {
        const int n = g * 8 + j;
        const float qr = qkr[k][n], qi = qki[k][n];
        const float nr = pr[j] * qr - pi[j] * qi;
        pi[j] = pr[j] * qi + pi[j] * qr;
        pr[j] = nr;
      }
    }
  }
  for (int l = l0; l < Lm; l += 64) {
    float acc = 0.f;
#pragma unroll
    for (int j = 0; j < 8; ++j) {
      const int n = g * 8 + j;
      acc += sCr[n] * pr[j] - sCi[n] * pi[j];
    }
    acc += __shfl_xor(acc, 1);
    acc += __shfl_xor(acc, 2);
    if (g == 0) Ksh[l] = 2.f * acc;
    if (l + 64 < Lm) {
#pragma unroll
      for (int j = 0; j < 8; ++j) {
        const int n = g * 8 + j;
        const float qr = qkr[6][n], qi = qki[6][n];
        const float nr = pr[j] * qr - pi[j] * qi;
        pi[j] = pr[j] * qi + pi[j] * qr;
        pr[j] = nr;
      }
    }
  }
  __syncthreads();
  const size_t base_tiles = ((m == 0) ? 0 : (m == 1) ? (size_t)64 * NL_ * 10
                                                     : (size_t)64 * NL_ * 30) +
                            (size_t)li * 64 * NT + (size_t)h * NT;
  unsigned short* Tg = TtG + base_tiles * 512;
  for (int w = tid; w < NT * 256; w += 256) {
    const int nd = w >> 8;
    const int rem = w & 255;
    const int lane = rem >> 2;
    const int pp = rem & 3;
    const int base = nd * 16 + (lane & 15) - ((lane >> 4) << 3) - 2 * pp;
    const float f0 = (base >= 0) ? Ksh[base] : 0.f;
    const float f1 = (base - 1 >= 0) ? Ksh[base - 1] : 0.f;
    *(unsigned int*)&Tg[nd * 512 + lane * 8 + 2 * pp] =
        (unsigned int)f2bf(f0) | ((unsigned int)f2bf(f1) << 16);
  }
}

// ---------------------------------------------------------------------------
// Pack f32 weights -> bf16 hi/lo (identity indexing).
// ---------------------------------------------------------------------------
__global__ void k_pack_w(const float* __restrict__ W, unsigned short* __restrict__ hi,
                         unsigned short* __restrict__ lo, int n) {
  const int p = blockIdx.x * 256 + threadIdx.x;
  if (p < n) {
    const float w = W[p];
    const unsigned short h = f2bf(w);
    hi[p] = h;
    lo[p] = f2bf(w - bf2f(h));
  }
}

// Gather-pack conv weights into P[k][o*64+i] hi/lo. src = o*so + i*si + k.
__global__ void k_pack_gather(const float* __restrict__ W, unsigned short* __restrict__ hi,
                              unsigned short* __restrict__ lo, int n, int so, int si) {
  const int idx = blockIdx.x * 256 + threadIdx.x;
  if (idx < n) {
    const int k = idx >> 12;
    const int rem = idx & 4095;
    const int o = rem >> 6;
    const int i = rem & 63;
    const float w = W[o * so + i * si + k];
    const unsigned short h = f2bf(w);
    hi[idx] = h;
    lo[idx] = f2bf(w - bf2f(h));
  }
}

// ---------------------------------------------------------------------------
// MFMA 1x1 encoder v2: LDS-staged. Block = (b, 32-l tile). OUT-OF-PLACE only.
// ---------------------------------------------------------------------------
__global__ __launch_bounds__(256) void k_enc_mfma(
    const unsigned short* __restrict__ Whi, const unsigned short* __restrict__ Wlo,
    const float* __restrict__ bvec, const float* __restrict__ in_,
    float* __restrict__ out, int Lcur) {
  constexpr int KS = 72;
  __shared__ __align__(16) unsigned short Xhi[32 * KS];
  __shared__ __align__(16) unsigned short Xlo[32 * KS];
  const int tid = threadIdx.x;
  const int w = tid >> 6, lane = tid & 63, c15 = lane & 15, g4 = lane >> 4;
  const int tilesPerB = Lcur >> 5;
  const int b = blockIdx.x / tilesPerB;
  const int l0 = ((blockIdx.x % tilesPerB) << 5);
  const size_t bbase = (size_t)b * H_ * Lcur;

#pragma unroll
  for (int e = 0; e < 8; ++e) {
    const int idx = e * 256 + tid;
    const int ch = idx >> 5;
    const int c = idx & 31;
    const float v = in_[bbase + (size_t)ch * Lcur + l0 + c];
    const unsigned short hh = f2bf(v);
    Xhi[c * KS + ch] = hh;
    Xlo[c * KS + ch] = f2bf(v - bf2f(hh));
  }
  bf16x8 wh[2], wl[2];
#pragma unroll
  for (int q = 0; q < 2; ++q) {
    const int ra = (16 * w + c15) * 64 + q * 32 + 8 * g4;
    wh[q] = *(const bf16x8*)(Whi + ra);
    wl[q] = *(const bf16x8*)(Wlo + ra);
  }
  __syncthreads();

  f32x4 acc[2] = {{0.f, 0.f, 0.f, 0.f}, {0.f, 0.f, 0.f, 0.f}};
#pragma unroll
  for (int lt = 0; lt < 2; ++lt) {
    const int lc = lt * 16 + c15;
#pragma unroll
    for (int q = 0; q < 2; ++q) {
      const int crow = q * 32 + 8 * g4;
      const bf16x8 xh = *(const bf16x8*)&Xhi[lc * KS + crow];
      const bf16x8 xl = *(const bf16x8*)&Xlo[lc * KS + crow];
      acc[lt] = __builtin_amdgcn_mfma_f32_16x16x32_bf16(wh[q], xh, acc[lt], 0, 0, 0);
      acc[lt] = __builtin_amdgcn_mfma_f32_16x16x32_bf16(wh[q], xl, acc[lt], 0, 0, 0);
      acc[lt] = __builtin_amdgcn_mfma_f32_16x16x32_bf16(wl[q], xh, acc[lt], 0, 0, 0);
    }
  }
#pragma unroll
  for (int lt = 0; lt < 2; ++lt) {
#pragma unroll
    for (int r = 0; r < 4; ++r) {
      const int ca = 16 * w + 4 * g4 + r;
      out[bbase + (size_t)ca * Lcur + l0 + lt * 16 + c15] = acc[lt][r] + bvec[ca];
    }
  }
}

// ---------------------------------------------------------------------------
// MFMA strided down-conv v2 (k=KW, s=2, pad=PAD), LDS-staged.
// ---------------------------------------------------------------------------
template <int KW, int PAD>
__global__ __launch_bounds__(256) void k_down_mfma(
    const unsigned short* __restrict__ Phi, const unsigned short* __restrict__ Plo,
    const float* __restrict__ bias, const float* __restrict__ in_,
    float* __restrict__ out, int Lin, int Lout) {
  constexpr int WCOLS = 62 + KW;
  constexpr int KS = 72;
  __shared__ __align__(16) unsigned short Xhi[WCOLS * KS];
  __shared__ __align__(16) unsigned short Xlo[WCOLS * KS];
  const int tid = threadIdx.x;
  const int w = tid >> 6, lane = tid & 63, c15 = lane & 15, g4 = lane >> 4;
  const int tilesPerB = Lout >> 5;
  const int b = blockIdx.x / tilesPerB;
  const int t0 = ((blockIdx.x % tilesPerB) << 5);
  const int c0 = 2 * t0 - PAD;
  const size_t ibase = (size_t)b * H_ * Lin;

  for (int idx = tid; idx < 64 * WCOLS; idx += 256) {
    const int ch = idx / WCOLS;
    const int c = idx % WCOLS;
    const int gc = c0 + c;
    const float v = (gc >= 0 && gc < Lin) ? in_[ibase + (size_t)ch * Lin + gc] : 0.f;
    const unsigned short hh = f2bf(v);
    Xhi[c * KS + ch] = hh;
    Xlo[c * KS + ch] = f2bf(v - bf2f(hh));
  }
  bf16x8 wh[KW][2], wl[KW][2];
#pragma unroll
  for (int k = 0; k < KW; ++k)
#pragma unroll
    for (int q = 0; q < 2; ++q) {
      const int ra = (k << 12) + (16 * w + c15) * 64 + q * 32 + 8 * g4;
      wh[k][q] = *(const bf16x8*)(Phi + ra);
      wl[k][q] = *(const bf16x8*)(Plo + ra);
    }
  __syncthreads();

  f32x4 acc[2] = {{0.f, 0.f, 0.f, 0.f}, {0.f, 0.f, 0.f, 0.f}};
#pragma unroll
  for (int lt = 0; lt < 2; ++lt) {
#pragma unroll
    for (int q = 0; q < 2; ++q) {
      const int crow = q * 32 + 8 * g4;
#pragma unroll
      for (int k = 0; k < KW; ++k) {
        const int lc = 2 * (lt * 16 + c15) + k;
        const bf16x8 xh = *(const bf16x8*)&Xhi[lc * KS + crow];
        const bf16x8 xl = *(const bf16x8*)&Xlo[lc * KS + crow];
        acc[lt] = __builtin_amdgcn_mfma_f32_16x16x32_bf16(wh[k][q], xh, acc[lt], 0, 0, 0);
        acc[lt] = __builtin_amdgcn_mfma_f32_16x16x32_bf16(wh[k][q], xl, acc[lt], 0, 0, 0);
        acc[lt] = __builtin_amdgcn_mfma_f32_16x16x32_bf16(wl[k][q], xh, acc[lt], 0, 0, 0);
      }
    }
  }
  const size_t obase = (size_t)b * H_ * Lout;
#pragma unroll
  for (int lt = 0; lt < 2; ++lt) {
#pragma unroll
    for (int r = 0; r < 4; ++r) {
      const int ca = 16 * w + 4 * g4 + r;
      out[obase + (size_t)ca * Lout + t0 + lt * 16 + c15] = acc[lt][r] + bias[ca];
    }
  }
}

// ---------------------------------------------------------------------------
// MFMA ConvTranspose1d v2 (k=3 s=2 p=1 op=1), LDS-staged; optional fused
// second input. NOTE: out must NOT alias in_/in2/skip.
// ---------------------------------------------------------------------------
__global__ __launch_bounds__(256) void k_convT_mfma(
    const unsigned short* __restrict__ Phi, const unsigned short* __restrict__ Plo,
    const float* __restrict__ bias, const float* __restrict__ skip,
    const float* __restrict__ in_, const float* __restrict__ in2,
    float* __restrict__ out, int Lin, int hasBias) {
  constexpr int WCOLS = 33;
  constexpr int KS = 72;
  __shared__ __align__(16) unsigned short Xhi[WCOLS * KS];
  __shared__ __align__(16) unsigned short Xlo[WCOLS * KS];
  const int tid = threadIdx.x;
  const int w = tid >> 6, lane = tid & 63, c15 = lane & 15, g4 = lane >> 4;
  const int tilesPerB = Lin >> 5;
  const int b = blockIdx.x / tilesPerB;
  const int j0 = ((blockIdx.x % tilesPerB) << 5);
  const int Lout = 2 * Lin;
  const size_t ibase = (size_t)b * H_ * Lin;

  for (int idx = tid; idx < 64 * WCOLS; idx += 256) {
    const int ch = idx / WCOLS;
    const int c = idx % WCOLS;
    const int gc = j0 + c;
    float v = 0.f;
    if (gc < Lin) {
      const size_t p = ibase + (size_t)ch * Lin + gc;
      v = in_[p];
      if (in2) v += in2[p];
    }
    const unsigned short hh = f2bf(v);
    Xhi[c * KS + ch] = hh;
    Xlo[c * KS + ch] = f2bf(v - bf2f(hh));
  }
  bf16x8 wh[3][2], wl[3][2];
#pragma unroll
  for (int k = 0; k < 3; ++k)
#pragma unroll
    for (int q = 0; q < 2; ++q) {
      const int ra = (k << 12) + (16 * w + c15) * 64 + q * 32 + 8 * g4;
      wh[k][q] = *(const bf16x8*)(Phi + ra);
      wl[k][q] = *(const bf16x8*)(Plo + ra);
    }
  __syncthreads();

  f32x4 aE[2] = {{0.f, 0.f, 0.f, 0.f}, {0.f, 0.f, 0.f, 0.f}};
  f32x4 aO[2] = {{0.f, 0.f, 0.f, 0.f}, {0.f, 0.f, 0.f, 0.f}};
#pragma unroll
  for (int lt = 0; lt < 2; ++lt) {
    const int lc = lt * 16 + c15;
#pragma unroll
    for (int q = 0; q < 2; ++q) {
      const int crow = q * 32 + 8 * g4;
      const bf16x8 xjh = *(const bf16x8*)&Xhi[lc * KS + crow];
      const bf16x8 xjl = *(const bf16x8*)&Xlo[lc * KS + crow];
      const bf16x8 xnh = *(const bf16x8*)&Xhi[(lc + 1) * KS + crow];
      const bf16x8 xnl = *(const bf16x8*)&Xlo[(lc + 1) * KS + crow];
      aE[lt] = __builtin_amdgcn_mfma_f32_16x16x32_bf16(wh[1][q], xjh, aE[lt], 0, 0, 0);
      aE[lt] = __builtin_amdgcn_mfma_f32_16x16x32_bf16(wh[1][q], xjl, aE[lt], 0, 0, 0);
      aE[lt] = __builtin_amdgcn_mfma_f32_16x16x32_bf16(wl[1][q], xjh, aE[lt], 0, 0, 0);
      aO[lt] = __builtin_amdgcn_mfma_f32_16x16x32_bf16(wh[2][q], xjh, aO[lt], 0, 0, 0);
      aO[lt] = __builtin_amdgcn_mfma_f32_16x16x32_bf16(wh[2][q], xjl, aO[lt], 0, 0, 0);
      aO[lt] = __builtin_amdgcn_mfma_f32_16x16x32_bf16(wl[2][q], xjh, aO[lt], 0, 0, 0);
      aO[lt] = __builtin_amdgcn_mfma_f32_16x16x32_bf16(wh[0][q], xnh, aO[lt], 0, 0, 0);
      aO[lt] = __builtin_amdgcn_mfma_f32_16x16x32_bf16(wh[0][q], xnl, aO[lt], 0, 0, 0);
      aO[lt] = __builtin_amdgcn_mfma_f32_16x16x32_bf16(wl[0][q], xnh, aO[lt], 0, 0, 0);
    }
  }
  const size_t obase = (size_t)b * H_ * Lout;
#pragma unroll
  for (int lt = 0; lt < 2; ++lt) {
#pragma unroll
    for (int r = 0; r < 4; ++r) {
      const int ca = 16 * w + 4 * g4 + r;
      const float bb = hasBias ? bias[ca] : 0.f;
      const size_t pos = obase + (size_t)ca * Lout + 2 * (j0 + lt * 16 + c15);
      out[pos] = aE[lt][r] + bb + skip[pos];
      out[pos + 1] = aO[lt][r] + bb + skip[pos + 1];
    }
  }
}

// ---------------------------------------------------------------------------
// MFMA causal conv + D-skip + gelu, v4: diagonal-major K-loop.
// Wave owns strided tile set {wv, wv+4, ...} (balanced). Loop over Toeplitz
// diagonal nd: B-frag Th[nd] loaded ONCE per wave (prefetched 1 ahead), used
// for every owned tile t >= nd with (t-nd) even via A-frag at j0=(t-nd)*16.
// Same MFMA set as v3 (summation order within acc reversed: f32-dust only).
// ---------------------------------------------------------------------------
template <int L>
__global__ __launch_bounds__(256) void k_conv_gelu_mfma(
    const float* __restrict__ u, const unsigned short* __restrict__ Tt,
    const float* __restrict__ D, float* __restrict__ y) {
  constexpr int NT = L / 16;
  constexpr int MAXT = (NT + 3) / 4;
  constexpr int LP = L + 8;
  __shared__ unsigned short uhi[16 * LP];

  const int h = blockIdx.x & 63;
  const int b0 = (blockIdx.x >> 6) * 16;
  const int tid = threadIdx.x;

  // stage u (bf16): row = tid>>4 (16 rows), 16 threads per row, float4 loads
  {
    const int row = tid >> 4;
    const int ct = tid & 15;
    const float4* src = (const float4*)(u + ((size_t)(b0 + row) * H_ + h) * L);
#pragma unroll
    for (int c4 = ct; c4 < L / 4; c4 += 16) {
      const float4 v = src[c4];
      const unsigned int p0 = (unsigned int)f2bf(v.x) | ((unsigned int)f2bf(v.y) << 16);
      const unsigned int p1 = (unsigned int)f2bf(v.z) | ((unsigned int)f2bf(v.w) << 16);
      unsigned int* dst = (unsigned int*)&uhi[row * LP + 4 * c4];
      dst[0] = p0;
      dst[1] = p1;
    }
  }
  __syncthreads();

  const int wv = tid >> 6;
  const int lane = tid & 63;
  const float Dh = D[h];
  const int lquad = lane & 15;
  const int lhi = lane >> 4;
  const unsigned short* Th = Tt + (size_t)h * NT * 512 + lane * 8;
  const int myNT = (NT - wv + 3) >> 2;  // tiles wv, wv+4, ...

  f32x4 acc[MAXT];
#pragma unroll
  for (int i = 0; i < MAXT; ++i) acc[i] = (f32x4){0.f, 0.f, 0.f, 0.f};

  bf16x8 bf = *(const bf16x8*)(Th);
  for (int nd = 0; nd < NT; ++nd) {
    bf16x8 nbf = bf;
    if (nd + 1 < NT) nbf = *(const bf16x8*)(Th + (size_t)(nd + 1) * 512);
#pragma unroll
    for (int i = 0; i < MAXT; ++i) {
      const int t = wv + 4 * i;
      if (i < myNT && t >= nd && (((t - nd) & 1) == 0)) {
        const int colbase = (t - nd) * 16 + (lhi << 3);
        const bf16x8 ah = *(const bf16x8*)&uhi[lquad * LP + colbase];
        acc[i] = __builtin_amdgcn_mfma_f32_16x16x32_bf16(ah, bf, acc[i], 0, 0, 0);
      }
    }
    bf = nbf;
  }

#pragma unroll
  for (int i = 0; i < MAXT; ++i) {
    if (i >= myNT) break;
    const int t = wv + 4 * i;
    const int l = t * 16 + lquad;
#pragma unroll
    for (int r = 0; r < 4; ++r) {
      const int row = (lhi << 2) + r;
      const float uv = bf2f(uhi[row * LP + l]);
      const float val = acc[i][r] + uv * Dh;
      y[((size_t)(b0 + row) * H_ + h) * L + l] = gelu_f(val);
    }
  }
}

// ---------------------------------------------------------------------------
// MFMA out-proj (64->128) + GLU + residual + LayerNorm, v2 (unchanged).
// ---------------------------------------------------------------------------
template <int LT>
__global__ __launch_bounds__(256) void k_glu_ln_mfma2(
    const unsigned short* __restrict__ Whi, const unsigned short* __restrict__ Wlo,
    const float* __restrict__ ob, const float* __restrict__ lng,
    const float* __restrict__ lnb, const float* __restrict__ ybuf,
    const float* __restrict__ xbuf, float* __restrict__ obuf, int Lcur) {
  constexpr int LTILE = LT * 16;
  constexpr int KS = 72;
  __shared__ __align__(16) unsigned short Yhi[LTILE * KS];
  __shared__ __align__(16) unsigned short Ylo[LTILE * KS];
  __shared__ float red[4][LTILE][2];
  const int tid = threadIdx.x;
  const int w = tid >> 6, lane = tid & 63, c15 = lane & 15, g4 = lane >> 4;
  const int tilesPerB = Lcur / LTILE;
  const int b = blockIdx.x / tilesPerB;
  const int l0 = (blockIdx.x % tilesPerB) * LTILE;
  const size_t bbase = (size_t)b * H_ * Lcur;

  constexpr int NE = (64 * LTILE) / 256;
#pragma unroll
  for (int e = 0; e < NE; ++e) {
    const int idx = e * 256 + tid;
    const int k = idx / LTILE;
    const int l = idx % LTILE;
    const float v = ybuf[bbase + (size_t)k * Lcur + l0 + l];
    const unsigned short hh = f2bf(v);
    Yhi[l * KS + k] = hh;
    Ylo[l * KS + k] = f2bf(v - bf2f(hh));
  }

  bf16x8 wah[2], wal[2], wgh[2], wgl[2];
#pragma unroll
  for (int q = 0; q < 2; ++q) {
    const int crow = q * 32 + 8 * g4;
    const int ra = (16 * w + c15) * 64 + crow;
    const int rg = ((64 + 16 * w) + c15) * 64 + crow;
    wah[q] = *(const bf16x8*)(Whi + ra);
    wal[q] = *(const bf16x8*)(Wlo + ra);
    wgh[q] = *(const bf16x8*)(Whi + rg);
    wgl[q] = *(const bf16x8*)(Wlo + rg);
  }
  __syncthreads();

  float wv[LT][4];
#pragma unroll
  for (int lt = 0; lt < LT; ++lt) {
    const int ll = lt * 16 + c15;
    f32x4 accA = {0.f, 0.f, 0.f, 0.f}, accG = {0.f, 0.f, 0.f, 0.f};
#pragma unroll
    for (int q = 0; q < 2; ++q) {
      const int crow = q * 32 + 8 * g4;
      const bf16x8 yh = *(const bf16x8*)&Yhi[ll * KS + crow];
      const bf16x8 yl = *(const bf16x8*)&Ylo[ll * KS + crow];
      accA = __builtin_amdgcn_mfma_f32_16x16x32_bf16(wah[q], yh, accA, 0, 0, 0);
      accA = __builtin_amdgcn_mfma_f32_16x16x32_bf16(wah[q], yl, accA, 0, 0, 0);
      accA = __builtin_amdgcn_mfma_f32_16x16x32_bf16(wal[q], yh, accA, 0, 0, 0);
      accG = __builtin_amdgcn_mfma_f32_16x16x32_bf16(wgh[q], yh, accG, 0, 0, 0);
      accG = __builtin_amdgcn_mfma_f32_16x16x32_bf16(wgh[q], yl, accG, 0, 0, 0);
      accG = __builtin_amdgcn_mfma_f32_16x16x32_bf16(wgl[q], yh, accG, 0, 0, 0);
    }
    float s1 = 0.f, s2 = 0.f;
#pragma unroll
    for (int r = 0; r < 4; ++r) {
      const int ca = 16 * w + 4 * g4 + r;
      const float a = accA[r] + ob[ca];
      const float g = accG[r] + ob[H_ + ca];
      const float z = a / (1.f + expf(-g));
      const float xv = xbuf[bbase + (size_t)ca * Lcur + l0 + ll];
      wv[lt][r] = z + xv;
      s1 += wv[lt][r];
      s2 += wv[lt][r] * wv[lt][r];
    }
    s1 += __shfl_xor(s1, 16);
    s2 += __shfl_xor(s2, 16);
    s1 += __shfl_xor(s1, 32);
    s2 += __shfl_xor(s2, 32);
    if (g4 == 0) {
      red[w][ll][0] = s1;
      red[w][ll][1] = s2;
    }
  }
  __syncthreads();
#pragma unroll
  for (int lt = 0; lt < LT; ++lt) {
    const int ll = lt * 16 + c15;
    float t1 = 0.f, t2 = 0.f;
#pragma unroll
    for (int q = 0; q < 4; ++q) {
      t1 += red[q][ll][0];
      t2 += red[q][ll][1];
    }
    const float mean = t1 * (1.f / 64.f);
    const float var = t2 * (1.f / 64.f) - mean * mean;
    const float rstd = rsqrtf(var + 1e-5f);
#pragma unroll
    for (int r = 0; r < 4; ++r) {
      const int ca = 16 * w + 4 * g4 + r;
      obuf[bbase + (size_t)ca * Lcur + l0 + ll] =
          (wv[lt][r] - mean) * rstd * lng[ca] + lnb[ca];
    }
  }
}

}  // namespace

// ---------------------------------------------------------------------------
extern "C" void kernel_launch(void* const* d_in, const int* in_sizes, int n_in,
                              void* d_out, int out_size, void* d_ws, size_t ws_size,
                              hipStream_t stream) {
  const float* x       = (const float*)d_in[0];
  const float* enc_W   = (const float*)d_in[1];
  const float* enc_b   = (const float*)d_in[2];
  const float* ln_g    = (const float*)d_in[3];
  const float* ln_b    = (const float*)d_in[4];
  const float* s4_D    = (const float*)d_in[5];
  const float* s4_ldt  = (const float*)d_in[6];
  const float* s4_C    = (const float*)d_in[7];
  const float* s4_logA = (const float*)d_in[8];
  const float* s4_Aim  = (const float*)d_in[9];
  const float* out_W   = (const float*)d_in[10];
  const float* out_b   = (const float*)d_in[11];
  const float* cd1_W   = (const float*)d_in[12];
  const float* cd1_b   = (const float*)d_in[13];
  const float* cd2_W   = (const float*)d_in[14];
  const float* cd2_b   = (const float*)d_in[15];
  const float* up_W    = (const float*)d_in[16];
  const float* up_b    = (const float*)d_in[17];
  const float* up1_W   = (const float*)d_in[18];
  float* outp = (float*)d_out;

  // ---- workspace arena (~127.2 MB, lifetime-overlapped) ----
  unsigned short* TtG = (unsigned short*)d_ws;
  const size_t ttg_shorts = (size_t)64 * NL_ * 70 * 512;      // 18.35M
  const size_t nWsz = (size_t)NM_ * NL_ * 2 * H_ * H_;        // 1.57M
  unsigned short* oWhi = TtG + ttg_shorts;
  unsigned short* oWlo = oWhi + nWsz;
  unsigned short* eWhi = oWlo + nWsz;
  unsigned short* eWlo = eWhi + 3 * 4096;
  unsigned short* c1hi = eWlo + 3 * 4096;
  unsigned short* c1lo = c1hi + 3 * 4096;
  unsigned short* c2hi = c1lo + 3 * 4096;
  unsigned short* c2lo = c2hi + 2 * 4096;
  unsigned short* uphi = c2lo + 2 * 4096;
  unsigned short* uplo = uphi + 3 * 4096;
  unsigned short* u1hi = uplo + 3 * 4096;
  unsigned short* u1lo = u1hi + 3 * 4096;
  float* slotA = (float*)(u1lo + 3 * 4096);            // B*H*L0 floats
  float* slotB = slotA + (size_t)B_ * H_ * L0_;        // B*H*L0 floats

  // lifetime map (stream-serial, encoders all OUT-OF-PLACE):
  float* enc1  = slotA;                                // B*H*L1
  float* enc2  = slotA + (size_t)B_ * H_ * L1_;        // B*H*L2
  float* st0   = slotB;                                // B*H*L2
  float* scr0  = slotB + (size_t)B_ * H_ * L2_;        // B*H*L2
  float* dec21 = slotB + (size_t)2 * B_ * H_ * L2_;    // B*H*L1 — disjoint from st0
  float* st1   = slotA;                                // B*H*L1 (enc1/enc2 dead)
  float* scr1  = slotA + (size_t)B_ * H_ * L1_;        // B*H*L1
  float* dec32 = slotB;                                // B*H*L0 (st0/dec21 dead)
  float* st2   = slotA;                                // B*H*L0 (st1/scr1 dead)
  float* scr2  = slotB;                                // B*H*L0 (dec32 dead post-enc)

  auto tt_layer = [&](int m, int i) -> const unsigned short* {
    const size_t NTm = (m == 0) ? 10 : (m == 1) ? 20 : 40;
    const size_t base = (m == 0) ? 0 : (m == 1) ? (size_t)64 * NL_ * 10
                                                : (size_t)64 * NL_ * 30;
    return TtG + (base + (size_t)i * 64 * NTm) * 512;
  };

  k_compute_K_tt<<<NM_ * NL_ * H_, 256, 0, stream>>>(s4_ldt, s4_C, s4_logA, s4_Aim, TtG);
  k_pack_w<<<((int)nWsz + 255) / 256, 256, 0, stream>>>(out_W, oWhi, oWlo, (int)nWsz);
  k_pack_w<<<48, 256, 0, stream>>>(enc_W, eWhi, eWlo, 3 * 4096);
  k_pack_gather<<<48, 256, 0, stream>>>(cd1_W, c1hi, c1lo, 3 * 4096, 192, 3);
  k_pack_gather<<<32, 256, 0, stream>>>(cd2_W, c2hi, c2lo, 2 * 4096, 128, 2);
  k_pack_gather<<<48, 256, 0, stream>>>(up_W, uphi, uplo, 3 * 4096, 3, 192);
  k_pack_gather<<<48, 256, 0, stream>>>(up1_W, u1hi, u1lo, 3 * 4096, 3, 192);

  // enc1 = conv_d1(x), enc2 = conv_d2(enc1)
  k_down_mfma<3, 1><<<B_ * (L1_ / 32), 256, 0, stream>>>(c1hi, c1lo, cd1_b, x, enc1,
                                                         L0_, L1_);
  k_down_mfma<2, 0><<<B_ * (L2_ / 32), 256, 0, stream>>>(c2hi, c2lo, cd2_b, enc1, enc2,
                                                         L1_, L2_);

  auto run_model = [&](int m, const float* input, float* state, float* scratch,
                       int Lm, float* final_out) {
    k_enc_mfma<<<B_ * (Lm / 32), 256, 0, stream>>>(eWhi + m * 4096, eWlo + m * 4096,
                                                   enc_b + (size_t)m * H_, input, state, Lm);
    for (int i = 0; i < NL_; ++i) {
      const unsigned short* Tl = tt_layer(m, i);
      const float* Dl = s4_D + ((size_t)m * NL_ + i) * H_;
      const int cgrid = (B_ / 16) * H_;
      if (Lm == L2_)
        k_conv_gelu_mfma<L2_><<<cgrid, 256, 0, stream>>>(state, Tl, Dl, scratch);
      else if (Lm == L1_)
        k_conv_gelu_mfma<L1_><<<cgrid, 256, 0, stream>>>(state, Tl, Dl, scratch);
      else
        k_conv_gelu_mfma<L0_><<<cgrid, 256, 0, stream>>>(state, Tl, Dl, scratch);
      float* obuf = (i == NL_ - 1 && final_out) ? final_out : state;
      const size_t wbase = ((size_t)m * NL_ + i) * 2 * H_ * H_;
      if (Lm == L2_)
        k_glu_ln_mfma2<2><<<B_ * (Lm / 32), 256, 0, stream>>>(
            oWhi + wbase, oWlo + wbase,
            out_b + ((size_t)m * NL_ + i) * 2 * H_,
            ln_g + ((size_t)m * NL_ + i) * H_,
            ln_b + ((size_t)m * NL_ + i) * H_,
            scratch, state, obuf, Lm);
      else
        k_glu_ln_mfma2<4><<<B_ * (Lm / 64), 256, 0, stream>>>(
            oWhi + wbase, oWlo + wbase,
            out_b + ((size_t)m * NL_ + i) * 2 * H_,
            ln_g + ((size_t)m * NL_ + i) * H_,
            ln_b + ((size_t)m * NL_ + i) * H_,
            scratch, state, obuf, Lm);
    }
  };

  // model 0 on enc2 (L=160): encoder out-of-place into st0
  run_model(0, enc2, st0, scr0, L2_, nullptr);
  // dec21 = convT(enc2 + m0out, up_W) + up_b + enc1  (fused add; disjoint)
  k_convT_mfma<<<B_ * (L2_ / 32), 256, 0, stream>>>(uphi, uplo, up_b, enc1, enc2, st0,
                                                    dec21, L2_, 1);
  // model 1 on dec21 (L=320): encoder into st1 (slotA)
  run_model(1, dec21, st1, scr1, L1_, nullptr);
  // dec32 = convT(m1-out, up1_W) + enc0 -> slotB (dec21/st0 dead)
  k_convT_mfma<<<B_ * (L1_ / 32), 256, 0, stream>>>(u1hi, u1lo, up_b, x, st1, nullptr,
                                                    dec32, L1_, 0);
  // model 2 on dec32 (L=640): encoder into st2 (slotA); final layer -> d_out
  run_model(2, dec32, st2, scr2, L0_, outp);
}

// Round 15
// 1148.589 us; speedup vs baseline: 1.0850x; 1.0850x over previous
//
#include <hip/hip_runtime.h>
#include <hip/hip_bf16.h>
#include <math.h>

namespace {

constexpr int B_ = 256, H_ = 64, L0_ = 640, L1_ = 320, L2_ = 160;
constexpr int N2_ = 32, NL_ = 8, NM_ = 3;

typedef __attribute__((ext_vector_type(8))) short bf16x8;
typedef __attribute__((ext_vector_type(4))) float f32x4;

__device__ __forceinline__ unsigned short f2bf(float x) {
  __hip_bfloat16 h = __float2bfloat16(x);
  unsigned short u;
  __builtin_memcpy(&u, &h, 2);
  return u;
}
__device__ __forceinline__ float bf2f(unsigned short h) {
  return __uint_as_float(((unsigned int)h) << 16);
}
__device__ __forceinline__ float gelu_f(float x) {
  const float t = 0.7978845608028654f * (x + 0.044715f * x * x * x);
  return x / (1.f + __expf(-2.f * t));
}
__device__ __forceinline__ void split8(const float* v, bf16x8& hi, bf16x8& lo) {
#pragma unroll
  for (int i = 0; i < 8; ++i) {
    const unsigned short hh = f2bf(v[i]);
    hi[i] = (short)hh;
    lo[i] = (short)f2bf(v[i] - bf2f(hh));
  }
}

// ---------------------------------------------------------------------------
// K + Toeplitz-fragment precompute (spill-free). One block per (m, layer, h).
// ---------------------------------------------------------------------------
__global__ __launch_bounds__(256) void k_compute_K_tt(
    const float* __restrict__ log_dt, const float* __restrict__ C,
    const float* __restrict__ logA, const float* __restrict__ Aim,
    unsigned short* __restrict__ TtG) {
  const int bid = blockIdx.x;
  const int m = bid / (NL_ * H_);
  const int rest = bid % (NL_ * H_);
  const int li = rest / H_;
  const int h = rest % H_;
  const int ph = (m * NL_ + li) * H_ + h;
  __shared__ float qkr[7][N2_], qki[7][N2_];
  __shared__ float sCr[N2_], sCi[N2_];
  __shared__ float Ksh[L0_];
  const int tid = threadIdx.x;
  if (tid < N2_) {
    const int n = tid;
    const float dt = expf(log_dt[ph]);
    const float Are = -expf(logA[(size_t)ph * N2_ + n]);
    const float Ai = Aim[(size_t)ph * N2_ + n];
    const float ar = dt * Are, ai = dt * Ai;
    const float er = expf(ar);
    float sn, cs;
    sincosf(ai, &sn, &cs);
    const float mr = er * cs - 1.f;
    const float mi = er * sn;
    const float den = Are * Are + Ai * Ai;
    const float qr_ = (mr * Are + mi * Ai) / den;
    const float qi_ = (mi * Are - mr * Ai) / den;
    const float C0 = C[((size_t)ph * N2_ + n) * 2 + 0];
    const float C1 = C[((size_t)ph * N2_ + n) * 2 + 1];
    sCr[n] = C0 * qr_ - C1 * qi_;
    sCi[n] = C0 * qi_ + C1 * qr_;
    float qr = er * cs, qi = er * sn;
#pragma unroll
    for (int k = 0; k < 7; ++k) {
      qkr[k][n] = qr;
      qki[k][n] = qi;
      const float nr = qr * qr - qi * qi;
      qi = 2.f * qr * qi;
      qr = nr;
    }
  }
  __syncthreads();
  const int Lm = (m == 0) ? L2_ : (m == 1) ? L1_ : L0_;
  const int NT = Lm / 16;

  const int l0 = tid >> 2;
  const int g = tid & 3;
  float pr[8], pi[8];
#pragma unroll
  for (int j = 0; j < 8; ++j) { pr[j] = 1.f; pi[j] = 0.f; }
#pragma unroll
  for (int k = 0; k < 6; ++k) {
    if ((l0 >> k) & 1) {
#pragma unroll
      for (int j = 0; j < 8; ++j) {
        const int n = g * 8 + j;
        const float qr = qkr[k][n], qi = qki[k][n];
        const float nr = pr[j] * qr - pi[j] * qi;
        pi[j] = pr[j] * qi + pi[j] * qr;
        pr[j] = nr;
      }
    }
  }
  for (int l = l0; l < Lm; l += 64) {
    float acc = 0.f;
#pragma unroll
    for (int j = 0; j < 8; ++j) {
      const int n = g * 8 + j;
      acc += sCr[n] * pr[j] - sCi[n] * pi[j];
    }
    acc += __shfl_xor(acc, 1);
    acc += __shfl_xor(acc, 2);
    if (g == 0) Ksh[l] = 2.f * acc;
    if (l + 64 < Lm) {
#pragma unroll
      for (int j = 0; j < 8; ++j) {
        const int n = g * 8 + j;
        const float qr = qkr[6][n], qi = qki[6][n];
        const float nr = pr[j] * qr - pi[j] * qi;
        pi[j] = pr[j] * qi + pi[j] * qr;
        pr[j] = nr;
      }
    }
  }
  __syncthreads();
  const size_t base_tiles = ((m == 0) ? 0 : (m == 1) ? (size_t)64 * NL_ * 10
                                                     : (size_t)64 * NL_ * 30) +
                            (size_t)li * 64 * NT + (size_t)h * NT;
  unsigned short* Tg = TtG + base_tiles * 512;
  for (int w = tid; w < NT * 256; w += 256) {
    const int nd = w >> 8;
    const int rem = w & 255;
    const int lane = rem >> 2;
    const int pp = rem & 3;
    const int base = nd * 16 + (lane & 15) - ((lane >> 4) << 3) - 2 * pp;
    const float f0 = (base >= 0) ? Ksh[base] : 0.f;
    const float f1 = (base - 1 >= 0) ? Ksh[base - 1] : 0.f;
    *(unsigned int*)&Tg[nd * 512 + lane * 8 + 2 * pp] =
        (unsigned int)f2bf(f0) | ((unsigned int)f2bf(f1) << 16);
  }
}

// ---------------------------------------------------------------------------
// Pack f32 weights -> bf16 hi/lo (identity indexing).
// ---------------------------------------------------------------------------
__global__ void k_pack_w(const float* __restrict__ W, unsigned short* __restrict__ hi,
                         unsigned short* __restrict__ lo, int n) {
  const int p = blockIdx.x * 256 + threadIdx.x;
  if (p < n) {
    const float w = W[p];
    const unsigned short h = f2bf(w);
    hi[p] = h;
    lo[p] = f2bf(w - bf2f(h));
  }
}

// Gather-pack conv weights into P[k][o*64+i] hi/lo. src = o*so + i*si + k.
__global__ void k_pack_gather(const float* __restrict__ W, unsigned short* __restrict__ hi,
                              unsigned short* __restrict__ lo, int n, int so, int si) {
  const int idx = blockIdx.x * 256 + threadIdx.x;
  if (idx < n) {
    const int k = idx >> 12;
    const int rem = idx & 4095;
    const int o = rem >> 6;
    const int i = rem & 63;
    const float w = W[o * so + i * si + k];
    const unsigned short h = f2bf(w);
    hi[idx] = h;
    lo[idx] = f2bf(w - bf2f(h));
  }
}

// ---------------------------------------------------------------------------
// MFMA 1x1 encoder v2: LDS-staged. Block = (b, 32-l tile). OUT-OF-PLACE only.
// ---------------------------------------------------------------------------
__global__ __launch_bounds__(256) void k_enc_mfma(
    const unsigned short* __restrict__ Whi, const unsigned short* __restrict__ Wlo,
    const float* __restrict__ bvec, const float* __restrict__ in_,
    float* __restrict__ out, int Lcur) {
  constexpr int KS = 72;
  __shared__ __align__(16) unsigned short Xhi[32 * KS];
  __shared__ __align__(16) unsigned short Xlo[32 * KS];
  const int tid = threadIdx.x;
  const int w = tid >> 6, lane = tid & 63, c15 = lane & 15, g4 = lane >> 4;
  const int tilesPerB = Lcur >> 5;
  const int b = blockIdx.x / tilesPerB;
  const int l0 = ((blockIdx.x % tilesPerB) << 5);
  const size_t bbase = (size_t)b * H_ * Lcur;

#pragma unroll
  for (int e = 0; e < 8; ++e) {
    const int idx = e * 256 + tid;
    const int ch = idx >> 5;
    const int c = idx & 31;
    const float v = in_[bbase + (size_t)ch * Lcur + l0 + c];
    const unsigned short hh = f2bf(v);
    Xhi[c * KS + ch] = hh;
    Xlo[c * KS + ch] = f2bf(v - bf2f(hh));
  }
  bf16x8 wh[2], wl[2];
#pragma unroll
  for (int q = 0; q < 2; ++q) {
    const int ra = (16 * w + c15) * 64 + q * 32 + 8 * g4;
    wh[q] = *(const bf16x8*)(Whi + ra);
    wl[q] = *(const bf16x8*)(Wlo + ra);
  }
  __syncthreads();

  f32x4 acc[2] = {{0.f, 0.f, 0.f, 0.f}, {0.f, 0.f, 0.f, 0.f}};
#pragma unroll
  for (int lt = 0; lt < 2; ++lt) {
    const int lc = lt * 16 + c15;
#pragma unroll
    for (int q = 0; q < 2; ++q) {
      const int crow = q * 32 + 8 * g4;
      const bf16x8 xh = *(const bf16x8*)&Xhi[lc * KS + crow];
      const bf16x8 xl = *(const bf16x8*)&Xlo[lc * KS + crow];
      acc[lt] = __builtin_amdgcn_mfma_f32_16x16x32_bf16(wh[q], xh, acc[lt], 0, 0, 0);
      acc[lt] = __builtin_amdgcn_mfma_f32_16x16x32_bf16(wh[q], xl, acc[lt], 0, 0, 0);
      acc[lt] = __builtin_amdgcn_mfma_f32_16x16x32_bf16(wl[q], xh, acc[lt], 0, 0, 0);
    }
  }
#pragma unroll
  for (int lt = 0; lt < 2; ++lt) {
#pragma unroll
    for (int r = 0; r < 4; ++r) {
      const int ca = 16 * w + 4 * g4 + r;
      out[bbase + (size_t)ca * Lcur + l0 + lt * 16 + c15] = acc[lt][r] + bvec[ca];
    }
  }
}

// ---------------------------------------------------------------------------
// MFMA strided down-conv v2 (k=KW, s=2, pad=PAD), LDS-staged.
// ---------------------------------------------------------------------------
template <int KW, int PAD>
__global__ __launch_bounds__(256) void k_down_mfma(
    const unsigned short* __restrict__ Phi, const unsigned short* __restrict__ Plo,
    const float* __restrict__ bias, const float* __restrict__ in_,
    float* __restrict__ out, int Lin, int Lout) {
  constexpr int WCOLS = 62 + KW;
  constexpr int KS = 72;
  __shared__ __align__(16) unsigned short Xhi[WCOLS * KS];
  __shared__ __align__(16) unsigned short Xlo[WCOLS * KS];
  const int tid = threadIdx.x;
  const int w = tid >> 6, lane = tid & 63, c15 = lane & 15, g4 = lane >> 4;
  const int tilesPerB = Lout >> 5;
  const int b = blockIdx.x / tilesPerB;
  const int t0 = ((blockIdx.x % tilesPerB) << 5);
  const int c0 = 2 * t0 - PAD;
  const size_t ibase = (size_t)b * H_ * Lin;

  for (int idx = tid; idx < 64 * WCOLS; idx += 256) {
    const int ch = idx / WCOLS;
    const int c = idx % WCOLS;
    const int gc = c0 + c;
    const float v = (gc >= 0 && gc < Lin) ? in_[ibase + (size_t)ch * Lin + gc] : 0.f;
    const unsigned short hh = f2bf(v);
    Xhi[c * KS + ch] = hh;
    Xlo[c * KS + ch] = f2bf(v - bf2f(hh));
  }
  bf16x8 wh[KW][2], wl[KW][2];
#pragma unroll
  for (int k = 0; k < KW; ++k)
#pragma unroll
    for (int q = 0; q < 2; ++q) {
      const int ra = (k << 12) + (16 * w + c15) * 64 + q * 32 + 8 * g4;
      wh[k][q] = *(const bf16x8*)(Phi + ra);
      wl[k][q] = *(const bf16x8*)(Plo + ra);
    }
  __syncthreads();

  f32x4 acc[2] = {{0.f, 0.f, 0.f, 0.f}, {0.f, 0.f, 0.f, 0.f}};
#pragma unroll
  for (int lt = 0; lt < 2; ++lt) {
#pragma unroll
    for (int q = 0; q < 2; ++q) {
      const int crow = q * 32 + 8 * g4;
#pragma unroll
      for (int k = 0; k < KW; ++k) {
        const int lc = 2 * (lt * 16 + c15) + k;
        const bf16x8 xh = *(const bf16x8*)&Xhi[lc * KS + crow];
        const bf16x8 xl = *(const bf16x8*)&Xlo[lc * KS + crow];
        acc[lt] = __builtin_amdgcn_mfma_f32_16x16x32_bf16(wh[k][q], xh, acc[lt], 0, 0, 0);
        acc[lt] = __builtin_amdgcn_mfma_f32_16x16x32_bf16(wh[k][q], xl, acc[lt], 0, 0, 0);
        acc[lt] = __builtin_amdgcn_mfma_f32_16x16x32_bf16(wl[k][q], xh, acc[lt], 0, 0, 0);
      }
    }
  }
  const size_t obase = (size_t)b * H_ * Lout;
#pragma unroll
  for (int lt = 0; lt < 2; ++lt) {
#pragma unroll
    for (int r = 0; r < 4; ++r) {
      const int ca = 16 * w + 4 * g4 + r;
      out[obase + (size_t)ca * Lout + t0 + lt * 16 + c15] = acc[lt][r] + bias[ca];
    }
  }
}

// ---------------------------------------------------------------------------
// MFMA ConvTranspose1d v2 (k=3 s=2 p=1 op=1), LDS-staged; optional fused
// second input. NOTE: out must NOT alias in_/in2/skip.
// ---------------------------------------------------------------------------
__global__ __launch_bounds__(256) void k_convT_mfma(
    const unsigned short* __restrict__ Phi, const unsigned short* __restrict__ Plo,
    const float* __restrict__ bias, const float* __restrict__ skip,
    const float* __restrict__ in_, const float* __restrict__ in2,
    float* __restrict__ out, int Lin, int hasBias) {
  constexpr int WCOLS = 33;
  constexpr int KS = 72;
  __shared__ __align__(16) unsigned short Xhi[WCOLS * KS];
  __shared__ __align__(16) unsigned short Xlo[WCOLS * KS];
  const int tid = threadIdx.x;
  const int w = tid >> 6, lane = tid & 63, c15 = lane & 15, g4 = lane >> 4;
  const int tilesPerB = Lin >> 5;
  const int b = blockIdx.x / tilesPerB;
  const int j0 = ((blockIdx.x % tilesPerB) << 5);
  const int Lout = 2 * Lin;
  const size_t ibase = (size_t)b * H_ * Lin;

  for (int idx = tid; idx < 64 * WCOLS; idx += 256) {
    const int ch = idx / WCOLS;
    const int c = idx % WCOLS;
    const int gc = j0 + c;
    float v = 0.f;
    if (gc < Lin) {
      const size_t p = ibase + (size_t)ch * Lin + gc;
      v = in_[p];
      if (in2) v += in2[p];
    }
    const unsigned short hh = f2bf(v);
    Xhi[c * KS + ch] = hh;
    Xlo[c * KS + ch] = f2bf(v - bf2f(hh));
  }
  bf16x8 wh[3][2], wl[3][2];
#pragma unroll
  for (int k = 0; k < 3; ++k)
#pragma unroll
    for (int q = 0; q < 2; ++q) {
      const int ra = (k << 12) + (16 * w + c15) * 64 + q * 32 + 8 * g4;
      wh[k][q] = *(const bf16x8*)(Phi + ra);
      wl[k][q] = *(const bf16x8*)(Plo + ra);
    }
  __syncthreads();

  f32x4 aE[2] = {{0.f, 0.f, 0.f, 0.f}, {0.f, 0.f, 0.f, 0.f}};
  f32x4 aO[2] = {{0.f, 0.f, 0.f, 0.f}, {0.f, 0.f, 0.f, 0.f}};
#pragma unroll
  for (int lt = 0; lt < 2; ++lt) {
    const int lc = lt * 16 + c15;
#pragma unroll
    for (int q = 0; q < 2; ++q) {
      const int crow = q * 32 + 8 * g4;
      const bf16x8 xjh = *(const bf16x8*)&Xhi[lc * KS + crow];
      const bf16x8 xjl = *(const bf16x8*)&Xlo[lc * KS + crow];
      const bf16x8 xnh = *(const bf16x8*)&Xhi[(lc + 1) * KS + crow];
      const bf16x8 xnl = *(const bf16x8*)&Xlo[(lc + 1) * KS + crow];
      aE[lt] = __builtin_amdgcn_mfma_f32_16x16x32_bf16(wh[1][q], xjh, aE[lt], 0, 0, 0);
      aE[lt] = __builtin_amdgcn_mfma_f32_16x16x32_bf16(wh[1][q], xjl, aE[lt], 0, 0, 0);
      aE[lt] = __builtin_amdgcn_mfma_f32_16x16x32_bf16(wl[1][q], xjh, aE[lt], 0, 0, 0);
      aO[lt] = __builtin_amdgcn_mfma_f32_16x16x32_bf16(wh[2][q], xjh, aO[lt], 0, 0, 0);
      aO[lt] = __builtin_amdgcn_mfma_f32_16x16x32_bf16(wh[2][q], xjl, aO[lt], 0, 0, 0);
      aO[lt] = __builtin_amdgcn_mfma_f32_16x16x32_bf16(wl[2][q], xjh, aO[lt], 0, 0, 0);
      aO[lt] = __builtin_amdgcn_mfma_f32_16x16x32_bf16(wh[0][q], xnh, aO[lt], 0, 0, 0);
      aO[lt] = __builtin_amdgcn_mfma_f32_16x16x32_bf16(wh[0][q], xnl, aO[lt], 0, 0, 0);
      aO[lt] = __builtin_amdgcn_mfma_f32_16x16x32_bf16(wl[0][q], xnh, aO[lt], 0, 0, 0);
    }
  }
  const size_t obase = (size_t)b * H_ * Lout;
#pragma unroll
  for (int lt = 0; lt < 2; ++lt) {
#pragma unroll
    for (int r = 0; r < 4; ++r) {
      const int ca = 16 * w + 4 * g4 + r;
      const float bb = hasBias ? bias[ca] : 0.f;
      const size_t pos = obase + (size_t)ca * Lout + 2 * (j0 + lt * 16 + c15);
      out[pos] = aE[lt][r] + bb + skip[pos];
      out[pos + 1] = aO[lt][r] + bb + skip[pos + 1];
    }
  }
}

// ---------------------------------------------------------------------------
// MFMA causal conv + D-skip + gelu, v5: v3 structure (4 acc regs, tile-major)
// + depth-1 software prefetch of B-frags (curB[4] hold diag t0+t-2s; loads
// for step s+1 issued before this step's MFMAs). Same MFMA set/order as v3.
// ---------------------------------------------------------------------------
template <int L>
__global__ __launch_bounds__(256) void k_conv_gelu_mfma(
    const float* __restrict__ u, const unsigned short* __restrict__ Tt,
    const float* __restrict__ D, float* __restrict__ y) {
  constexpr int NT = L / 16;
  constexpr int NG = (NT + 3) / 4;
  constexpr int LP = L + 8;
  __shared__ unsigned short uhi[16 * LP];

  const int h = blockIdx.x & 63;
  const int b0 = (blockIdx.x >> 6) * 16;
  const int tid = threadIdx.x;

  // stage u (bf16): row = tid>>4 (16 rows), 16 threads per row, float4 loads
  {
    const int row = tid >> 4;
    const int ct = tid & 15;
    const float4* src = (const float4*)(u + ((size_t)(b0 + row) * H_ + h) * L);
#pragma unroll
    for (int c4 = ct; c4 < L / 4; c4 += 16) {
      const float4 v = src[c4];
      const unsigned int p0 = (unsigned int)f2bf(v.x) | ((unsigned int)f2bf(v.y) << 16);
      const unsigned int p1 = (unsigned int)f2bf(v.z) | ((unsigned int)f2bf(v.w) << 16);
      unsigned int* dst = (unsigned int*)&uhi[row * LP + 4 * c4];
      dst[0] = p0;
      dst[1] = p1;
    }
  }
  __syncthreads();

  const int wv = tid >> 6;
  const int lane = tid & 63;
  const float Dh = D[h];
  const int lquad = lane & 15;
  const int lhi = lane >> 4;
  const unsigned short* Th = Tt + (size_t)h * NT * 512 + lane * 8;

  for (int g = wv; g < NG; g += 4) {
    const int t0 = g * 4;
    const int ntile = (NT - t0 < 4) ? (NT - t0) : 4;
    f32x4 acc[4];
#pragma unroll
    for (int t = 0; t < 4; ++t) acc[t] = (f32x4){0.f, 0.f, 0.f, 0.f};

    // prologue: B-frags for s=0 (tile t uses diag t0+t)
    bf16x8 curB[4];
#pragma unroll
    for (int t = 0; t < 4; ++t)
      if (t < ntile) curB[t] = *(const bf16x8*)(Th + (size_t)(t0 + t) * 512);

    const int nsteps = ((t0 + ntile - 1) * 16) / 32 + 1;
    for (int s = 0; s < nsteps; ++s) {
      const int j0 = 32 * s;
      const int colbase = j0 + (lhi << 3);
      const bf16x8 ah = *(const bf16x8*)&uhi[lquad * LP + colbase];
      // prefetch B-frags for step s+1 (diag decreases by 2) — independent of
      // this step's MFMAs, issued early so latency hides under compute
      bf16x8 nxtB[4];
#pragma unroll
      for (int t = 0; t < 4; ++t) {
        const int ndn = t0 + t - 2 * (s + 1);
        nxtB[t] = curB[t];
        if (t < ntile && ndn >= 0)
          nxtB[t] = *(const bf16x8*)(Th + (size_t)ndn * 512);
      }
#pragma unroll
      for (int t = 0; t < 4; ++t) {
        if (t >= ntile) break;
        const int d0 = (t0 + t) * 16 - j0;
        if (d0 < 0) continue;  // causal: wave-uniform skip
        acc[t] = __builtin_amdgcn_mfma_f32_16x16x32_bf16(ah, curB[t], acc[t], 0, 0, 0);
      }
#pragma unroll
      for (int t = 0; t < 4; ++t) curB[t] = nxtB[t];
    }
#pragma unroll
    for (int t = 0; t < 4; ++t) {
      if (t >= ntile) break;
      const int l = (t0 + t) * 16 + lquad;
#pragma unroll
      for (int r = 0; r < 4; ++r) {
        const int row = (lhi << 2) + r;
        const float uv = bf2f(uhi[row * LP + l]);
        const float val = acc[t][r] + uv * Dh;
        y[((size_t)(b0 + row) * H_ + h) * L + l] = gelu_f(val);
      }
    }
  }
}

// ---------------------------------------------------------------------------
// MFMA out-proj (64->128) + GLU + residual + LayerNorm, v2 (unchanged).
// ---------------------------------------------------------------------------
template <int LT>
__global__ __launch_bounds__(256) void k_glu_ln_mfma2(
    const unsigned short* __restrict__ Whi, const unsigned short* __restrict__ Wlo,
    const float* __restrict__ ob, const float* __restrict__ lng,
    const float* __restrict__ lnb, const float* __restrict__ ybuf,
    const float* __restrict__ xbuf, float* __restrict__ obuf, int Lcur) {
  constexpr int LTILE = LT * 16;
  constexpr int KS = 72;
  __shared__ __align__(16) unsigned short Yhi[LTILE * KS];
  __shared__ __align__(16) unsigned short Ylo[LTILE * KS];
  __shared__ float red[4][LTILE][2];
  const int tid = threadIdx.x;
  const int w = tid >> 6, lane = tid & 63, c15 = lane & 15, g4 = lane >> 4;
  const int tilesPerB = Lcur / LTILE;
  const int b = blockIdx.x / tilesPerB;
  const int l0 = (blockIdx.x % tilesPerB) * LTILE;
  const size_t bbase = (size_t)b * H_ * Lcur;

  constexpr int NE = (64 * LTILE) / 256;
#pragma unroll
  for (int e = 0; e < NE; ++e) {
    const int idx = e * 256 + tid;
    const int k = idx / LTILE;
    const int l = idx % LTILE;
    const float v = ybuf[bbase + (size_t)k * Lcur + l0 + l];
    const unsigned short hh = f2bf(v);
    Yhi[l * KS + k] = hh;
    Ylo[l * KS + k] = f2bf(v - bf2f(hh));
  }

  bf16x8 wah[2], wal[2], wgh[2], wgl[2];
#pragma unroll
  for (int q = 0; q < 2; ++q) {
    const int crow = q * 32 + 8 * g4;
    const int ra = (16 * w + c15) * 64 + crow;
    const int rg = ((64 + 16 * w) + c15) * 64 + crow;
    wah[q] = *(const bf16x8*)(Whi + ra);
    wal[q] = *(const bf16x8*)(Wlo + ra);
    wgh[q] = *(const bf16x8*)(Whi + rg);
    wgl[q] = *(const bf16x8*)(Wlo + rg);
  }
  __syncthreads();

  float wv[LT][4];
#pragma unroll
  for (int lt = 0; lt < LT; ++lt) {
    const int ll = lt * 16 + c15;
    f32x4 accA = {0.f, 0.f, 0.f, 0.f}, accG = {0.f, 0.f, 0.f, 0.f};
#pragma unroll
    for (int q = 0; q < 2; ++q) {
      const int crow = q * 32 + 8 * g4;
      const bf16x8 yh = *(const bf16x8*)&Yhi[ll * KS + crow];
      const bf16x8 yl = *(const bf16x8*)&Ylo[ll * KS + crow];
      accA = __builtin_amdgcn_mfma_f32_16x16x32_bf16(wah[q], yh, accA, 0, 0, 0);
      accA = __builtin_amdgcn_mfma_f32_16x16x32_bf16(wah[q], yl, accA, 0, 0, 0);
      accA = __builtin_amdgcn_mfma_f32_16x16x32_bf16(wal[q], yh, accA, 0, 0, 0);
      accG = __builtin_amdgcn_mfma_f32_16x16x32_bf16(wgh[q], yh, accG, 0, 0, 0);
      accG = __builtin_amdgcn_mfma_f32_16x16x32_bf16(wgh[q], yl, accG, 0, 0, 0);
      accG = __builtin_amdgcn_mfma_f32_16x16x32_bf16(wgl[q], yh, accG, 0, 0, 0);
    }
    float s1 = 0.f, s2 = 0.f;
#pragma unroll
    for (int r = 0; r < 4; ++r) {
      const int ca = 16 * w + 4 * g4 + r;
      const float a = accA[r] + ob[ca];
      const float g = accG[r] + ob[H_ + ca];
      const float z = a / (1.f + expf(-g));
      const float xv = xbuf[bbase + (size_t)ca * Lcur + l0 + ll];
      wv[lt][r] = z + xv;
      s1 += wv[lt][r];
      s2 += wv[lt][r] * wv[lt][r];
    }
    s1 += __shfl_xor(s1, 16);
    s2 += __shfl_xor(s2, 16);
    s1 += __shfl_xor(s1, 32);
    s2 += __shfl_xor(s2, 32);
    if (g4 == 0) {
      red[w][ll][0] = s1;
      red[w][ll][1] = s2;
    }
  }
  __syncthreads();
#pragma unroll
  for (int lt = 0; lt < LT; ++lt) {
    const int ll = lt * 16 + c15;
    float t1 = 0.f, t2 = 0.f;
#pragma unroll
    for (int q = 0; q < 4; ++q) {
      t1 += red[q][ll][0];
      t2 += red[q][ll][1];
    }
    const float mean = t1 * (1.f / 64.f);
    const float var = t2 * (1.f / 64.f) - mean * mean;
    const float rstd = rsqrtf(var + 1e-5f);
#pragma unroll
    for (int r = 0; r < 4; ++r) {
      const int ca = 16 * w + 4 * g4 + r;
      obuf[bbase + (size_t)ca * Lcur + l0 + ll] =
          (wv[lt][r] - mean) * rstd * lng[ca] + lnb[ca];
    }
  }
}

}  // namespace

// ---------------------------------------------------------------------------
extern "C" void kernel_launch(void* const* d_in, const int* in_sizes, int n_in,
                              void* d_out, int out_size, void* d_ws, size_t ws_size,
                              hipStream_t stream) {
  const float* x       = (const float*)d_in[0];
  const float* enc_W   = (const float*)d_in[1];
  const float* enc_b   = (const float*)d_in[2];
  const float* ln_g    = (const float*)d_in[3];
  const float* ln_b    = (const float*)d_in[4];
  const float* s4_D    = (const float*)d_in[5];
  const float* s4_ldt  = (const float*)d_in[6];
  const float* s4_C    = (const float*)d_in[7];
  const float* s4_logA = (const float*)d_in[8];
  const float* s4_Aim  = (const float*)d_in[9];
  const float* out_W   = (const float*)d_in[10];
  const float* out_b   = (const float*)d_in[11];
  const float* cd1_W   = (const float*)d_in[12];
  const float* cd1_b   = (const float*)d_in[13];
  const float* cd2_W   = (const float*)d_in[14];
  const float* cd2_b   = (const float*)d_in[15];
  const float* up_W    = (const float*)d_in[16];
  const float* up_b    = (const float*)d_in[17];
  const float* up1_W   = (const float*)d_in[18];
  float* outp = (float*)d_out;

  // ---- workspace arena (~127.2 MB, lifetime-overlapped) ----
  unsigned short* TtG = (unsigned short*)d_ws;
  const size_t ttg_shorts = (size_t)64 * NL_ * 70 * 512;      // 18.35M
  const size_t nWsz = (size_t)NM_ * NL_ * 2 * H_ * H_;        // 1.57M
  unsigned short* oWhi = TtG + ttg_shorts;
  unsigned short* oWlo = oWhi + nWsz;
  unsigned short* eWhi = oWlo + nWsz;
  unsigned short* eWlo = eWhi + 3 * 4096;
  unsigned short* c1hi = eWlo + 3 * 4096;
  unsigned short* c1lo = c1hi + 3 * 4096;
  unsigned short* c2hi = c1lo + 3 * 4096;
  unsigned short* c2lo = c2hi + 2 * 4096;
  unsigned short* uphi = c2lo + 2 * 4096;
  unsigned short* uplo = uphi + 3 * 4096;
  unsigned short* u1hi = uplo + 3 * 4096;
  unsigned short* u1lo = u1hi + 3 * 4096;
  float* slotA = (float*)(u1lo + 3 * 4096);            // B*H*L0 floats
  float* slotB = slotA + (size_t)B_ * H_ * L0_;        // B*H*L0 floats

  // lifetime map (stream-serial, encoders all OUT-OF-PLACE):
  float* enc1  = slotA;                                // B*H*L1
  float* enc2  = slotA + (size_t)B_ * H_ * L1_;        // B*H*L2
  float* st0   = slotB;                                // B*H*L2
  float* scr0  = slotB + (size_t)B_ * H_ * L2_;        // B*H*L2
  float* dec21 = slotB + (size_t)2 * B_ * H_ * L2_;    // B*H*L1 — disjoint from st0
  float* st1   = slotA;                                // B*H*L1 (enc1/enc2 dead)
  float* scr1  = slotA + (size_t)B_ * H_ * L1_;        // B*H*L1
  float* dec32 = slotB;                                // B*H*L0 (st0/dec21 dead)
  float* st2   = slotA;                                // B*H*L0 (st1/scr1 dead)
  float* scr2  = slotB;                                // B*H*L0 (dec32 dead post-enc)

  auto tt_layer = [&](int m, int i) -> const unsigned short* {
    const size_t NTm = (m == 0) ? 10 : (m == 1) ? 20 : 40;
    const size_t base = (m == 0) ? 0 : (m == 1) ? (size_t)64 * NL_ * 10
                                                : (size_t)64 * NL_ * 30;
    return TtG + (base + (size_t)i * 64 * NTm) * 512;
  };

  k_compute_K_tt<<<NM_ * NL_ * H_, 256, 0, stream>>>(s4_ldt, s4_C, s4_logA, s4_Aim, TtG);
  k_pack_w<<<((int)nWsz + 255) / 256, 256, 0, stream>>>(out_W, oWhi, oWlo, (int)nWsz);
  k_pack_w<<<48, 256, 0, stream>>>(enc_W, eWhi, eWlo, 3 * 4096);
  k_pack_gather<<<48, 256, 0, stream>>>(cd1_W, c1hi, c1lo, 3 * 4096, 192, 3);
  k_pack_gather<<<32, 256, 0, stream>>>(cd2_W, c2hi, c2lo, 2 * 4096, 128, 2);
  k_pack_gather<<<48, 256, 0, stream>>>(up_W, uphi, uplo, 3 * 4096, 3, 192);
  k_pack_gather<<<48, 256, 0, stream>>>(up1_W, u1hi, u1lo, 3 * 4096, 3, 192);

  // enc1 = conv_d1(x), enc2 = conv_d2(enc1)
  k_down_mfma<3, 1><<<B_ * (L1_ / 32), 256, 0, stream>>>(c1hi, c1lo, cd1_b, x, enc1,
                                                         L0_, L1_);
  k_down_mfma<2, 0><<<B_ * (L2_ / 32), 256, 0, stream>>>(c2hi, c2lo, cd2_b, enc1, enc2,
                                                         L1_, L2_);

  auto run_model = [&](int m, const float* input, float* state, float* scratch,
                       int Lm, float* final_out) {
    k_enc_mfma<<<B_ * (Lm / 32), 256, 0, stream>>>(eWhi + m * 4096, eWlo + m * 4096,
                                                   enc_b + (size_t)m * H_, input, state, Lm);
    for (int i = 0; i < NL_; ++i) {
      const unsigned short* Tl = tt_layer(m, i);
      const float* Dl = s4_D + ((size_t)m * NL_ + i) * H_;
      const int cgrid = (B_ / 16) * H_;
      if (Lm == L2_)
        k_conv_gelu_mfma<L2_><<<cgrid, 256, 0, stream>>>(state, Tl, Dl, scratch);
      else if (Lm == L1_)
        k_conv_gelu_mfma<L1_><<<cgrid, 256, 0, stream>>>(state, Tl, Dl, scratch);
      else
        k_conv_gelu_mfma<L0_><<<cgrid, 256, 0, stream>>>(state, Tl, Dl, scratch);
      float* obuf = (i == NL_ - 1 && final_out) ? final_out : state;
      const size_t wbase = ((size_t)m * NL_ + i) * 2 * H_ * H_;
      if (Lm == L2_)
        k_glu_ln_mfma2<2><<<B_ * (Lm / 32), 256, 0, stream>>>(
            oWhi + wbase, oWlo + wbase,
            out_b + ((size_t)m * NL_ + i) * 2 * H_,
            ln_g + ((size_t)m * NL_ + i) * H_,
            ln_b + ((size_t)m * NL_ + i) * H_,
            scratch, state, obuf, Lm);
      else
        k_glu_ln_mfma2<4><<<B_ * (Lm / 64), 256, 0, stream>>>(
            oWhi + wbase, oWlo + wbase,
            out_b + ((size_t)m * NL_ + i) * 2 * H_,
            ln_g + ((size_t)m * NL_ + i) * H_,
            ln_b + ((size_t)m * NL_ + i) * H_,
            scratch, state, obuf, Lm);
    }
  };

  // model 0 on enc2 (L=160): encoder out-of-place into st0
  run_model(0, enc2, st0, scr0, L2_, nullptr);
  // dec21 = convT(enc2 + m0out, up_W) + up_b + enc1  (fused add; disjoint)
  k_convT_mfma<<<B_ * (L2_ / 32), 256, 0, stream>>>(uphi, uplo, up_b, enc1, enc2, st0,
                                                    dec21, L2_, 1);
  // model 1 on dec21 (L=320): encoder into st1 (slotA)
  run_model(1, dec21, st1, scr1, L1_, nullptr);
  // dec32 = convT(m1-out, up1_W) + enc0 -> slotB (dec21/st0 dead)
  k_convT_mfma<<<B_ * (L1_ / 32), 256, 0, stream>>>(u1hi, u1lo, up_b, x, st1, nullptr,
                                                    dec32, L1_, 0);
  // model 2 on dec32 (L=640): encoder into st2 (slotA); final layer -> d_out
  run_model(2, dec32, st2, scr2, L0_, outp);
}

// Round 16
// 1120.131 us; speedup vs baseline: 1.1126x; 1.0254x over previous
//
#include <hip/hip_runtime.h>
#include <hip/hip_bf16.h>
#include <math.h>

namespace {

constexpr int B_ = 256, H_ = 64, L0_ = 640, L1_ = 320, L2_ = 160;
constexpr int N2_ = 32, NL_ = 8, NM_ = 3;

typedef __attribute__((ext_vector_type(8))) short bf16x8;
typedef __attribute__((ext_vector_type(4))) float f32x4;

__device__ __forceinline__ unsigned short f2bf(float x) {
  __hip_bfloat16 h = __float2bfloat16(x);
  unsigned short u;
  __builtin_memcpy(&u, &h, 2);
  return u;
}
__device__ __forceinline__ float bf2f(unsigned short h) {
  return __uint_as_float(((unsigned int)h) << 16);
}
__device__ __forceinline__ float gelu_f(float x) {
  const float t = 0.7978845608028654f * (x + 0.044715f * x * x * x);
  return x / (1.f + __expf(-2.f * t));
}
__device__ __forceinline__ void split8(const float* v, bf16x8& hi, bf16x8& lo) {
#pragma unroll
  for (int i = 0; i < 8; ++i) {
    const unsigned short hh = f2bf(v[i]);
    hi[i] = (short)hh;
    lo[i] = (short)f2bf(v[i] - bf2f(hh));
  }
}

// ---------------------------------------------------------------------------
// K + Toeplitz-fragment precompute (spill-free). One block per (m, layer, h).
// ---------------------------------------------------------------------------
__global__ __launch_bounds__(256) void k_compute_K_tt(
    const float* __restrict__ log_dt, const float* __restrict__ C,
    const float* __restrict__ logA, const float* __restrict__ Aim,
    unsigned short* __restrict__ TtG) {
  const int bid = blockIdx.x;
  const int m = bid / (NL_ * H_);
  const int rest = bid % (NL_ * H_);
  const int li = rest / H_;
  const int h = rest % H_;
  const int ph = (m * NL_ + li) * H_ + h;
  __shared__ float qkr[7][N2_], qki[7][N2_];
  __shared__ float sCr[N2_], sCi[N2_];
  __shared__ float Ksh[L0_];
  const int tid = threadIdx.x;
  if (tid < N2_) {
    const int n = tid;
    const float dt = expf(log_dt[ph]);
    const float Are = -expf(logA[(size_t)ph * N2_ + n]);
    const float Ai = Aim[(size_t)ph * N2_ + n];
    const float ar = dt * Are, ai = dt * Ai;
    const float er = expf(ar);
    float sn, cs;
    sincosf(ai, &sn, &cs);
    const float mr = er * cs - 1.f;
    const float mi = er * sn;
    const float den = Are * Are + Ai * Ai;
    const float qr_ = (mr * Are + mi * Ai) / den;
    const float qi_ = (mi * Are - mr * Ai) / den;
    const float C0 = C[((size_t)ph * N2_ + n) * 2 + 0];
    const float C1 = C[((size_t)ph * N2_ + n) * 2 + 1];
    sCr[n] = C0 * qr_ - C1 * qi_;
    sCi[n] = C0 * qi_ + C1 * qr_;
    float qr = er * cs, qi = er * sn;
#pragma unroll
    for (int k = 0; k < 7; ++k) {
      qkr[k][n] = qr;
      qki[k][n] = qi;
      const float nr = qr * qr - qi * qi;
      qi = 2.f * qr * qi;
      qr = nr;
    }
  }
  __syncthreads();
  const int Lm = (m == 0) ? L2_ : (m == 1) ? L1_ : L0_;
  const int NT = Lm / 16;

  const int l0 = tid >> 2;
  const int g = tid & 3;
  float pr[8], pi[8];
#pragma unroll
  for (int j = 0; j < 8; ++j) { pr[j] = 1.f; pi[j] = 0.f; }
#pragma unroll
  for (int k = 0; k < 6; ++k) {
    if ((l0 >> k) & 1) {
#pragma unroll
      for (int j = 0; j < 8; ++j) {
        const int n = g * 8 + j;
        const float qr = qkr[k][n], qi = qki[k][n];
        const float nr = pr[j] * qr - pi[j] * qi;
        pi[j] = pr[j] * qi + pi[j] * qr;
        pr[j] = nr;
      }
    }
  }
  for (int l = l0; l < Lm; l += 64) {
    float acc = 0.f;
#pragma unroll
    for (int j = 0; j < 8; ++j) {
      const int n = g * 8 + j;
      acc += sCr[n] * pr[j] - sCi[n] * pi[j];
    }
    acc += __shfl_xor(acc, 1);
    acc += __shfl_xor(acc, 2);
    if (g == 0) Ksh[l] = 2.f * acc;
    if (l + 64 < Lm) {
#pragma unroll
      for (int j = 0; j < 8; ++j) {
        const int n = g * 8 + j;
        const float qr = qkr[6][n], qi = qki[6][n];
        const float nr = pr[j] * qr - pi[j] * qi;
        pi[j] = pr[j] * qi + pi[j] * qr;
        pr[j] = nr;
      }
    }
  }
  __syncthreads();
  const size_t base_tiles = ((m == 0) ? 0 : (m == 1) ? (size_t)64 * NL_ * 10
                                                     : (size_t)64 * NL_ * 30) +
                            (size_t)li * 64 * NT + (size_t)h * NT;
  unsigned short* Tg = TtG + base_tiles * 512;
  for (int w = tid; w < NT * 256; w += 256) {
    const int nd = w >> 8;
    const int rem = w & 255;
    const int lane = rem >> 2;
    const int pp = rem & 3;
    const int base = nd * 16 + (lane & 15) - ((lane >> 4) << 3) - 2 * pp;
    const float f0 = (base >= 0) ? Ksh[base] : 0.f;
    const float f1 = (base - 1 >= 0) ? Ksh[base - 1] : 0.f;
    *(unsigned int*)&Tg[nd * 512 + lane * 8 + 2 * pp] =
        (unsigned int)f2bf(f0) | ((unsigned int)f2bf(f1) << 16);
  }
}

// ---------------------------------------------------------------------------
// Pack f32 weights -> bf16 hi/lo (identity indexing).
// ---------------------------------------------------------------------------
__global__ void k_pack_w(const float* __restrict__ W, unsigned short* __restrict__ hi,
                         unsigned short* __restrict__ lo, int n) {
  const int p = blockIdx.x * 256 + threadIdx.x;
  if (p < n) {
    const float w = W[p];
    const unsigned short h = f2bf(w);
    hi[p] = h;
    lo[p] = f2bf(w - bf2f(h));
  }
}

// Gather-pack conv weights into P[k][o*64+i] hi/lo. src = o*so + i*si + k.
__global__ void k_pack_gather(const float* __restrict__ W, unsigned short* __restrict__ hi,
                              unsigned short* __restrict__ lo, int n, int so, int si) {
  const int idx = blockIdx.x * 256 + threadIdx.x;
  if (idx < n) {
    const int k = idx >> 12;
    const int rem = idx & 4095;
    const int o = rem >> 6;
    const int i = rem & 63;
    const float w = W[o * so + i * si + k];
    const unsigned short h = f2bf(w);
    hi[idx] = h;
    lo[idx] = f2bf(w - bf2f(h));
  }
}

// ---------------------------------------------------------------------------
// MFMA 1x1 encoder v2: LDS-staged. Block = (b, 32-l tile). OUT-OF-PLACE only.
// ---------------------------------------------------------------------------
__global__ __launch_bounds__(256) void k_enc_mfma(
    const unsigned short* __restrict__ Whi, const unsigned short* __restrict__ Wlo,
    const float* __restrict__ bvec, const float* __restrict__ in_,
    float* __restrict__ out, int Lcur) {
  constexpr int KS = 72;
  __shared__ __align__(16) unsigned short Xhi[32 * KS];
  __shared__ __align__(16) unsigned short Xlo[32 * KS];
  const int tid = threadIdx.x;
  const int w = tid >> 6, lane = tid & 63, c15 = lane & 15, g4 = lane >> 4;
  const int tilesPerB = Lcur >> 5;
  const int b = blockIdx.x / tilesPerB;
  const int l0 = ((blockIdx.x % tilesPerB) << 5);
  const size_t bbase = (size_t)b * H_ * Lcur;

#pragma unroll
  for (int e = 0; e < 8; ++e) {
    const int idx = e * 256 + tid;
    const int ch = idx >> 5;
    const int c = idx & 31;
    const float v = in_[bbase + (size_t)ch * Lcur + l0 + c];
    const unsigned short hh = f2bf(v);
    Xhi[c * KS + ch] = hh;
    Xlo[c * KS + ch] = f2bf(v - bf2f(hh));
  }
  bf16x8 wh[2], wl[2];
#pragma unroll
  for (int q = 0; q < 2; ++q) {
    const int ra = (16 * w + c15) * 64 + q * 32 + 8 * g4;
    wh[q] = *(const bf16x8*)(Whi + ra);
    wl[q] = *(const bf16x8*)(Wlo + ra);
  }
  __syncthreads();

  f32x4 acc[2] = {{0.f, 0.f, 0.f, 0.f}, {0.f, 0.f, 0.f, 0.f}};
#pragma unroll
  for (int lt = 0; lt < 2; ++lt) {
    const int lc = lt * 16 + c15;
#pragma unroll
    for (int q = 0; q < 2; ++q) {
      const int crow = q * 32 + 8 * g4;
      const bf16x8 xh = *(const bf16x8*)&Xhi[lc * KS + crow];
      const bf16x8 xl = *(const bf16x8*)&Xlo[lc * KS + crow];
      acc[lt] = __builtin_amdgcn_mfma_f32_16x16x32_bf16(wh[q], xh, acc[lt], 0, 0, 0);
      acc[lt] = __builtin_amdgcn_mfma_f32_16x16x32_bf16(wh[q], xl, acc[lt], 0, 0, 0);
      acc[lt] = __builtin_amdgcn_mfma_f32_16x16x32_bf16(wl[q], xh, acc[lt], 0, 0, 0);
    }
  }
#pragma unroll
  for (int lt = 0; lt < 2; ++lt) {
#pragma unroll
    for (int r = 0; r < 4; ++r) {
      const int ca = 16 * w + 4 * g4 + r;
      out[bbase + (size_t)ca * Lcur + l0 + lt * 16 + c15] = acc[lt][r] + bvec[ca];
    }
  }
}

// ---------------------------------------------------------------------------
// MFMA strided down-conv v2 (k=KW, s=2, pad=PAD), LDS-staged.
// ---------------------------------------------------------------------------
template <int KW, int PAD>
__global__ __launch_bounds__(256) void k_down_mfma(
    const unsigned short* __restrict__ Phi, const unsigned short* __restrict__ Plo,
    const float* __restrict__ bias, const float* __restrict__ in_,
    float* __restrict__ out, int Lin, int Lout) {
  constexpr int WCOLS = 62 + KW;
  constexpr int KS = 72;
  __shared__ __align__(16) unsigned short Xhi[WCOLS * KS];
  __shared__ __align__(16) unsigned short Xlo[WCOLS * KS];
  const int tid = threadIdx.x;
  const int w = tid >> 6, lane = tid & 63, c15 = lane & 15, g4 = lane >> 4;
  const int tilesPerB = Lout >> 5;
  const int b = blockIdx.x / tilesPerB;
  const int t0 = ((blockIdx.x % tilesPerB) << 5);
  const int c0 = 2 * t0 - PAD;
  const size_t ibase = (size_t)b * H_ * Lin;

  for (int idx = tid; idx < 64 * WCOLS; idx += 256) {
    const int ch = idx / WCOLS;
    const int c = idx % WCOLS;
    const int gc = c0 + c;
    const float v = (gc >= 0 && gc < Lin) ? in_[ibase + (size_t)ch * Lin + gc] : 0.f;
    const unsigned short hh = f2bf(v);
    Xhi[c * KS + ch] = hh;
    Xlo[c * KS + ch] = f2bf(v - bf2f(hh));
  }
  bf16x8 wh[KW][2], wl[KW][2];
#pragma unroll
  for (int k = 0; k < KW; ++k)
#pragma unroll
    for (int q = 0; q < 2; ++q) {
      const int ra = (k << 12) + (16 * w + c15) * 64 + q * 32 + 8 * g4;
      wh[k][q] = *(const bf16x8*)(Phi + ra);
      wl[k][q] = *(const bf16x8*)(Plo + ra);
    }
  __syncthreads();

  f32x4 acc[2] = {{0.f, 0.f, 0.f, 0.f}, {0.f, 0.f, 0.f, 0.f}};
#pragma unroll
  for (int lt = 0; lt < 2; ++lt) {
#pragma unroll
    for (int q = 0; q < 2; ++q) {
      const int crow = q * 32 + 8 * g4;
#pragma unroll
      for (int k = 0; k < KW; ++k) {
        const int lc = 2 * (lt * 16 + c15) + k;
        const bf16x8 xh = *(const bf16x8*)&Xhi[lc * KS + crow];
        const bf16x8 xl = *(const bf16x8*)&Xlo[lc * KS + crow];
        acc[lt] = __builtin_amdgcn_mfma_f32_16x16x32_bf16(wh[k][q], xh, acc[lt], 0, 0, 0);
        acc[lt] = __builtin_amdgcn_mfma_f32_16x16x32_bf16(wh[k][q], xl, acc[lt], 0, 0, 0);
        acc[lt] = __builtin_amdgcn_mfma_f32_16x16x32_bf16(wl[k][q], xh, acc[lt], 0, 0, 0);
      }
    }
  }
  const size_t obase = (size_t)b * H_ * Lout;
#pragma unroll
  for (int lt = 0; lt < 2; ++lt) {
#pragma unroll
    for (int r = 0; r < 4; ++r) {
      const int ca = 16 * w + 4 * g4 + r;
      out[obase + (size_t)ca * Lout + t0 + lt * 16 + c15] = acc[lt][r] + bias[ca];
    }
  }
}

// ---------------------------------------------------------------------------
// MFMA ConvTranspose1d v2 (k=3 s=2 p=1 op=1), LDS-staged; optional fused
// second input. NOTE: out must NOT alias in_/in2/skip.
// ---------------------------------------------------------------------------
__global__ __launch_bounds__(256) void k_convT_mfma(
    const unsigned short* __restrict__ Phi, const unsigned short* __restrict__ Plo,
    const float* __restrict__ bias, const float* __restrict__ skip,
    const float* __restrict__ in_, const float* __restrict__ in2,
    float* __restrict__ out, int Lin, int hasBias) {
  constexpr int WCOLS = 33;
  constexpr int KS = 72;
  __shared__ __align__(16) unsigned short Xhi[WCOLS * KS];
  __shared__ __align__(16) unsigned short Xlo[WCOLS * KS];
  const int tid = threadIdx.x;
  const int w = tid >> 6, lane = tid & 63, c15 = lane & 15, g4 = lane >> 4;
  const int tilesPerB = Lin >> 5;
  const int b = blockIdx.x / tilesPerB;
  const int j0 = ((blockIdx.x % tilesPerB) << 5);
  const int Lout = 2 * Lin;
  const size_t ibase = (size_t)b * H_ * Lin;

  for (int idx = tid; idx < 64 * WCOLS; idx += 256) {
    const int ch = idx / WCOLS;
    const int c = idx % WCOLS;
    const int gc = j0 + c;
    float v = 0.f;
    if (gc < Lin) {
      const size_t p = ibase + (size_t)ch * Lin + gc;
      v = in_[p];
      if (in2) v += in2[p];
    }
    const unsigned short hh = f2bf(v);
    Xhi[c * KS + ch] = hh;
    Xlo[c * KS + ch] = f2bf(v - bf2f(hh));
  }
  bf16x8 wh[3][2], wl[3][2];
#pragma unroll
  for (int k = 0; k < 3; ++k)
#pragma unroll
    for (int q = 0; q < 2; ++q) {
      const int ra = (k << 12) + (16 * w + c15) * 64 + q * 32 + 8 * g4;
      wh[k][q] = *(const bf16x8*)(Phi + ra);
      wl[k][q] = *(const bf16x8*)(Plo + ra);
    }
  __syncthreads();

  f32x4 aE[2] = {{0.f, 0.f, 0.f, 0.f}, {0.f, 0.f, 0.f, 0.f}};
  f32x4 aO[2] = {{0.f, 0.f, 0.f, 0.f}, {0.f, 0.f, 0.f, 0.f}};
#pragma unroll
  for (int lt = 0; lt < 2; ++lt) {
    const int lc = lt * 16 + c15;
#pragma unroll
    for (int q = 0; q < 2; ++q) {
      const int crow = q * 32 + 8 * g4;
      const bf16x8 xjh = *(const bf16x8*)&Xhi[lc * KS + crow];
      const bf16x8 xjl = *(const bf16x8*)&Xlo[lc * KS + crow];
      const bf16x8 xnh = *(const bf16x8*)&Xhi[(lc + 1) * KS + crow];
      const bf16x8 xnl = *(const bf16x8*)&Xlo[(lc + 1) * KS + crow];
      aE[lt] = __builtin_amdgcn_mfma_f32_16x16x32_bf16(wh[1][q], xjh, aE[lt], 0, 0, 0);
      aE[lt] = __builtin_amdgcn_mfma_f32_16x16x32_bf16(wh[1][q], xjl, aE[lt], 0, 0, 0);
      aE[lt] = __builtin_amdgcn_mfma_f32_16x16x32_bf16(wl[1][q], xjh, aE[lt], 0, 0, 0);
      aO[lt] = __builtin_amdgcn_mfma_f32_16x16x32_bf16(wh[2][q], xjh, aO[lt], 0, 0, 0);
      aO[lt] = __builtin_amdgcn_mfma_f32_16x16x32_bf16(wh[2][q], xjl, aO[lt], 0, 0, 0);
      aO[lt] = __builtin_amdgcn_mfma_f32_16x16x32_bf16(wl[2][q], xjh, aO[lt], 0, 0, 0);
      aO[lt] = __builtin_amdgcn_mfma_f32_16x16x32_bf16(wh[0][q], xnh, aO[lt], 0, 0, 0);
      aO[lt] = __builtin_amdgcn_mfma_f32_16x16x32_bf16(wh[0][q], xnl, aO[lt], 0, 0, 0);
      aO[lt] = __builtin_amdgcn_mfma_f32_16x16x32_bf16(wl[0][q], xnh, aO[lt], 0, 0, 0);
    }
  }
  const size_t obase = (size_t)b * H_ * Lout;
#pragma unroll
  for (int lt = 0; lt < 2; ++lt) {
#pragma unroll
    for (int r = 0; r < 4; ++r) {
      const int ca = 16 * w + 4 * g4 + r;
      const float bb = hasBias ? bias[ca] : 0.f;
      const size_t pos = obase + (size_t)ca * Lout + 2 * (j0 + lt * 16 + c15);
      out[pos] = aE[lt][r] + bb + skip[pos];
      out[pos + 1] = aO[lt][r] + bb + skip[pos + 1];
    }
  }
}

// ---------------------------------------------------------------------------
// MFMA causal conv + D-skip + gelu, v6: 32 batch rows per block (one h).
// Each B-frag (Toeplitz diag) feeds TWO MFMAs (row-halves 0-15 / 16-31),
// halving B-loads and loop overhead per MFMA. Depth-1 prefetch kept from v5.
// Same per-output MFMA math as v5 -> identical numerics.
// ---------------------------------------------------------------------------
template <int L>
__global__ __launch_bounds__(256) void k_conv_gelu_mfma(
    const float* __restrict__ u, const unsigned short* __restrict__ Tt,
    const float* __restrict__ D, float* __restrict__ y) {
  constexpr int NT = L / 16;
  constexpr int NG = (NT + 3) / 4;
  constexpr int LP = L + 24;  // 2*LP % 16 == 0 (16B-aligned b128 frags)
  __shared__ unsigned short uhi[32 * LP];

  const int h = blockIdx.x & 63;
  const int b0 = (blockIdx.x >> 6) * 32;
  const int tid = threadIdx.x;

  // stage u (bf16): row = tid>>3 (32 rows), 8 threads per row, float4 loads
  {
    const int row = tid >> 3;
    const int ct = tid & 7;
    const float4* src = (const float4*)(u + ((size_t)(b0 + row) * H_ + h) * L);
#pragma unroll
    for (int c4 = ct; c4 < L / 4; c4 += 8) {
      const float4 v = src[c4];
      const unsigned int p0 = (unsigned int)f2bf(v.x) | ((unsigned int)f2bf(v.y) << 16);
      const unsigned int p1 = (unsigned int)f2bf(v.z) | ((unsigned int)f2bf(v.w) << 16);
      unsigned int* dst = (unsigned int*)&uhi[row * LP + 4 * c4];
      dst[0] = p0;
      dst[1] = p1;
    }
  }
  __syncthreads();

  const int wv = tid >> 6;
  const int lane = tid & 63;
  const float Dh = D[h];
  const int lquad = lane & 15;
  const int lhi = lane >> 4;
  const unsigned short* Th = Tt + (size_t)h * NT * 512 + lane * 8;

  for (int g = wv; g < NG; g += 4) {
    const int t0 = g * 4;
    const int ntile = (NT - t0 < 4) ? (NT - t0) : 4;
    f32x4 acc[2][4];
#pragma unroll
    for (int a = 0; a < 2; ++a)
#pragma unroll
      for (int t = 0; t < 4; ++t) acc[a][t] = (f32x4){0.f, 0.f, 0.f, 0.f};

    // prologue: B-frags for s=0 (tile t uses diag t0+t)
    bf16x8 curB[4];
#pragma unroll
    for (int t = 0; t < 4; ++t)
      if (t < ntile) curB[t] = *(const bf16x8*)(Th + (size_t)(t0 + t) * 512);

    const int nsteps = ((t0 + ntile - 1) * 16) / 32 + 1;
    for (int s = 0; s < nsteps; ++s) {
      const int j0 = 32 * s;
      const int colbase = j0 + (lhi << 3);
      const bf16x8 ah0 = *(const bf16x8*)&uhi[lquad * LP + colbase];
      const bf16x8 ah1 = *(const bf16x8*)&uhi[(16 + lquad) * LP + colbase];
      // prefetch B-frags for step s+1 (diag decreases by 2)
      bf16x8 nxtB[4];
#pragma unroll
      for (int t = 0; t < 4; ++t) {
        const int ndn = t0 + t - 2 * (s + 1);
        nxtB[t] = curB[t];
        if (t < ntile && ndn >= 0)
          nxtB[t] = *(const bf16x8*)(Th + (size_t)ndn * 512);
      }
#pragma unroll
      for (int t = 0; t < 4; ++t) {
        if (t >= ntile) break;
        const int d0 = (t0 + t) * 16 - j0;
        if (d0 < 0) continue;  // causal: wave-uniform skip
        acc[0][t] = __builtin_amdgcn_mfma_f32_16x16x32_bf16(ah0, curB[t], acc[0][t], 0, 0, 0);
        acc[1][t] = __builtin_amdgcn_mfma_f32_16x16x32_bf16(ah1, curB[t], acc[1][t], 0, 0, 0);
      }
#pragma unroll
      for (int t = 0; t < 4; ++t) curB[t] = nxtB[t];
    }
#pragma unroll
    for (int t = 0; t < 4; ++t) {
      if (t >= ntile) break;
      const int l = (t0 + t) * 16 + lquad;
#pragma unroll
      for (int a = 0; a < 2; ++a) {
#pragma unroll
        for (int r = 0; r < 4; ++r) {
          const int row = a * 16 + (lhi << 2) + r;
          const float uv = bf2f(uhi[row * LP + l]);
          const float val = acc[a][t][r] + uv * Dh;
          y[((size_t)(b0 + row) * H_ + h) * L + l] = gelu_f(val);
        }
      }
    }
  }
}

// ---------------------------------------------------------------------------
// MFMA out-proj (64->128) + GLU + residual + LayerNorm, v2 (unchanged).
// ---------------------------------------------------------------------------
template <int LT>
__global__ __launch_bounds__(256) void k_glu_ln_mfma2(
    const unsigned short* __restrict__ Whi, const unsigned short* __restrict__ Wlo,
    const float* __restrict__ ob, const float* __restrict__ lng,
    const float* __restrict__ lnb, const float* __restrict__ ybuf,
    const float* __restrict__ xbuf, float* __restrict__ obuf, int Lcur) {
  constexpr int LTILE = LT * 16;
  constexpr int KS = 72;
  __shared__ __align__(16) unsigned short Yhi[LTILE * KS];
  __shared__ __align__(16) unsigned short Ylo[LTILE * KS];
  __shared__ float red[4][LTILE][2];
  const int tid = threadIdx.x;
  const int w = tid >> 6, lane = tid & 63, c15 = lane & 15, g4 = lane >> 4;
  const int tilesPerB = Lcur / LTILE;
  const int b = blockIdx.x / tilesPerB;
  const int l0 = (blockIdx.x % tilesPerB) * LTILE;
  const size_t bbase = (size_t)b * H_ * Lcur;

  constexpr int NE = (64 * LTILE) / 256;
#pragma unroll
  for (int e = 0; e < NE; ++e) {
    const int idx = e * 256 + tid;
    const int k = idx / LTILE;
    const int l = idx % LTILE;
    const float v = ybuf[bbase + (size_t)k * Lcur + l0 + l];
    const unsigned short hh = f2bf(v);
    Yhi[l * KS + k] = hh;
    Ylo[l * KS + k] = f2bf(v - bf2f(hh));
  }

  bf16x8 wah[2], wal[2], wgh[2], wgl[2];
#pragma unroll
  for (int q = 0; q < 2; ++q) {
    const int crow = q * 32 + 8 * g4;
    const int ra = (16 * w + c15) * 64 + crow;
    const int rg = ((64 + 16 * w) + c15) * 64 + crow;
    wah[q] = *(const bf16x8*)(Whi + ra);
    wal[q] = *(const bf16x8*)(Wlo + ra);
    wgh[q] = *(const bf16x8*)(Whi + rg);
    wgl[q] = *(const bf16x8*)(Wlo + rg);
  }
  __syncthreads();

  float wv[LT][4];
#pragma unroll
  for (int lt = 0; lt < LT; ++lt) {
    const int ll = lt * 16 + c15;
    f32x4 accA = {0.f, 0.f, 0.f, 0.f}, accG = {0.f, 0.f, 0.f, 0.f};
#pragma unroll
    for (int q = 0; q < 2; ++q) {
      const int crow = q * 32 + 8 * g4;
      const bf16x8 yh = *(const bf16x8*)&Yhi[ll * KS + crow];
      const bf16x8 yl = *(const bf16x8*)&Ylo[ll * KS + crow];
      accA = __builtin_amdgcn_mfma_f32_16x16x32_bf16(wah[q], yh, accA, 0, 0, 0);
      accA = __builtin_amdgcn_mfma_f32_16x16x32_bf16(wah[q], yl, accA, 0, 0, 0);
      accA = __builtin_amdgcn_mfma_f32_16x16x32_bf16(wal[q], yh, accA, 0, 0, 0);
      accG = __builtin_amdgcn_mfma_f32_16x16x32_bf16(wgh[q], yh, accG, 0, 0, 0);
      accG = __builtin_amdgcn_mfma_f32_16x16x32_bf16(wgh[q], yl, accG, 0, 0, 0);
      accG = __builtin_amdgcn_mfma_f32_16x16x32_bf16(wgl[q], yh, accG, 0, 0, 0);
    }
    float s1 = 0.f, s2 = 0.f;
#pragma unroll
    for (int r = 0; r < 4; ++r) {
      const int ca = 16 * w + 4 * g4 + r;
      const float a = accA[r] + ob[ca];
      const float g = accG[r] + ob[H_ + ca];
      const float z = a / (1.f + expf(-g));
      const float xv = xbuf[bbase + (size_t)ca * Lcur + l0 + ll];
      wv[lt][r] = z + xv;
      s1 += wv[lt][r];
      s2 += wv[lt][r] * wv[lt][r];
    }
    s1 += __shfl_xor(s1, 16);
    s2 += __shfl_xor(s2, 16);
    s1 += __shfl_xor(s1, 32);
    s2 += __shfl_xor(s2, 32);
    if (g4 == 0) {
      red[w][ll][0] = s1;
      red[w][ll][1] = s2;
    }
  }
  __syncthreads();
#pragma unroll
  for (int lt = 0; lt < LT; ++lt) {
    const int ll = lt * 16 + c15;
    float t1 = 0.f, t2 = 0.f;
#pragma unroll
    for (int q = 0; q < 4; ++q) {
      t1 += red[q][ll][0];
      t2 += red[q][ll][1];
    }
    const float mean = t1 * (1.f / 64.f);
    const float var = t2 * (1.f / 64.f) - mean * mean;
    const float rstd = rsqrtf(var + 1e-5f);
#pragma unroll
    for (int r = 0; r < 4; ++r) {
      const int ca = 16 * w + 4 * g4 + r;
      obuf[bbase + (size_t)ca * Lcur + l0 + ll] =
          (wv[lt][r] - mean) * rstd * lng[ca] + lnb[ca];
    }
  }
}

}  // namespace

// ---------------------------------------------------------------------------
extern "C" void kernel_launch(void* const* d_in, const int* in_sizes, int n_in,
                              void* d_out, int out_size, void* d_ws, size_t ws_size,
                              hipStream_t stream) {
  const float* x       = (const float*)d_in[0];
  const float* enc_W   = (const float*)d_in[1];
  const float* enc_b   = (const float*)d_in[2];
  const float* ln_g    = (const float*)d_in[3];
  const float* ln_b    = (const float*)d_in[4];
  const float* s4_D    = (const float*)d_in[5];
  const float* s4_ldt  = (const float*)d_in[6];
  const float* s4_C    = (const float*)d_in[7];
  const float* s4_logA = (const float*)d_in[8];
  const float* s4_Aim  = (const float*)d_in[9];
  const float* out_W   = (const float*)d_in[10];
  const float* out_b   = (const float*)d_in[11];
  const float* cd1_W   = (const float*)d_in[12];
  const float* cd1_b   = (const float*)d_in[13];
  const float* cd2_W   = (const float*)d_in[14];
  const float* cd2_b   = (const float*)d_in[15];
  const float* up_W    = (const float*)d_in[16];
  const float* up_b    = (const float*)d_in[17];
  const float* up1_W   = (const float*)d_in[18];
  float* outp = (float*)d_out;

  // ---- workspace arena (~127.2 MB, lifetime-overlapped) ----
  unsigned short* TtG = (unsigned short*)d_ws;
  const size_t ttg_shorts = (size_t)64 * NL_ * 70 * 512;      // 18.35M
  const size_t nWsz = (size_t)NM_ * NL_ * 2 * H_ * H_;        // 1.57M
  unsigned short* oWhi = TtG + ttg_shorts;
  unsigned short* oWlo = oWhi + nWsz;
  unsigned short* eWhi = oWlo + nWsz;
  unsigned short* eWlo = eWhi + 3 * 4096;
  unsigned short* c1hi = eWlo + 3 * 4096;
  unsigned short* c1lo = c1hi + 3 * 4096;
  unsigned short* c2hi = c1lo + 3 * 4096;
  unsigned short* c2lo = c2hi + 2 * 4096;
  unsigned short* uphi = c2lo + 2 * 4096;
  unsigned short* uplo = uphi + 3 * 4096;
  unsigned short* u1hi = uplo + 3 * 4096;
  unsigned short* u1lo = u1hi + 3 * 4096;
  float* slotA = (float*)(u1lo + 3 * 4096);            // B*H*L0 floats
  float* slotB = slotA + (size_t)B_ * H_ * L0_;        // B*H*L0 floats

  // lifetime map (stream-serial, encoders all OUT-OF-PLACE):
  float* enc1  = slotA;                                // B*H*L1
  float* enc2  = slotA + (size_t)B_ * H_ * L1_;        // B*H*L2
  float* st0   = slotB;                                // B*H*L2
  float* scr0  = slotB + (size_t)B_ * H_ * L2_;        // B*H*L2
  float* dec21 = slotB + (size_t)2 * B_ * H_ * L2_;    // B*H*L1 — disjoint from st0
  float* st1   = slotA;                                // B*H*L1 (enc1/enc2 dead)
  float* scr1  = slotA + (size_t)B_ * H_ * L1_;        // B*H*L1
  float* dec32 = slotB;                                // B*H*L0 (st0/dec21 dead)
  float* st2   = slotA;                                // B*H*L0 (st1/scr1 dead)
  float* scr2  = slotB;                                // B*H*L0 (dec32 dead post-enc)

  auto tt_layer = [&](int m, int i) -> const unsigned short* {
    const size_t NTm = (m == 0) ? 10 : (m == 1) ? 20 : 40;
    const size_t base = (m == 0) ? 0 : (m == 1) ? (size_t)64 * NL_ * 10
                                                : (size_t)64 * NL_ * 30;
    return TtG + (base + (size_t)i * 64 * NTm) * 512;
  };

  k_compute_K_tt<<<NM_ * NL_ * H_, 256, 0, stream>>>(s4_ldt, s4_C, s4_logA, s4_Aim, TtG);
  k_pack_w<<<((int)nWsz + 255) / 256, 256, 0, stream>>>(out_W, oWhi, oWlo, (int)nWsz);
  k_pack_w<<<48, 256, 0, stream>>>(enc_W, eWhi, eWlo, 3 * 4096);
  k_pack_gather<<<48, 256, 0, stream>>>(cd1_W, c1hi, c1lo, 3 * 4096, 192, 3);
  k_pack_gather<<<32, 256, 0, stream>>>(cd2_W, c2hi, c2lo, 2 * 4096, 128, 2);
  k_pack_gather<<<48, 256, 0, stream>>>(up_W, uphi, uplo, 3 * 4096, 3, 192);
  k_pack_gather<<<48, 256, 0, stream>>>(up1_W, u1hi, u1lo, 3 * 4096, 3, 192);

  // enc1 = conv_d1(x), enc2 = conv_d2(enc1)
  k_down_mfma<3, 1><<<B_ * (L1_ / 32), 256, 0, stream>>>(c1hi, c1lo, cd1_b, x, enc1,
                                                         L0_, L1_);
  k_down_mfma<2, 0><<<B_ * (L2_ / 32), 256, 0, stream>>>(c2hi, c2lo, cd2_b, enc1, enc2,
                                                         L1_, L2_);

  auto run_model = [&](int m, const float* input, float* state, float* scratch,
                       int Lm, float* final_out) {
    k_enc_mfma<<<B_ * (Lm / 32), 256, 0, stream>>>(eWhi + m * 4096, eWlo + m * 4096,
                                                   enc_b + (size_t)m * H_, input, state, Lm);
    for (int i = 0; i < NL_; ++i) {
      const unsigned short* Tl = tt_layer(m, i);
      const float* Dl = s4_D + ((size_t)m * NL_ + i) * H_;
      const int cgrid = (B_ / 32) * H_;
      if (Lm == L2_)
        k_conv_gelu_mfma<L2_><<<cgrid, 256, 0, stream>>>(state, Tl, Dl, scratch);
      else if (Lm == L1_)
        k_conv_gelu_mfma<L1_><<<cgrid, 256, 0, stream>>>(state, Tl, Dl, scratch);
      else
        k_conv_gelu_mfma<L0_><<<cgrid, 256, 0, stream>>>(state, Tl, Dl, scratch);
      float* obuf = (i == NL_ - 1 && final_out) ? final_out : state;
      const size_t wbase = ((size_t)m * NL_ + i) * 2 * H_ * H_;
      if (Lm == L2_)
        k_glu_ln_mfma2<2><<<B_ * (Lm / 32), 256, 0, stream>>>(
            oWhi + wbase, oWlo + wbase,
            out_b + ((size_t)m * NL_ + i) * 2 * H_,
            ln_g + ((size_t)m * NL_ + i) * H_,
            ln_b + ((size_t)m * NL_ + i) * H_,
            scratch, state, obuf, Lm);
      else
        k_glu_ln_mfma2<4><<<B_ * (Lm / 64), 256, 0, stream>>>(
            oWhi + wbase, oWlo + wbase,
            out_b + ((size_t)m * NL_ + i) * 2 * H_,
            ln_g + ((size_t)m * NL_ + i) * H_,
            ln_b + ((size_t)m * NL_ + i) * H_,
            scratch, state, obuf, Lm);
    }
  };

  // model 0 on enc2 (L=160): encoder out-of-place into st0
  run_model(0, enc2, st0, scr0, L2_, nullptr);
  // dec21 = convT(enc2 + m0out, up_W) + up_b + enc1  (fused add; disjoint)
  k_convT_mfma<<<B_ * (L2_ / 32), 256, 0, stream>>>(uphi, uplo, up_b, enc1, enc2, st0,
                                                    dec21, L2_, 1);
  // model 1 on dec21 (L=320): encoder into st1 (slotA)
  run_model(1, dec21, st1, scr1, L1_, nullptr);
  // dec32 = convT(m1-out, up1_W) + enc0 -> slotB (dec21/st0 dead)
  k_convT_mfma<<<B_ * (L1_ / 32), 256, 0, stream>>>(u1hi, u1lo, up_b, x, st1, nullptr,
                                                    dec32, L1_, 0);
  // model 2 on dec32 (L=640): encoder into st2 (slotA); final layer -> d_out
  run_model(2, dec32, st2, scr2, L0_, outp);
}

// Round 17
// 1008.486 us; speedup vs baseline: 1.2358x; 1.1107x over previous
//
#include <hip/hip_runtime.h>
#include <hip/hip_bf16.h>
#include <math.h>

namespace {

constexpr int B_ = 256, H_ = 64, L0_ = 640, L1_ = 320, L2_ = 160;
constexpr int N2_ = 32, NL_ = 8, NM_ = 3;

typedef __attribute__((ext_vector_type(8))) short bf16x8;
typedef __attribute__((ext_vector_type(4))) float f32x4;

__device__ __forceinline__ unsigned short f2bf(float x) {
  __hip_bfloat16 h = __float2bfloat16(x);
  unsigned short u;
  __builtin_memcpy(&u, &h, 2);
  return u;
}
__device__ __forceinline__ float bf2f(unsigned short h) {
  return __uint_as_float(((unsigned int)h) << 16);
}
__device__ __forceinline__ float gelu_f(float x) {
  const float t = 0.7978845608028654f * (x + 0.044715f * x * x * x);
  return x * __builtin_amdgcn_rcpf(1.f + __expf(-2.f * t));
}
__device__ __forceinline__ void split8(const float* v, bf16x8& hi, bf16x8& lo) {
#pragma unroll
  for (int i = 0; i < 8; ++i) {
    const unsigned short hh = f2bf(v[i]);
    hi[i] = (short)hh;
    lo[i] = (short)f2bf(v[i] - bf2f(hh));
  }
}

// ---------------------------------------------------------------------------
// K + Toeplitz-fragment precompute (spill-free). One block per (m, layer, h).
// ---------------------------------------------------------------------------
__global__ __launch_bounds__(256) void k_compute_K_tt(
    const float* __restrict__ log_dt, const float* __restrict__ C,
    const float* __restrict__ logA, const float* __restrict__ Aim,
    unsigned short* __restrict__ TtG) {
  const int bid = blockIdx.x;
  const int m = bid / (NL_ * H_);
  const int rest = bid % (NL_ * H_);
  const int li = rest / H_;
  const int h = rest % H_;
  const int ph = (m * NL_ + li) * H_ + h;
  __shared__ float qkr[7][N2_], qki[7][N2_];
  __shared__ float sCr[N2_], sCi[N2_];
  __shared__ float Ksh[L0_];
  const int tid = threadIdx.x;
  if (tid < N2_) {
    const int n = tid;
    const float dt = expf(log_dt[ph]);
    const float Are = -expf(logA[(size_t)ph * N2_ + n]);
    const float Ai = Aim[(size_t)ph * N2_ + n];
    const float ar = dt * Are, ai = dt * Ai;
    const float er = expf(ar);
    float sn, cs;
    sincosf(ai, &sn, &cs);
    const float mr = er * cs - 1.f;
    const float mi = er * sn;
    const float den = Are * Are + Ai * Ai;
    const float qr_ = (mr * Are + mi * Ai) / den;
    const float qi_ = (mi * Are - mr * Ai) / den;
    const float C0 = C[((size_t)ph * N2_ + n) * 2 + 0];
    const float C1 = C[((size_t)ph * N2_ + n) * 2 + 1];
    sCr[n] = C0 * qr_ - C1 * qi_;
    sCi[n] = C0 * qi_ + C1 * qr_;
    float qr = er * cs, qi = er * sn;
#pragma unroll
    for (int k = 0; k < 7; ++k) {
      qkr[k][n] = qr;
      qki[k][n] = qi;
      const float nr = qr * qr - qi * qi;
      qi = 2.f * qr * qi;
      qr = nr;
    }
  }
  __syncthreads();
  const int Lm = (m == 0) ? L2_ : (m == 1) ? L1_ : L0_;
  const int NT = Lm / 16;

  const int l0 = tid >> 2;
  const int g = tid & 3;
  float pr[8], pi[8];
#pragma unroll
  for (int j = 0; j < 8; ++j) { pr[j] = 1.f; pi[j] = 0.f; }
#pragma unroll
  for (int k = 0; k < 6; ++k) {
    if ((l0 >> k) & 1) {
#pragma unroll
      for (int j = 0; j < 8; ++j) {
        const int n = g * 8 + j;
        const float qr = qkr[k][n], qi = qki[k][n];
        const float nr = pr[j] * qr - pi[j] * qi;
        pi[j] = pr[j] * qi + pi[j] * qr;
        pr[j] = nr;
      }
    }
  }
  for (int l = l0; l < Lm; l += 64) {
    float acc = 0.f;
#pragma unroll
    for (int j = 0; j < 8; ++j) {
      const int n = g * 8 + j;
      acc += sCr[n] * pr[j] - sCi[n] * pi[j];
    }
    acc += __shfl_xor(acc, 1);
    acc += __shfl_xor(acc, 2);
    if (g == 0) Ksh[l] = 2.f * acc;
    if (l + 64 < Lm) {
#pragma unroll
      for (int j = 0; j < 8; ++j) {
        const int n = g * 8 + j;
        const float qr = qkr[6][n], qi = qki[6][n];
        const float nr = pr[j] * qr - pi[j] * qi;
        pi[j] = pr[j] * qi + pi[j] * qr;
        pr[j] = nr;
      }
    }
  }
  __syncthreads();
  const size_t base_tiles = ((m == 0) ? 0 : (m == 1) ? (size_t)64 * NL_ * 10
                                                     : (size_t)64 * NL_ * 30) +
                            (size_t)li * 64 * NT + (size_t)h * NT;
  unsigned short* Tg = TtG + base_tiles * 512;
  for (int w = tid; w < NT * 256; w += 256) {
    const int nd = w >> 8;
    const int rem = w & 255;
    const int lane = rem >> 2;
    const int pp = rem & 3;
    const int base = nd * 16 + (lane & 15) - ((lane >> 4) << 3) - 2 * pp;
    const float f0 = (base >= 0) ? Ksh[base] : 0.f;
    const float f1 = (base - 1 >= 0) ? Ksh[base - 1] : 0.f;
    *(unsigned int*)&Tg[nd * 512 + lane * 8 + 2 * pp] =
        (unsigned int)f2bf(f0) | ((unsigned int)f2bf(f1) << 16);
  }
}

// ---------------------------------------------------------------------------
// Pack f32 weights -> bf16 hi/lo (identity indexing).
// ---------------------------------------------------------------------------
__global__ void k_pack_w(const float* __restrict__ W, unsigned short* __restrict__ hi,
                         unsigned short* __restrict__ lo, int n) {
  const int p = blockIdx.x * 256 + threadIdx.x;
  if (p < n) {
    const float w = W[p];
    const unsigned short h = f2bf(w);
    hi[p] = h;
    lo[p] = f2bf(w - bf2f(h));
  }
}

// Gather-pack conv weights into P[k][o*64+i] hi/lo. src = o*so + i*si + k.
__global__ void k_pack_gather(const float* __restrict__ W, unsigned short* __restrict__ hi,
                              unsigned short* __restrict__ lo, int n, int so, int si) {
  const int idx = blockIdx.x * 256 + threadIdx.x;
  if (idx < n) {
    const int k = idx >> 12;
    const int rem = idx & 4095;
    const int o = rem >> 6;
    const int i = rem & 63;
    const float w = W[o * so + i * si + k];
    const unsigned short h = f2bf(w);
    hi[idx] = h;
    lo[idx] = f2bf(w - bf2f(h));
  }
}

// ---------------------------------------------------------------------------
// MFMA 1x1 encoder v2: LDS-staged. Block = (b, 32-l tile). OUT-OF-PLACE only.
// ---------------------------------------------------------------------------
__global__ __launch_bounds__(256) void k_enc_mfma(
    const unsigned short* __restrict__ Whi, const unsigned short* __restrict__ Wlo,
    const float* __restrict__ bvec, const float* __restrict__ in_,
    float* __restrict__ out, int Lcur) {
  constexpr int KS = 72;
  __shared__ __align__(16) unsigned short Xhi[32 * KS];
  __shared__ __align__(16) unsigned short Xlo[32 * KS];
  const int tid = threadIdx.x;
  const int w = tid >> 6, lane = tid & 63, c15 = lane & 15, g4 = lane >> 4;
  const int tilesPerB = Lcur >> 5;
  const int b = blockIdx.x / tilesPerB;
  const int l0 = ((blockIdx.x % tilesPerB) << 5);
  const size_t bbase = (size_t)b * H_ * Lcur;

#pragma unroll
  for (int e = 0; e < 8; ++e) {
    const int idx = e * 256 + tid;
    const int ch = idx >> 5;
    const int c = idx & 31;
    const float v = in_[bbase + (size_t)ch * Lcur + l0 + c];
    const unsigned short hh = f2bf(v);
    Xhi[c * KS + ch] = hh;
    Xlo[c * KS + ch] = f2bf(v - bf2f(hh));
  }
  bf16x8 wh[2], wl[2];
#pragma unroll
  for (int q = 0; q < 2; ++q) {
    const int ra = (16 * w + c15) * 64 + q * 32 + 8 * g4;
    wh[q] = *(const bf16x8*)(Whi + ra);
    wl[q] = *(const bf16x8*)(Wlo + ra);
  }
  __syncthreads();

  f32x4 acc[2] = {{0.f, 0.f, 0.f, 0.f}, {0.f, 0.f, 0.f, 0.f}};
#pragma unroll
  for (int lt = 0; lt < 2; ++lt) {
    const int lc = lt * 16 + c15;
#pragma unroll
    for (int q = 0; q < 2; ++q) {
      const int crow = q * 32 + 8 * g4;
      const bf16x8 xh = *(const bf16x8*)&Xhi[lc * KS + crow];
      const bf16x8 xl = *(const bf16x8*)&Xlo[lc * KS + crow];
      acc[lt] = __builtin_amdgcn_mfma_f32_16x16x32_bf16(wh[q], xh, acc[lt], 0, 0, 0);
      acc[lt] = __builtin_amdgcn_mfma_f32_16x16x32_bf16(wh[q], xl, acc[lt], 0, 0, 0);
      acc[lt] = __builtin_amdgcn_mfma_f32_16x16x32_bf16(wl[q], xh, acc[lt], 0, 0, 0);
    }
  }
#pragma unroll
  for (int lt = 0; lt < 2; ++lt) {
#pragma unroll
    for (int r = 0; r < 4; ++r) {
      const int ca = 16 * w + 4 * g4 + r;
      out[bbase + (size_t)ca * Lcur + l0 + lt * 16 + c15] = acc[lt][r] + bvec[ca];
    }
  }
}

// ---------------------------------------------------------------------------
// MFMA strided down-conv v2 (k=KW, s=2, pad=PAD), LDS-staged.
// ---------------------------------------------------------------------------
template <int KW, int PAD>
__global__ __launch_bounds__(256) void k_down_mfma(
    const unsigned short* __restrict__ Phi, const unsigned short* __restrict__ Plo,
    const float* __restrict__ bias, const float* __restrict__ in_,
    float* __restrict__ out, int Lin, int Lout) {
  constexpr int WCOLS = 62 + KW;
  constexpr int KS = 72;
  __shared__ __align__(16) unsigned short Xhi[WCOLS * KS];
  __shared__ __align__(16) unsigned short Xlo[WCOLS * KS];
  const int tid = threadIdx.x;
  const int w = tid >> 6, lane = tid & 63, c15 = lane & 15, g4 = lane >> 4;
  const int tilesPerB = Lout >> 5;
  const int b = blockIdx.x / tilesPerB;
  const int t0 = ((blockIdx.x % tilesPerB) << 5);
  const int c0 = 2 * t0 - PAD;
  const size_t ibase = (size_t)b * H_ * Lin;

  for (int idx = tid; idx < 64 * WCOLS; idx += 256) {
    const int ch = idx / WCOLS;
    const int c = idx % WCOLS;
    const int gc = c0 + c;
    const float v = (gc >= 0 && gc < Lin) ? in_[ibase + (size_t)ch * Lin + gc] : 0.f;
    const unsigned short hh = f2bf(v);
    Xhi[c * KS + ch] = hh;
    Xlo[c * KS + ch] = f2bf(v - bf2f(hh));
  }
  bf16x8 wh[KW][2], wl[KW][2];
#pragma unroll
  for (int k = 0; k < KW; ++k)
#pragma unroll
    for (int q = 0; q < 2; ++q) {
      const int ra = (k << 12) + (16 * w + c15) * 64 + q * 32 + 8 * g4;
      wh[k][q] = *(const bf16x8*)(Phi + ra);
      wl[k][q] = *(const bf16x8*)(Plo + ra);
    }
  __syncthreads();

  f32x4 acc[2] = {{0.f, 0.f, 0.f, 0.f}, {0.f, 0.f, 0.f, 0.f}};
#pragma unroll
  for (int lt = 0; lt < 2; ++lt) {
#pragma unroll
    for (int q = 0; q < 2; ++q) {
      const int crow = q * 32 + 8 * g4;
#pragma unroll
      for (int k = 0; k < KW; ++k) {
        const int lc = 2 * (lt * 16 + c15) + k;
        const bf16x8 xh = *(const bf16x8*)&Xhi[lc * KS + crow];
        const bf16x8 xl = *(const bf16x8*)&Xlo[lc * KS + crow];
        acc[lt] = __builtin_amdgcn_mfma_f32_16x16x32_bf16(wh[k][q], xh, acc[lt], 0, 0, 0);
        acc[lt] = __builtin_amdgcn_mfma_f32_16x16x32_bf16(wh[k][q], xl, acc[lt], 0, 0, 0);
        acc[lt] = __builtin_amdgcn_mfma_f32_16x16x32_bf16(wl[k][q], xh, acc[lt], 0, 0, 0);
      }
    }
  }
  const size_t obase = (size_t)b * H_ * Lout;
#pragma unroll
  for (int lt = 0; lt < 2; ++lt) {
#pragma unroll
    for (int r = 0; r < 4; ++r) {
      const int ca = 16 * w + 4 * g4 + r;
      out[obase + (size_t)ca * Lout + t0 + lt * 16 + c15] = acc[lt][r] + bias[ca];
    }
  }
}

// ---------------------------------------------------------------------------
// MFMA ConvTranspose1d v2 (k=3 s=2 p=1 op=1), LDS-staged; optional fused
// second input. NOTE: out must NOT alias in_/in2/skip.
// ---------------------------------------------------------------------------
__global__ __launch_bounds__(256) void k_convT_mfma(
    const unsigned short* __restrict__ Phi, const unsigned short* __restrict__ Plo,
    const float* __restrict__ bias, const float* __restrict__ skip,
    const float* __restrict__ in_, const float* __restrict__ in2,
    float* __restrict__ out, int Lin, int hasBias) {
  constexpr int WCOLS = 33;
  constexpr int KS = 72;
  __shared__ __align__(16) unsigned short Xhi[WCOLS * KS];
  __shared__ __align__(16) unsigned short Xlo[WCOLS * KS];
  const int tid = threadIdx.x;
  const int w = tid >> 6, lane = tid & 63, c15 = lane & 15, g4 = lane >> 4;
  const int tilesPerB = Lin >> 5;
  const int b = blockIdx.x / tilesPerB;
  const int j0 = ((blockIdx.x % tilesPerB) << 5);
  const int Lout = 2 * Lin;
  const size_t ibase = (size_t)b * H_ * Lin;

  for (int idx = tid; idx < 64 * WCOLS; idx += 256) {
    const int ch = idx / WCOLS;
    const int c = idx % WCOLS;
    const int gc = j0 + c;
    float v = 0.f;
    if (gc < Lin) {
      const size_t p = ibase + (size_t)ch * Lin + gc;
      v = in_[p];
      if (in2) v += in2[p];
    }
    const unsigned short hh = f2bf(v);
    Xhi[c * KS + ch] = hh;
    Xlo[c * KS + ch] = f2bf(v - bf2f(hh));
  }
  bf16x8 wh[3][2], wl[3][2];
#pragma unroll
  for (int k = 0; k < 3; ++k)
#pragma unroll
    for (int q = 0; q < 2; ++q) {
      const int ra = (k << 12) + (16 * w + c15) * 64 + q * 32 + 8 * g4;
      wh[k][q] = *(const bf16x8*)(Phi + ra);
      wl[k][q] = *(const bf16x8*)(Plo + ra);
    }
  __syncthreads();

  f32x4 aE[2] = {{0.f, 0.f, 0.f, 0.f}, {0.f, 0.f, 0.f, 0.f}};
  f32x4 aO[2] = {{0.f, 0.f, 0.f, 0.f}, {0.f, 0.f, 0.f, 0.f}};
#pragma unroll
  for (int lt = 0; lt < 2; ++lt) {
    const int lc = lt * 16 + c15;
#pragma unroll
    for (int q = 0; q < 2; ++q) {
      const int crow = q * 32 + 8 * g4;
      const bf16x8 xjh = *(const bf16x8*)&Xhi[lc * KS + crow];
      const bf16x8 xjl = *(const bf16x8*)&Xlo[lc * KS + crow];
      const bf16x8 xnh = *(const bf16x8*)&Xhi[(lc + 1) * KS + crow];
      const bf16x8 xnl = *(const bf16x8*)&Xlo[(lc + 1) * KS + crow];
      aE[lt] = __builtin_amdgcn_mfma_f32_16x16x32_bf16(wh[1][q], xjh, aE[lt], 0, 0, 0);
      aE[lt] = __builtin_amdgcn_mfma_f32_16x16x32_bf16(wh[1][q], xjl, aE[lt], 0, 0, 0);
      aE[lt] = __builtin_amdgcn_mfma_f32_16x16x32_bf16(wl[1][q], xjh, aE[lt], 0, 0, 0);
      aO[lt] = __builtin_amdgcn_mfma_f32_16x16x32_bf16(wh[2][q], xjh, aO[lt], 0, 0, 0);
      aO[lt] = __builtin_amdgcn_mfma_f32_16x16x32_bf16(wh[2][q], xjl, aO[lt], 0, 0, 0);
      aO[lt] = __builtin_amdgcn_mfma_f32_16x16x32_bf16(wl[2][q], xjh, aO[lt], 0, 0, 0);
      aO[lt] = __builtin_amdgcn_mfma_f32_16x16x32_bf16(wh[0][q], xnh, aO[lt], 0, 0, 0);
      aO[lt] = __builtin_amdgcn_mfma_f32_16x16x32_bf16(wh[0][q], xnl, aO[lt], 0, 0, 0);
      aO[lt] = __builtin_amdgcn_mfma_f32_16x16x32_bf16(wl[0][q], xnh, aO[lt], 0, 0, 0);
    }
  }
  const size_t obase = (size_t)b * H_ * Lout;
#pragma unroll
  for (int lt = 0; lt < 2; ++lt) {
#pragma unroll
    for (int r = 0; r < 4; ++r) {
      const int ca = 16 * w + 4 * g4 + r;
      const float bb = hasBias ? bias[ca] : 0.f;
      const size_t pos = obase + (size_t)ca * Lout + 2 * (j0 + lt * 16 + c15);
      out[pos] = aE[lt][r] + bb + skip[pos];
      out[pos + 1] = aO[lt][r] + bb + skip[pos + 1];
    }
  }
}

// ---------------------------------------------------------------------------
// MFMA causal conv + D-skip + gelu, v7: v6 structure with copy-free depth-1
// prefetch. curB[t] is refilled UNCONDITIONALLY each step with the diagonal
// index clamped to [0, NT-1]: when the true index is out of range, tile t is
// inactive (d0<0 guard) so the register value is dead. Removes the nxtB
// array + 16 movs/selects per step. Same MFMA set/order as v6.
// ---------------------------------------------------------------------------
template <int L>
__global__ __launch_bounds__(256) void k_conv_gelu_mfma(
    const float* __restrict__ u, const unsigned short* __restrict__ Tt,
    const float* __restrict__ D, float* __restrict__ y) {
  constexpr int NT = L / 16;
  constexpr int NG = (NT + 3) / 4;
  constexpr int LP = L + 24;  // 2*LP % 16 == 0 (16B-aligned b128 frags)
  __shared__ unsigned short uhi[32 * LP];

  const int h = blockIdx.x & 63;
  const int b0 = (blockIdx.x >> 6) * 32;
  const int tid = threadIdx.x;

  // stage u (bf16): row = tid>>3 (32 rows), 8 threads per row, float4 loads
  {
    const int row = tid >> 3;
    const int ct = tid & 7;
    const float4* src = (const float4*)(u + ((size_t)(b0 + row) * H_ + h) * L);
#pragma unroll
    for (int c4 = ct; c4 < L / 4; c4 += 8) {
      const float4 v = src[c4];
      const unsigned int p0 = (unsigned int)f2bf(v.x) | ((unsigned int)f2bf(v.y) << 16);
      const unsigned int p1 = (unsigned int)f2bf(v.z) | ((unsigned int)f2bf(v.w) << 16);
      unsigned int* dst = (unsigned int*)&uhi[row * LP + 4 * c4];
      dst[0] = p0;
      dst[1] = p1;
    }
  }
  __syncthreads();

  const int wv = tid >> 6;
  const int lane = tid & 63;
  const float Dh = D[h];
  const int lquad = lane & 15;
  const int lhi = lane >> 4;
  const unsigned short* Th = Tt + (size_t)h * NT * 512 + lane * 8;

  for (int g = wv; g < NG; g += 4) {
    const int t0 = g * 4;
    const int ntile = (NT - t0 < 4) ? (NT - t0) : 4;
    f32x4 acc[2][4];
#pragma unroll
    for (int a = 0; a < 2; ++a)
#pragma unroll
      for (int t = 0; t < 4; ++t) acc[a][t] = (f32x4){0.f, 0.f, 0.f, 0.f};

    // prologue: B-frags for s=0 (tile t uses diag t0+t; clamp keeps in-range)
    bf16x8 curB[4];
#pragma unroll
    for (int t = 0; t < 4; ++t) {
      const int nd0 = (t0 + t < NT) ? (t0 + t) : (NT - 1);
      curB[t] = *(const bf16x8*)(Th + (size_t)nd0 * 512);
    }

    const int nsteps = ((t0 + ntile - 1) * 16) / 32 + 1;
    for (int s = 0; s < nsteps; ++s) {
      const int j0 = 32 * s;
      const int colbase = j0 + (lhi << 3);
      const bf16x8 ah0 = *(const bf16x8*)&uhi[lquad * LP + colbase];
      const bf16x8 ah1 = *(const bf16x8*)&uhi[(16 + lquad) * LP + colbase];
#pragma unroll
      for (int t = 0; t < 4; ++t) {
        if (t >= ntile) break;
        const int d0 = (t0 + t) * 16 - j0;
        if (d0 < 0) continue;  // causal: wave-uniform skip
        acc[0][t] = __builtin_amdgcn_mfma_f32_16x16x32_bf16(ah0, curB[t], acc[0][t], 0, 0, 0);
        acc[1][t] = __builtin_amdgcn_mfma_f32_16x16x32_bf16(ah1, curB[t], acc[1][t], 0, 0, 0);
      }
      // unconditional clamped refill for step s+1 (dead when out of range)
#pragma unroll
      for (int t = 0; t < 4; ++t) {
        int ndn = t0 + t - 2 * (s + 1);
        ndn = ndn < 0 ? 0 : ndn;
        curB[t] = *(const bf16x8*)(Th + (size_t)ndn * 512);
      }
    }
#pragma unroll
    for (int t = 0; t < 4; ++t) {
      if (t >= ntile) break;
      const int l = (t0 + t) * 16 + lquad;
#pragma unroll
      for (int a = 0; a < 2; ++a) {
#pragma unroll
        for (int r = 0; r < 4; ++r) {
          const int row = a * 16 + (lhi << 2) + r;
          const float uv = bf2f(uhi[row * LP + l]);
          const float val = acc[a][t][r] + uv * Dh;
          y[((size_t)(b0 + row) * H_ + h) * L + l] = gelu_f(val);
        }
      }
    }
  }
}

// ---------------------------------------------------------------------------
// MFMA out-proj (64->128) + GLU + residual + LayerNorm, v2 (unchanged).
// ---------------------------------------------------------------------------
template <int LT>
__global__ __launch_bounds__(256) void k_glu_ln_mfma2(
    const unsigned short* __restrict__ Whi, const unsigned short* __restrict__ Wlo,
    const float* __restrict__ ob, const float* __restrict__ lng,
    const float* __restrict__ lnb, const float* __restrict__ ybuf,
    const float* __restrict__ xbuf, float* __restrict__ obuf, int Lcur) {
  constexpr int LTILE = LT * 16;
  constexpr int KS = 72;
  __shared__ __align__(16) unsigned short Yhi[LTILE * KS];
  __shared__ __align__(16) unsigned short Ylo[LTILE * KS];
  __shared__ float red[4][LTILE][2];
  const int tid = threadIdx.x;
  const int w = tid >> 6, lane = tid & 63, c15 = lane & 15, g4 = lane >> 4;
  const int tilesPerB = Lcur / LTILE;
  const int b = blockIdx.x / tilesPerB;
  const int l0 = (blockIdx.x % tilesPerB) * LTILE;
  const size_t bbase = (size_t)b * H_ * Lcur;

  constexpr int NE = (64 * LTILE) / 256;
#pragma unroll
  for (int e = 0; e < NE; ++e) {
    const int idx = e * 256 + tid;
    const int k = idx / LTILE;
    const int l = idx % LTILE;
    const float v = ybuf[bbase + (size_t)k * Lcur + l0 + l];
    const unsigned short hh = f2bf(v);
    Yhi[l * KS + k] = hh;
    Ylo[l * KS + k] = f2bf(v - bf2f(hh));
  }

  bf16x8 wah[2], wal[2], wgh[2], wgl[2];
#pragma unroll
  for (int q = 0; q < 2; ++q) {
    const int crow = q * 32 + 8 * g4;
    const int ra = (16 * w + c15) * 64 + crow;
    const int rg = ((64 + 16 * w) + c15) * 64 + crow;
    wah[q] = *(const bf16x8*)(Whi + ra);
    wal[q] = *(const bf16x8*)(Wlo + ra);
    wgh[q] = *(const bf16x8*)(Whi + rg);
    wgl[q] = *(const bf16x8*)(Wlo + rg);
  }
  __syncthreads();

  float wv[LT][4];
#pragma unroll
  for (int lt = 0; lt < LT; ++lt) {
    const int ll = lt * 16 + c15;
    f32x4 accA = {0.f, 0.f, 0.f, 0.f}, accG = {0.f, 0.f, 0.f, 0.f};
#pragma unroll
    for (int q = 0; q < 2; ++q) {
      const int crow = q * 32 + 8 * g4;
      const bf16x8 yh = *(const bf16x8*)&Yhi[ll * KS + crow];
      const bf16x8 yl = *(const bf16x8*)&Ylo[ll * KS + crow];
      accA = __builtin_amdgcn_mfma_f32_16x16x32_bf16(wah[q], yh, accA, 0, 0, 0);
      accA = __builtin_amdgcn_mfma_f32_16x16x32_bf16(wah[q], yl, accA, 0, 0, 0);
      accA = __builtin_amdgcn_mfma_f32_16x16x32_bf16(wal[q], yh, accA, 0, 0, 0);
      accG = __builtin_amdgcn_mfma_f32_16x16x32_bf16(wgh[q], yh, accG, 0, 0, 0);
      accG = __builtin_amdgcn_mfma_f32_16x16x32_bf16(wgh[q], yl, accG, 0, 0, 0);
      accG = __builtin_amdgcn_mfma_f32_16x16x32_bf16(wgl[q], yh, accG, 0, 0, 0);
    }
    float s1 = 0.f, s2 = 0.f;
#pragma unroll
    for (int r = 0; r < 4; ++r) {
      const int ca = 16 * w + 4 * g4 + r;
      const float a = accA[r] + ob[ca];
      const float g = accG[r] + ob[H_ + ca];
      const float z = a / (1.f + expf(-g));
      const float xv = xbuf[bbase + (size_t)ca * Lcur + l0 + ll];
      wv[lt][r] = z + xv;
      s1 += wv[lt][r];
      s2 += wv[lt][r] * wv[lt][r];
    }
    s1 += __shfl_xor(s1, 16);
    s2 += __shfl_xor(s2, 16);
    s1 += __shfl_xor(s1, 32);
    s2 += __shfl_xor(s2, 32);
    if (g4 == 0) {
      red[w][ll][0] = s1;
      red[w][ll][1] = s2;
    }
  }
  __syncthreads();
#pragma unroll
  for (int lt = 0; lt < LT; ++lt) {
    const int ll = lt * 16 + c15;
    float t1 = 0.f, t2 = 0.f;
#pragma unroll
    for (int q = 0; q < 4; ++q) {
      t1 += red[q][ll][0];
      t2 += red[q][ll][1];
    }
    const float mean = t1 * (1.f / 64.f);
    const float var = t2 * (1.f / 64.f) - mean * mean;
    const float rstd = rsqrtf(var + 1e-5f);
#pragma unroll
    for (int r = 0; r < 4; ++r) {
      const int ca = 16 * w + 4 * g4 + r;
      obuf[bbase + (size_t)ca * Lcur + l0 + ll] =
          (wv[lt][r] - mean) * rstd * lng[ca] + lnb[ca];
    }
  }
}

}  // namespace

// ---------------------------------------------------------------------------
extern "C" void kernel_launch(void* const* d_in, const int* in_sizes, int n_in,
                              void* d_out, int out_size, void* d_ws, size_t ws_size,
                              hipStream_t stream) {
  const float* x       = (const float*)d_in[0];
  const float* enc_W   = (const float*)d_in[1];
  const float* enc_b   = (const float*)d_in[2];
  const float* ln_g    = (const float*)d_in[3];
  const float* ln_b    = (const float*)d_in[4];
  const float* s4_D    = (const float*)d_in[5];
  const float* s4_ldt  = (const float*)d_in[6];
  const float* s4_C    = (const float*)d_in[7];
  const float* s4_logA = (const float*)d_in[8];
  const float* s4_Aim  = (const float*)d_in[9];
  const float* out_W   = (const float*)d_in[10];
  const float* out_b   = (const float*)d_in[11];
  const float* cd1_W   = (const float*)d_in[12];
  const float* cd1_b   = (const float*)d_in[13];
  const float* cd2_W   = (const float*)d_in[14];
  const float* cd2_b   = (const float*)d_in[15];
  const float* up_W    = (const float*)d_in[16];
  const float* up_b    = (const float*)d_in[17];
  const float* up1_W   = (const float*)d_in[18];
  float* outp = (float*)d_out;

  // ---- workspace arena (~127.2 MB, lifetime-overlapped) ----
  unsigned short* TtG = (unsigned short*)d_ws;
  const size_t ttg_shorts = (size_t)64 * NL_ * 70 * 512;      // 18.35M
  const size_t nWsz = (size_t)NM_ * NL_ * 2 * H_ * H_;        // 1.57M
  unsigned short* oWhi = TtG + ttg_shorts;
  unsigned short* oWlo = oWhi + nWsz;
  unsigned short* eWhi = oWlo + nWsz;
  unsigned short* eWlo = eWhi + 3 * 4096;
  unsigned short* c1hi = eWlo + 3 * 4096;
  unsigned short* c1lo = c1hi + 3 * 4096;
  unsigned short* c2hi = c1lo + 3 * 4096;
  unsigned short* c2lo = c2hi + 2 * 4096;
  unsigned short* uphi = c2lo + 2 * 4096;
  unsigned short* uplo = uphi + 3 * 4096;
  unsigned short* u1hi = uplo + 3 * 4096;
  unsigned short* u1lo = u1hi + 3 * 4096;
  float* slotA = (float*)(u1lo + 3 * 4096);            // B*H*L0 floats
  float* slotB = slotA + (size_t)B_ * H_ * L0_;        // B*H*L0 floats

  // lifetime map (stream-serial, encoders all OUT-OF-PLACE):
  float* enc1  = slotA;                                // B*H*L1
  float* enc2  = slotA + (size_t)B_ * H_ * L1_;        // B*H*L2
  float* st0   = slotB;                                // B*H*L2
  float* scr0  = slotB + (size_t)B_ * H_ * L2_;        // B*H*L2
  float* dec21 = slotB + (size_t)2 * B_ * H_ * L2_;    // B*H*L1 — disjoint from st0
  float* st1   = slotA;                                // B*H*L1 (enc1/enc2 dead)
  float* scr1  = slotA + (size_t)B_ * H_ * L1_;        // B*H*L1
  float* dec32 = slotB;                                // B*H*L0 (st0/dec21 dead)
  float* st2   = slotA;                                // B*H*L0 (st1/scr1 dead)
  float* scr2  = slotB;                                // B*H*L0 (dec32 dead post-enc)

  auto tt_layer = [&](int m, int i) -> const unsigned short* {
    const size_t NTm = (m == 0) ? 10 : (m == 1) ? 20 : 40;
    const size_t base = (m == 0) ? 0 : (m == 1) ? (size_t)64 * NL_ * 10
                                                : (size_t)64 * NL_ * 30;
    return TtG + (base + (size_t)i * 64 * NTm) * 512;
  };

  k_compute_K_tt<<<NM_ * NL_ * H_, 256, 0, stream>>>(s4_ldt, s4_C, s4_logA, s4_Aim, TtG);
  k_pack_w<<<((int)nWsz + 255) / 256, 256, 0, stream>>>(out_W, oWhi, oWlo, (int)nWsz);
  k_pack_w<<<48, 256, 0, stream>>>(enc_W, eWhi, eWlo, 3 * 4096);
  k_pack_gather<<<48, 256, 0, stream>>>(cd1_W, c1hi, c1lo, 3 * 4096, 192, 3);
  k_pack_gather<<<32, 256, 0, stream>>>(cd2_W, c2hi, c2lo, 2 * 4096, 128, 2);
  k_pack_gather<<<48, 256, 0, stream>>>(up_W, uphi, uplo, 3 * 4096, 3, 192);
  k_pack_gather<<<48, 256, 0, stream>>>(up1_W, u1hi, u1lo, 3 * 4096, 3, 192);

  // enc1 = conv_d1(x), enc2 = conv_d2(enc1)
  k_down_mfma<3, 1><<<B_ * (L1_ / 32), 256, 0, stream>>>(c1hi, c1lo, cd1_b, x, enc1,
                                                         L0_, L1_);
  k_down_mfma<2, 0><<<B_ * (L2_ / 32), 256, 0, stream>>>(c2hi, c2lo, cd2_b, enc1, enc2,
                                                         L1_, L2_);

  auto run_model = [&](int m, const float* input, float* state, float* scratch,
                       int Lm, float* final_out) {
    k_enc_mfma<<<B_ * (Lm / 32), 256, 0, stream>>>(eWhi + m * 4096, eWlo + m * 4096,
                                                   enc_b + (size_t)m * H_, input, state, Lm);
    for (int i = 0; i < NL_; ++i) {
      const unsigned short* Tl = tt_layer(m, i);
      const float* Dl = s4_D + ((size_t)m * NL_ + i) * H_;
      const int cgrid = (B_ / 32) * H_;
      if (Lm == L2_)
        k_conv_gelu_mfma<L2_><<<cgrid, 256, 0, stream>>>(state, Tl, Dl, scratch);
      else if (Lm == L1_)
        k_conv_gelu_mfma<L1_><<<cgrid, 256, 0, stream>>>(state, Tl, Dl, scratch);
      else
        k_conv_gelu_mfma<L0_><<<cgrid, 256, 0, stream>>>(state, Tl, Dl, scratch);
      float* obuf = (i == NL_ - 1 && final_out) ? final_out : state;
      const size_t wbase = ((size_t)m * NL_ + i) * 2 * H_ * H_;
      if (Lm == L2_)
        k_glu_ln_mfma2<2><<<B_ * (Lm / 32), 256, 0, stream>>>(
            oWhi + wbase, oWlo + wbase,
            out_b + ((size_t)m * NL_ + i) * 2 * H_,
            ln_g + ((size_t)m * NL_ + i) * H_,
            ln_b + ((size_t)m * NL_ + i) * H_,
            scratch, state, obuf, Lm);
      else
        k_glu_ln_mfma2<4><<<B_ * (Lm / 64), 256, 0, stream>>>(
            oWhi + wbase, oWlo + wbase,
            out_b + ((size_t)m * NL_ + i) * 2 * H_,
            ln_g + ((size_t)m * NL_ + i) * H_,
            ln_b + ((size_t)m * NL_ + i) * H_,
            scratch, state, obuf, Lm);
    }
  };

  // model 0 on enc2 (L=160): encoder out-of-place into st0
  run_model(0, enc2, st0, scr0, L2_, nullptr);
  // dec21 = convT(enc2 + m0out, up_W) + up_b + enc1  (fused add; disjoint)
  k_convT_mfma<<<B_ * (L2_ / 32), 256, 0, stream>>>(uphi, uplo, up_b, enc1, enc2, st0,
                                                    dec21, L2_, 1);
  // model 1 on dec21 (L=320): encoder into st1 (slotA)
  run_model(1, dec21, st1, scr1, L1_, nullptr);
  // dec32 = convT(m1-out, up1_W) + enc0 -> slotB (dec21/st0 dead)
  k_convT_mfma<<<B_ * (L1_ / 32), 256, 0, stream>>>(u1hi, u1lo, up_b, x, st1, nullptr,
                                                    dec32, L1_, 0);
  // model 2 on dec32 (L=640): encoder into st2 (slotA); final layer -> d_out
  run_model(2, dec32, st2, scr2, L0_, outp);
}

// Round 18
// 954.766 us; speedup vs baseline: 1.3053x; 1.0563x over previous
//
#include <hip/hip_runtime.h>
#include <hip/hip_bf16.h>
#include <math.h>

namespace {

constexpr int B_ = 256, H_ = 64, L0_ = 640, L1_ = 320, L2_ = 160;
constexpr int N2_ = 32, NL_ = 8, NM_ = 3;

typedef __attribute__((ext_vector_type(8))) short bf16x8;
typedef __attribute__((ext_vector_type(4))) float f32x4;

__device__ __forceinline__ unsigned short f2bf(float x) {
  __hip_bfloat16 h = __float2bfloat16(x);
  unsigned short u;
  __builtin_memcpy(&u, &h, 2);
  return u;
}
__device__ __forceinline__ float bf2f(unsigned short h) {
  return __uint_as_float(((unsigned int)h) << 16);
}
__device__ __forceinline__ float gelu_f(float x) {
  const float t = 0.7978845608028654f * (x + 0.044715f * x * x * x);
  return x * __builtin_amdgcn_rcpf(1.f + __expf(-2.f * t));
}

// ---------------------------------------------------------------------------
// K + Toeplitz-fragment precompute (spill-free). One block per (m, layer, h).
// ---------------------------------------------------------------------------
__global__ __launch_bounds__(256) void k_compute_K_tt(
    const float* __restrict__ log_dt, const float* __restrict__ C,
    const float* __restrict__ logA, const float* __restrict__ Aim,
    unsigned short* __restrict__ TtG) {
  const int bid = blockIdx.x;
  const int m = bid / (NL_ * H_);
  const int rest = bid % (NL_ * H_);
  const int li = rest / H_;
  const int h = rest % H_;
  const int ph = (m * NL_ + li) * H_ + h;
  __shared__ float qkr[7][N2_], qki[7][N2_];
  __shared__ float sCr[N2_], sCi[N2_];
  __shared__ float Ksh[L0_];
  const int tid = threadIdx.x;
  if (tid < N2_) {
    const int n = tid;
    const float dt = expf(log_dt[ph]);
    const float Are = -expf(logA[(size_t)ph * N2_ + n]);
    const float Ai = Aim[(size_t)ph * N2_ + n];
    const float ar = dt * Are, ai = dt * Ai;
    const float er = expf(ar);
    float sn, cs;
    sincosf(ai, &sn, &cs);
    const float mr = er * cs - 1.f;
    const float mi = er * sn;
    const float den = Are * Are + Ai * Ai;
    const float qr_ = (mr * Are + mi * Ai) / den;
    const float qi_ = (mi * Are - mr * Ai) / den;
    const float C0 = C[((size_t)ph * N2_ + n) * 2 + 0];
    const float C1 = C[((size_t)ph * N2_ + n) * 2 + 1];
    sCr[n] = C0 * qr_ - C1 * qi_;
    sCi[n] = C0 * qi_ + C1 * qr_;
    float qr = er * cs, qi = er * sn;
#pragma unroll
    for (int k = 0; k < 7; ++k) {
      qkr[k][n] = qr;
      qki[k][n] = qi;
      const float nr = qr * qr - qi * qi;
      qi = 2.f * qr * qi;
      qr = nr;
    }
  }
  __syncthreads();
  const int Lm = (m == 0) ? L2_ : (m == 1) ? L1_ : L0_;
  const int NT = Lm / 16;

  const int l0 = tid >> 2;
  const int g = tid & 3;
  float pr[8], pi[8];
#pragma unroll
  for (int j = 0; j < 8; ++j) { pr[j] = 1.f; pi[j] = 0.f; }
#pragma unroll
  for (int k = 0; k < 6; ++k) {
    if ((l0 >> k) & 1) {
#pragma unroll
      for (int j = 0; j < 8; ++j) {
        const int n = g * 8 + j;
        const float qr = qkr[k][n], qi = qki[k][n];
        const float nr = pr[j] * qr - pi[j] * qi;
        pi[j] = pr[j] * qi + pi[j] * qr;
        pr[j] = nr;
      }
    }
  }
  for (int l = l0; l < Lm; l += 64) {
    float acc = 0.f;
#pragma unroll
    for (int j = 0; j < 8; ++j) {
      const int n = g * 8 + j;
      acc += sCr[n] * pr[j] - sCi[n] * pi[j];
    }
    acc += __shfl_xor(acc, 1);
    acc += __shfl_xor(acc, 2);
    if (g == 0) Ksh[l] = 2.f * acc;
    if (l + 64 < Lm) {
#pragma unroll
      for (int j = 0; j < 8; ++j) {
        const int n = g * 8 + j;
        const float qr = qkr[6][n], qi = qki[6][n];
        const float nr = pr[j] * qr - pi[j] * qi;
        pi[j] = pr[j] * qi + pi[j] * qr;
        pr[j] = nr;
      }
    }
  }
  __syncthreads();
  const size_t base_tiles = ((m == 0) ? 0 : (m == 1) ? (size_t)64 * NL_ * 10
                                                     : (size_t)64 * NL_ * 30) +
                            (size_t)li * 64 * NT + (size_t)h * NT;
  unsigned short* Tg = TtG + base_tiles * 512;
  for (int w = tid; w < NT * 256; w += 256) {
    const int nd = w >> 8;
    const int rem = w & 255;
    const int lane = rem >> 2;
    const int pp = rem & 3;
    const int base = nd * 16 + (lane & 15) - ((lane >> 4) << 3) - 2 * pp;
    const float f0 = (base >= 0) ? Ksh[base] : 0.f;
    const float f1 = (base - 1 >= 0) ? Ksh[base - 1] : 0.f;
    *(unsigned int*)&Tg[nd * 512 + lane * 8 + 2 * pp] =
        (unsigned int)f2bf(f0) | ((unsigned int)f2bf(f1) << 16);
  }
}

// ---------------------------------------------------------------------------
// Pack f32 weights -> bf16 hi/lo (identity indexing).
// ---------------------------------------------------------------------------
__global__ void k_pack_w(const float* __restrict__ W, unsigned short* __restrict__ hi,
                         unsigned short* __restrict__ lo, int n) {
  const int p = blockIdx.x * 256 + threadIdx.x;
  if (p < n) {
    const float w = W[p];
    const unsigned short h = f2bf(w);
    hi[p] = h;
    lo[p] = f2bf(w - bf2f(h));
  }
}

// Gather-pack conv weights into P[k][o*64+i] hi/lo. src = o*so + i*si + k.
__global__ void k_pack_gather(const float* __restrict__ W, unsigned short* __restrict__ hi,
                              unsigned short* __restrict__ lo, int n, int so, int si) {
  const int idx = blockIdx.x * 256 + threadIdx.x;
  if (idx < n) {
    const int k = idx >> 12;
    const int rem = idx & 4095;
    const int o = rem >> 6;
    const int i = rem & 63;
    const float w = W[o * so + i * si + k];
    const unsigned short h = f2bf(w);
    hi[idx] = h;
    lo[idx] = f2bf(w - bf2f(h));
  }
}

// ---------------------------------------------------------------------------
// MFMA 1x1 encoder v2: LDS-staged. Block = (b, 32-l tile). OUT-OF-PLACE only.
// ---------------------------------------------------------------------------
__global__ __launch_bounds__(256) void k_enc_mfma(
    const unsigned short* __restrict__ Whi, const unsigned short* __restrict__ Wlo,
    const float* __restrict__ bvec, const float* __restrict__ in_,
    float* __restrict__ out, int Lcur) {
  constexpr int KS = 72;
  __shared__ __align__(16) unsigned short Xhi[32 * KS];
  __shared__ __align__(16) unsigned short Xlo[32 * KS];
  const int tid = threadIdx.x;
  const int w = tid >> 6, lane = tid & 63, c15 = lane & 15, g4 = lane >> 4;
  const int tilesPerB = Lcur >> 5;
  const int b = blockIdx.x / tilesPerB;
  const int l0 = ((blockIdx.x % tilesPerB) << 5);
  const size_t bbase = (size_t)b * H_ * Lcur;

#pragma unroll
  for (int e = 0; e < 8; ++e) {
    const int idx = e * 256 + tid;
    const int ch = idx >> 5;
    const int c = idx & 31;
    const float v = in_[bbase + (size_t)ch * Lcur + l0 + c];
    const unsigned short hh = f2bf(v);
    Xhi[c * KS + ch] = hh;
    Xlo[c * KS + ch] = f2bf(v - bf2f(hh));
  }
  bf16x8 wh[2], wl[2];
#pragma unroll
  for (int q = 0; q < 2; ++q) {
    const int ra = (16 * w + c15) * 64 + q * 32 + 8 * g4;
    wh[q] = *(const bf16x8*)(Whi + ra);
    wl[q] = *(const bf16x8*)(Wlo + ra);
  }
  __syncthreads();

  f32x4 acc[2] = {{0.f, 0.f, 0.f, 0.f}, {0.f, 0.f, 0.f, 0.f}};
#pragma unroll
  for (int lt = 0; lt < 2; ++lt) {
    const int lc = lt * 16 + c15;
#pragma unroll
    for (int q = 0; q < 2; ++q) {
      const int crow = q * 32 + 8 * g4;
      const bf16x8 xh = *(const bf16x8*)&Xhi[lc * KS + crow];
      const bf16x8 xl = *(const bf16x8*)&Xlo[lc * KS + crow];
      acc[lt] = __builtin_amdgcn_mfma_f32_16x16x32_bf16(wh[q], xh, acc[lt], 0, 0, 0);
      acc[lt] = __builtin_amdgcn_mfma_f32_16x16x32_bf16(wh[q], xl, acc[lt], 0, 0, 0);
      acc[lt] = __builtin_amdgcn_mfma_f32_16x16x32_bf16(wl[q], xh, acc[lt], 0, 0, 0);
    }
  }
#pragma unroll
  for (int lt = 0; lt < 2; ++lt) {
#pragma unroll
    for (int r = 0; r < 4; ++r) {
      const int ca = 16 * w + 4 * g4 + r;
      out[bbase + (size_t)ca * Lcur + l0 + lt * 16 + c15] = acc[lt][r] + bvec[ca];
    }
  }
}

// ---------------------------------------------------------------------------
// MFMA strided down-conv v2 (k=KW, s=2, pad=PAD), LDS-staged.
// ---------------------------------------------------------------------------
template <int KW, int PAD>
__global__ __launch_bounds__(256) void k_down_mfma(
    const unsigned short* __restrict__ Phi, const unsigned short* __restrict__ Plo,
    const float* __restrict__ bias, const float* __restrict__ in_,
    float* __restrict__ out, int Lin, int Lout) {
  constexpr int WCOLS = 62 + KW;
  constexpr int KS = 72;
  __shared__ __align__(16) unsigned short Xhi[WCOLS * KS];
  __shared__ __align__(16) unsigned short Xlo[WCOLS * KS];
  const int tid = threadIdx.x;
  const int w = tid >> 6, lane = tid & 63, c15 = lane & 15, g4 = lane >> 4;
  const int tilesPerB = Lout >> 5;
  const int b = blockIdx.x / tilesPerB;
  const int t0 = ((blockIdx.x % tilesPerB) << 5);
  const int c0 = 2 * t0 - PAD;
  const size_t ibase = (size_t)b * H_ * Lin;

  for (int idx = tid; idx < 64 * WCOLS; idx += 256) {
    const int ch = idx / WCOLS;
    const int c = idx % WCOLS;
    const int gc = c0 + c;
    const float v = (gc >= 0 && gc < Lin) ? in_[ibase + (size_t)ch * Lin + gc] : 0.f;
    const unsigned short hh = f2bf(v);
    Xhi[c * KS + ch] = hh;
    Xlo[c * KS + ch] = f2bf(v - bf2f(hh));
  }
  bf16x8 wh[KW][2], wl[KW][2];
#pragma unroll
  for (int k = 0; k < KW; ++k)
#pragma unroll
    for (int q = 0; q < 2; ++q) {
      const int ra = (k << 12) + (16 * w + c15) * 64 + q * 32 + 8 * g4;
      wh[k][q] = *(const bf16x8*)(Phi + ra);
      wl[k][q] = *(const bf16x8*)(Plo + ra);
    }
  __syncthreads();

  f32x4 acc[2] = {{0.f, 0.f, 0.f, 0.f}, {0.f, 0.f, 0.f, 0.f}};
#pragma unroll
  for (int lt = 0; lt < 2; ++lt) {
#pragma unroll
    for (int q = 0; q < 2; ++q) {
      const int crow = q * 32 + 8 * g4;
#pragma unroll
      for (int k = 0; k < KW; ++k) {
        const int lc = 2 * (lt * 16 + c15) + k;
        const bf16x8 xh = *(const bf16x8*)&Xhi[lc * KS + crow];
        const bf16x8 xl = *(const bf16x8*)&Xlo[lc * KS + crow];
        acc[lt] = __builtin_amdgcn_mfma_f32_16x16x32_bf16(wh[k][q], xh, acc[lt], 0, 0, 0);
        acc[lt] = __builtin_amdgcn_mfma_f32_16x16x32_bf16(wh[k][q], xl, acc[lt], 0, 0, 0);
        acc[lt] = __builtin_amdgcn_mfma_f32_16x16x32_bf16(wl[k][q], xh, acc[lt], 0, 0, 0);
      }
    }
  }
  const size_t obase = (size_t)b * H_ * Lout;
#pragma unroll
  for (int lt = 0; lt < 2; ++lt) {
#pragma unroll
    for (int r = 0; r < 4; ++r) {
      const int ca = 16 * w + 4 * g4 + r;
      out[obase + (size_t)ca * Lout + t0 + lt * 16 + c15] = acc[lt][r] + bias[ca];
    }
  }
}

// ---------------------------------------------------------------------------
// MFMA ConvTranspose1d v2 (k=3 s=2 p=1 op=1), LDS-staged; optional fused
// second input. NOTE: out must NOT alias in_/in2/skip.
// ---------------------------------------------------------------------------
__global__ __launch_bounds__(256) void k_convT_mfma(
    const unsigned short* __restrict__ Phi, const unsigned short* __restrict__ Plo,
    const float* __restrict__ bias, const float* __restrict__ skip,
    const float* __restrict__ in_, const float* __restrict__ in2,
    float* __restrict__ out, int Lin, int hasBias) {
  constexpr int WCOLS = 33;
  constexpr int KS = 72;
  __shared__ __align__(16) unsigned short Xhi[WCOLS * KS];
  __shared__ __align__(16) unsigned short Xlo[WCOLS * KS];
  const int tid = threadIdx.x;
  const int w = tid >> 6, lane = tid & 63, c15 = lane & 15, g4 = lane >> 4;
  const int tilesPerB = Lin >> 5;
  const int b = blockIdx.x / tilesPerB;
  const int j0 = ((blockIdx.x % tilesPerB) << 5);
  const int Lout = 2 * Lin;
  const size_t ibase = (size_t)b * H_ * Lin;

  for (int idx = tid; idx < 64 * WCOLS; idx += 256) {
    const int ch = idx / WCOLS;
    const int c = idx % WCOLS;
    const int gc = j0 + c;
    float v = 0.f;
    if (gc < Lin) {
      const size_t p = ibase + (size_t)ch * Lin + gc;
      v = in_[p];
      if (in2) v += in2[p];
    }
    const unsigned short hh = f2bf(v);
    Xhi[c * KS + ch] = hh;
    Xlo[c * KS + ch] = f2bf(v - bf2f(hh));
  }
  bf16x8 wh[3][2], wl[3][2];
#pragma unroll
  for (int k = 0; k < 3; ++k)
#pragma unroll
    for (int q = 0; q < 2; ++q) {
      const int ra = (k << 12) + (16 * w + c15) * 64 + q * 32 + 8 * g4;
      wh[k][q] = *(const bf16x8*)(Phi + ra);
      wl[k][q] = *(const bf16x8*)(Plo + ra);
    }
  __syncthreads();

  f32x4 aE[2] = {{0.f, 0.f, 0.f, 0.f}, {0.f, 0.f, 0.f, 0.f}};
  f32x4 aO[2] = {{0.f, 0.f, 0.f, 0.f}, {0.f, 0.f, 0.f, 0.f}};
#pragma unroll
  for (int lt = 0; lt < 2; ++lt) {
    const int lc = lt * 16 + c15;
#pragma unroll
    for (int q = 0; q < 2; ++q) {
      const int crow = q * 32 + 8 * g4;
      const bf16x8 xjh = *(const bf16x8*)&Xhi[lc * KS + crow];
      const bf16x8 xjl = *(const bf16x8*)&Xlo[lc * KS + crow];
      const bf16x8 xnh = *(const bf16x8*)&Xhi[(lc + 1) * KS + crow];
      const bf16x8 xnl = *(const bf16x8*)&Xlo[(lc + 1) * KS + crow];
      aE[lt] = __builtin_amdgcn_mfma_f32_16x16x32_bf16(wh[1][q], xjh, aE[lt], 0, 0, 0);
      aE[lt] = __builtin_amdgcn_mfma_f32_16x16x32_bf16(wh[1][q], xjl, aE[lt], 0, 0, 0);
      aE[lt] = __builtin_amdgcn_mfma_f32_16x16x32_bf16(wl[1][q], xjh, aE[lt], 0, 0, 0);
      aO[lt] = __builtin_amdgcn_mfma_f32_16x16x32_bf16(wh[2][q], xjh, aO[lt], 0, 0, 0);
      aO[lt] = __builtin_amdgcn_mfma_f32_16x16x32_bf16(wh[2][q], xjl, aO[lt], 0, 0, 0);
      aO[lt] = __builtin_amdgcn_mfma_f32_16x16x32_bf16(wl[2][q], xjh, aO[lt], 0, 0, 0);
      aO[lt] = __builtin_amdgcn_mfma_f32_16x16x32_bf16(wh[0][q], xnh, aO[lt], 0, 0, 0);
      aO[lt] = __builtin_amdgcn_mfma_f32_16x16x32_bf16(wh[0][q], xnl, aO[lt], 0, 0, 0);
      aO[lt] = __builtin_amdgcn_mfma_f32_16x16x32_bf16(wl[0][q], xnh, aO[lt], 0, 0, 0);
    }
  }
  const size_t obase = (size_t)b * H_ * Lout;
#pragma unroll
  for (int lt = 0; lt < 2; ++lt) {
#pragma unroll
    for (int r = 0; r < 4; ++r) {
      const int ca = 16 * w + 4 * g4 + r;
      const float bb = hasBias ? bias[ca] : 0.f;
      const size_t pos = obase + (size_t)ca * Lout + 2 * (j0 + lt * 16 + c15);
      out[pos] = aE[lt][r] + bb + skip[pos];
      out[pos + 1] = aO[lt][r] + bb + skip[pos + 1];
    }
  }
}

// ---------------------------------------------------------------------------
// MFMA causal conv + D-skip + gelu, v8: v7 + bf16 OUTPUT (scratch path).
// y is written as bf16 — it is consumed one kernel later as an MFMA input,
// so pre-quantizing here saves half the scratch traffic. Same MFMA math.
// ---------------------------------------------------------------------------
template <int L>
__global__ __launch_bounds__(256) void k_conv_gelu_mfma(
    const float* __restrict__ u, const unsigned short* __restrict__ Tt,
    const float* __restrict__ D, unsigned short* __restrict__ y) {
  constexpr int NT = L / 16;
  constexpr int NG = (NT + 3) / 4;
  constexpr int LP = L + 24;  // 2*LP % 16 == 0 (16B-aligned b128 frags)
  __shared__ unsigned short uhi[32 * LP];

  const int h = blockIdx.x & 63;
  const int b0 = (blockIdx.x >> 6) * 32;
  const int tid = threadIdx.x;

  // stage u (bf16): row = tid>>3 (32 rows), 8 threads per row, float4 loads
  {
    const int row = tid >> 3;
    const int ct = tid & 7;
    const float4* src = (const float4*)(u + ((size_t)(b0 + row) * H_ + h) * L);
#pragma unroll
    for (int c4 = ct; c4 < L / 4; c4 += 8) {
      const float4 v = src[c4];
      const unsigned int p0 = (unsigned int)f2bf(v.x) | ((unsigned int)f2bf(v.y) << 16);
      const unsigned int p1 = (unsigned int)f2bf(v.z) | ((unsigned int)f2bf(v.w) << 16);
      unsigned int* dst = (unsigned int*)&uhi[row * LP + 4 * c4];
      dst[0] = p0;
      dst[1] = p1;
    }
  }
  __syncthreads();

  const int wv = tid >> 6;
  const int lane = tid & 63;
  const float Dh = D[h];
  const int lquad = lane & 15;
  const int lhi = lane >> 4;
  const unsigned short* Th = Tt + (size_t)h * NT * 512 + lane * 8;

  for (int g = wv; g < NG; g += 4) {
    const int t0 = g * 4;
    const int ntile = (NT - t0 < 4) ? (NT - t0) : 4;
    f32x4 acc[2][4];
#pragma unroll
    for (int a = 0; a < 2; ++a)
#pragma unroll
      for (int t = 0; t < 4; ++t) acc[a][t] = (f32x4){0.f, 0.f, 0.f, 0.f};

    bf16x8 curB[4];
#pragma unroll
    for (int t = 0; t < 4; ++t) {
      const int nd0 = (t0 + t < NT) ? (t0 + t) : (NT - 1);
      curB[t] = *(const bf16x8*)(Th + (size_t)nd0 * 512);
    }

    const int nsteps = ((t0 + ntile - 1) * 16) / 32 + 1;
    for (int s = 0; s < nsteps; ++s) {
      const int j0 = 32 * s;
      const int colbase = j0 + (lhi << 3);
      const bf16x8 ah0 = *(const bf16x8*)&uhi[lquad * LP + colbase];
      const bf16x8 ah1 = *(const bf16x8*)&uhi[(16 + lquad) * LP + colbase];
#pragma unroll
      for (int t = 0; t < 4; ++t) {
        if (t >= ntile) break;
        const int d0 = (t0 + t) * 16 - j0;
        if (d0 < 0) continue;  // causal: wave-uniform skip
        acc[0][t] = __builtin_amdgcn_mfma_f32_16x16x32_bf16(ah0, curB[t], acc[0][t], 0, 0, 0);
        acc[1][t] = __builtin_amdgcn_mfma_f32_16x16x32_bf16(ah1, curB[t], acc[1][t], 0, 0, 0);
      }
      // unconditional clamped refill for step s+1 (dead when out of range)
#pragma unroll
      for (int t = 0; t < 4; ++t) {
        int ndn = t0 + t - 2 * (s + 1);
        ndn = ndn < 0 ? 0 : ndn;
        curB[t] = *(const bf16x8*)(Th + (size_t)ndn * 512);
      }
    }
#pragma unroll
    for (int t = 0; t < 4; ++t) {
      if (t >= ntile) break;
      const int l = (t0 + t) * 16 + lquad;
#pragma unroll
      for (int a = 0; a < 2; ++a) {
#pragma unroll
        for (int r = 0; r < 4; ++r) {
          const int row = a * 16 + (lhi << 2) + r;
          const float uv = bf2f(uhi[row * LP + l]);
          const float val = acc[a][t][r] + uv * Dh;
          y[((size_t)(b0 + row) * H_ + h) * L + l] = f2bf(gelu_f(val));
        }
      }
    }
  }
}

// ---------------------------------------------------------------------------
// MFMA out-proj (64->128) + GLU + residual + LayerNorm, v3: bf16 Y input.
// Y is already bf16 (conv output) -> staging is a pure transpose copy, no
// Ylo array (LDS halved), and 2 MFMAs per W-frag pair (W_hi*y + W_lo*y).
// Residual x stays f32. In-place safe (obuf may == xbuf).
// ---------------------------------------------------------------------------
template <int LT>
__global__ __launch_bounds__(256) void k_glu_ln_mfma2(
    const unsigned short* __restrict__ Whi, const unsigned short* __restrict__ Wlo,
    const float* __restrict__ ob, const float* __restrict__ lng,
    const float* __restrict__ lnb, const unsigned short* __restrict__ ybuf,
    const float* __restrict__ xbuf, float* __restrict__ obuf, int Lcur) {
  constexpr int LTILE = LT * 16;
  constexpr int KS = 72;
  __shared__ __align__(16) unsigned short Yhi[LTILE * KS];
  __shared__ float red[4][LTILE][2];
  const int tid = threadIdx.x;
  const int w = tid >> 6, lane = tid & 63, c15 = lane & 15, g4 = lane >> 4;
  const int tilesPerB = Lcur / LTILE;
  const int b = blockIdx.x / tilesPerB;
  const int l0 = (blockIdx.x % tilesPerB) * LTILE;
  const size_t bbase = (size_t)b * H_ * Lcur;

  constexpr int NE = (64 * LTILE) / 256;
#pragma unroll
  for (int e = 0; e < NE; ++e) {
    const int idx = e * 256 + tid;
    const int k = idx / LTILE;
    const int l = idx % LTILE;
    Yhi[l * KS + k] = ybuf[bbase + (size_t)k * Lcur + l0 + l];
  }

  bf16x8 wah[2], wal[2], wgh[2], wgl[2];
#pragma unroll
  for (int q = 0; q < 2; ++q) {
    const int crow = q * 32 + 8 * g4;
    const int ra = (16 * w + c15) * 64 + crow;
    const int rg = ((64 + 16 * w) + c15) * 64 + crow;
    wah[q] = *(const bf16x8*)(Whi + ra);
    wal[q] = *(const bf16x8*)(Wlo + ra);
    wgh[q] = *(const bf16x8*)(Whi + rg);
    wgl[q] = *(const bf16x8*)(Wlo + rg);
  }
  __syncthreads();

  float wv[LT][4];
#pragma unroll
  for (int lt = 0; lt < LT; ++lt) {
    const int ll = lt * 16 + c15;
    f32x4 accA = {0.f, 0.f, 0.f, 0.f}, accG = {0.f, 0.f, 0.f, 0.f};
#pragma unroll
    for (int q = 0; q < 2; ++q) {
      const int crow = q * 32 + 8 * g4;
      const bf16x8 yh = *(const bf16x8*)&Yhi[ll * KS + crow];
      accA = __builtin_amdgcn_mfma_f32_16x16x32_bf16(wah[q], yh, accA, 0, 0, 0);
      accA = __builtin_amdgcn_mfma_f32_16x16x32_bf16(wal[q], yh, accA, 0, 0, 0);
      accG = __builtin_amdgcn_mfma_f32_16x16x32_bf16(wgh[q], yh, accG, 0, 0, 0);
      accG = __builtin_amdgcn_mfma_f32_16x16x32_bf16(wgl[q], yh, accG, 0, 0, 0);
    }
    float s1 = 0.f, s2 = 0.f;
#pragma unroll
    for (int r = 0; r < 4; ++r) {
      const int ca = 16 * w + 4 * g4 + r;
      const float a = accA[r] + ob[ca];
      const float g = accG[r] + ob[H_ + ca];
      const float z = a / (1.f + expf(-g));
      const float xv = xbuf[bbase + (size_t)ca * Lcur + l0 + ll];
      wv[lt][r] = z + xv;
      s1 += wv[lt][r];
      s2 += wv[lt][r] * wv[lt][r];
    }
    s1 += __shfl_xor(s1, 16);
    s2 += __shfl_xor(s2, 16);
    s1 += __shfl_xor(s1, 32);
    s2 += __shfl_xor(s2, 32);
    if (g4 == 0) {
      red[w][ll][0] = s1;
      red[w][ll][1] = s2;
    }
  }
  __syncthreads();
#pragma unroll
  for (int lt = 0; lt < LT; ++lt) {
    const int ll = lt * 16 + c15;
    float t1 = 0.f, t2 = 0.f;
#pragma unroll
    for (int q = 0; q < 4; ++q) {
      t1 += red[q][ll][0];
      t2 += red[q][ll][1];
    }
    const float mean = t1 * (1.f / 64.f);
    const float var = t2 * (1.f / 64.f) - mean * mean;
    const float rstd = rsqrtf(var + 1e-5f);
#pragma unroll
    for (int r = 0; r < 4; ++r) {
      const int ca = 16 * w + 4 * g4 + r;
      obuf[bbase + (size_t)ca * Lcur + l0 + ll] =
          (wv[lt][r] - mean) * rstd * lng[ca] + lnb[ca];
    }
  }
}

}  // namespace

// ---------------------------------------------------------------------------
extern "C" void kernel_launch(void* const* d_in, const int* in_sizes, int n_in,
                              void* d_out, int out_size, void* d_ws, size_t ws_size,
                              hipStream_t stream) {
  const float* x       = (const float*)d_in[0];
  const float* enc_W   = (const float*)d_in[1];
  const float* enc_b   = (const float*)d_in[2];
  const float* ln_g    = (const float*)d_in[3];
  const float* ln_b    = (const float*)d_in[4];
  const float* s4_D    = (const float*)d_in[5];
  const float* s4_ldt  = (const float*)d_in[6];
  const float* s4_C    = (const float*)d_in[7];
  const float* s4_logA = (const float*)d_in[8];
  const float* s4_Aim  = (const float*)d_in[9];
  const float* out_W   = (const float*)d_in[10];
  const float* out_b   = (const float*)d_in[11];
  const float* cd1_W   = (const float*)d_in[12];
  const float* cd1_b   = (const float*)d_in[13];
  const float* cd2_W   = (const float*)d_in[14];
  const float* cd2_b   = (const float*)d_in[15];
  const float* up_W    = (const float*)d_in[16];
  const float* up_b    = (const float*)d_in[17];
  const float* up1_W   = (const float*)d_in[18];
  float* outp = (float*)d_out;

  // ---- workspace arena (~127.2 MB, lifetime-overlapped) ----
  unsigned short* TtG = (unsigned short*)d_ws;
  const size_t ttg_shorts = (size_t)64 * NL_ * 70 * 512;      // 18.35M
  const size_t nWsz = (size_t)NM_ * NL_ * 2 * H_ * H_;        // 1.57M
  unsigned short* oWhi = TtG + ttg_shorts;
  unsigned short* oWlo = oWhi + nWsz;
  unsigned short* eWhi = oWlo + nWsz;
  unsigned short* eWlo = eWhi + 3 * 4096;
  unsigned short* c1hi = eWlo + 3 * 4096;
  unsigned short* c1lo = c1hi + 3 * 4096;
  unsigned short* c2hi = c1lo + 3 * 4096;
  unsigned short* c2lo = c2hi + 2 * 4096;
  unsigned short* uphi = c2lo + 2 * 4096;
  unsigned short* uplo = uphi + 3 * 4096;
  unsigned short* u1hi = uplo + 3 * 4096;
  unsigned short* u1lo = u1hi + 3 * 4096;
  float* slotA = (float*)(u1lo + 3 * 4096);            // B*H*L0 floats
  float* slotB = slotA + (size_t)B_ * H_ * L0_;        // B*H*L0 floats

  // lifetime map (stream-serial, encoders all OUT-OF-PLACE):
  float* enc1  = slotA;                                // B*H*L1
  float* enc2  = slotA + (size_t)B_ * H_ * L1_;        // B*H*L2
  float* st0   = slotB;                                // B*H*L2
  float* scr0  = slotB + (size_t)B_ * H_ * L2_;        // B*H*L2 (bf16 now: half used)
  float* dec21 = slotB + (size_t)2 * B_ * H_ * L2_;    // B*H*L1 — disjoint from st0
  float* st1   = slotA;                                // B*H*L1 (enc1/enc2 dead)
  float* scr1  = slotA + (size_t)B_ * H_ * L1_;        // B*H*L1
  float* dec32 = slotB;                                // B*H*L0 (st0/dec21 dead)
  float* st2   = slotA;                                // B*H*L0 (st1/scr1 dead)
  float* scr2  = slotB;                                // B*H*L0 (dec32 dead post-enc)

  auto tt_layer = [&](int m, int i) -> const unsigned short* {
    const size_t NTm = (m == 0) ? 10 : (m == 1) ? 20 : 40;
    const size_t base = (m == 0) ? 0 : (m == 1) ? (size_t)64 * NL_ * 10
                                                : (size_t)64 * NL_ * 30;
    return TtG + (base + (size_t)i * 64 * NTm) * 512;
  };

  k_compute_K_tt<<<NM_ * NL_ * H_, 256, 0, stream>>>(s4_ldt, s4_C, s4_logA, s4_Aim, TtG);
  k_pack_w<<<((int)nWsz + 255) / 256, 256, 0, stream>>>(out_W, oWhi, oWlo, (int)nWsz);
  k_pack_w<<<48, 256, 0, stream>>>(enc_W, eWhi, eWlo, 3 * 4096);
  k_pack_gather<<<48, 256, 0, stream>>>(cd1_W, c1hi, c1lo, 3 * 4096, 192, 3);
  k_pack_gather<<<32, 256, 0, stream>>>(cd2_W, c2hi, c2lo, 2 * 4096, 128, 2);
  k_pack_gather<<<48, 256, 0, stream>>>(up_W, uphi, uplo, 3 * 4096, 3, 192);
  k_pack_gather<<<48, 256, 0, stream>>>(up1_W, u1hi, u1lo, 3 * 4096, 3, 192);

  // enc1 = conv_d1(x), enc2 = conv_d2(enc1)
  k_down_mfma<3, 1><<<B_ * (L1_ / 32), 256, 0, stream>>>(c1hi, c1lo, cd1_b, x, enc1,
                                                         L0_, L1_);
  k_down_mfma<2, 0><<<B_ * (L2_ / 32), 256, 0, stream>>>(c2hi, c2lo, cd2_b, enc1, enc2,
                                                         L1_, L2_);

  auto run_model = [&](int m, const float* input, float* state, float* scratch,
                       int Lm, float* final_out) {
    unsigned short* ybf = (unsigned short*)scratch;
    k_enc_mfma<<<B_ * (Lm / 32), 256, 0, stream>>>(eWhi + m * 4096, eWlo + m * 4096,
                                                   enc_b + (size_t)m * H_, input, state, Lm);
    for (int i = 0; i < NL_; ++i) {
      const unsigned short* Tl = tt_layer(m, i);
      const float* Dl = s4_D + ((size_t)m * NL_ + i) * H_;
      const int cgrid = (B_ / 32) * H_;
      if (Lm == L2_)
        k_conv_gelu_mfma<L2_><<<cgrid, 256, 0, stream>>>(state, Tl, Dl, ybf);
      else if (Lm == L1_)
        k_conv_gelu_mfma<L1_><<<cgrid, 256, 0, stream>>>(state, Tl, Dl, ybf);
      else
        k_conv_gelu_mfma<L0_><<<cgrid, 256, 0, stream>>>(state, Tl, Dl, ybf);
      float* obuf = (i == NL_ - 1 && final_out) ? final_out : state;
      const size_t wbase = ((size_t)m * NL_ + i) * 2 * H_ * H_;
      if (Lm == L2_)
        k_glu_ln_mfma2<2><<<B_ * (Lm / 32), 256, 0, stream>>>(
            oWhi + wbase, oWlo + wbase,
            out_b + ((size_t)m * NL_ + i) * 2 * H_,
            ln_g + ((size_t)m * NL_ + i) * H_,
            ln_b + ((size_t)m * NL_ + i) * H_,
            ybf, state, obuf, Lm);
      else
        k_glu_ln_mfma2<4><<<B_ * (Lm / 64), 256, 0, stream>>>(
            oWhi + wbase, oWlo + wbase,
            out_b + ((size_t)m * NL_ + i) * 2 * H_,
            ln_g + ((size_t)m * NL_ + i) * H_,
            ln_b + ((size_t)m * NL_ + i) * H_,
            ybf, state, obuf, Lm);
    }
  };

  // model 0 on enc2 (L=160): encoder out-of-place into st0
  run_model(0, enc2, st0, scr0, L2_, nullptr);
  // dec21 = convT(enc2 + m0out, up_W) + up_b + enc1  (fused add; disjoint)
  k_convT_mfma<<<B_ * (L2_ / 32), 256, 0, stream>>>(uphi, uplo, up_b, enc1, enc2, st0,
                                                    dec21, L2_, 1);
  // model 1 on dec21 (L=320): encoder into st1 (slotA)
  run_model(1, dec21, st1, scr1, L1_, nullptr);
  // dec32 = convT(m1-out, up1_W) + enc0 -> slotB (dec21/st0 dead)
  k_convT_mfma<<<B_ * (L1_ / 32), 256, 0, stream>>>(u1hi, u1lo, up_b, x, st1, nullptr,
                                                    dec32, L1_, 0);
  // model 2 on dec32 (L=640): encoder into st2 (slotA); final layer -> d_out
  run_model(2, dec32, st2, scr2, L0_, outp);
}

// Round 19
// 945.048 us; speedup vs baseline: 1.3187x; 1.0103x over previous
//
#include <hip/hip_runtime.h>
#include <hip/hip_bf16.h>
#include <math.h>

namespace {

constexpr int B_ = 256, H_ = 64, L0_ = 640, L1_ = 320, L2_ = 160;
constexpr int N2_ = 32, NL_ = 8, NM_ = 3;

typedef __attribute__((ext_vector_type(8))) short bf16x8;
typedef __attribute__((ext_vector_type(4))) float f32x4;

__device__ __forceinline__ unsigned short f2bf(float x) {
  __hip_bfloat16 h = __float2bfloat16(x);
  unsigned short u;
  __builtin_memcpy(&u, &h, 2);
  return u;
}
__device__ __forceinline__ float bf2f(unsigned short h) {
  return __uint_as_float(((unsigned int)h) << 16);
}
__device__ __forceinline__ float gelu_f(float x) {
  const float t = 0.7978845608028654f * (x + 0.044715f * x * x * x);
  return x * __builtin_amdgcn_rcpf(1.f + __expf(-2.f * t));
}
__device__ __forceinline__ void pack_one(float w, unsigned short* hi,
                                         unsigned short* lo, int idx) {
  const unsigned short h = f2bf(w);
  hi[idx] = h;
  lo[idx] = f2bf(w - bf2f(h));
}

// ---------------------------------------------------------------------------
// K + Toeplitz-fragment precompute (spill-free). One block per (m, layer, h).
// ---------------------------------------------------------------------------
__global__ __launch_bounds__(256) void k_compute_K_tt(
    const float* __restrict__ log_dt, const float* __restrict__ C,
    const float* __restrict__ logA, const float* __restrict__ Aim,
    unsigned short* __restrict__ TtG) {
  const int bid = blockIdx.x;
  const int m = bid / (NL_ * H_);
  const int rest = bid % (NL_ * H_);
  const int li = rest / H_;
  const int h = rest % H_;
  const int ph = (m * NL_ + li) * H_ + h;
  __shared__ float qkr[7][N2_], qki[7][N2_];
  __shared__ float sCr[N2_], sCi[N2_];
  __shared__ float Ksh[L0_];
  const int tid = threadIdx.x;
  if (tid < N2_) {
    const int n = tid;
    const float dt = expf(log_dt[ph]);
    const float Are = -expf(logA[(size_t)ph * N2_ + n]);
    const float Ai = Aim[(size_t)ph * N2_ + n];
    const float ar = dt * Are, ai = dt * Ai;
    const float er = expf(ar);
    float sn, cs;
    sincosf(ai, &sn, &cs);
    const float mr = er * cs - 1.f;
    const float mi = er * sn;
    const float den = Are * Are + Ai * Ai;
    const float qr_ = (mr * Are + mi * Ai) / den;
    const float qi_ = (mi * Are - mr * Ai) / den;
    const float C0 = C[((size_t)ph * N2_ + n) * 2 + 0];
    const float C1 = C[((size_t)ph * N2_ + n) * 2 + 1];
    sCr[n] = C0 * qr_ - C1 * qi_;
    sCi[n] = C0 * qi_ + C1 * qr_;
    float qr = er * cs, qi = er * sn;
#pragma unroll
    for (int k = 0; k < 7; ++k) {
      qkr[k][n] = qr;
      qki[k][n] = qi;
      const float nr = qr * qr - qi * qi;
      qi = 2.f * qr * qi;
      qr = nr;
    }
  }
  __syncthreads();
  const int Lm = (m == 0) ? L2_ : (m == 1) ? L1_ : L0_;
  const int NT = Lm / 16;

  const int l0 = tid >> 2;
  const int g = tid & 3;
  float pr[8], pi[8];
#pragma unroll
  for (int j = 0; j < 8; ++j) { pr[j] = 1.f; pi[j] = 0.f; }
#pragma unroll
  for (int k = 0; k < 6; ++k) {
    if ((l0 >> k) & 1) {
#pragma unroll
      for (int j = 0; j < 8; ++j) {
        const int n = g * 8 + j;
        const float qr = qkr[k][n], qi = qki[k][n];
        const float nr = pr[j] * qr - pi[j] * qi;
        pi[j] = pr[j] * qi + pi[j] * qr;
        pr[j] = nr;
      }
    }
  }
  for (int l = l0; l < Lm; l += 64) {
    float acc = 0.f;
#pragma unroll
    for (int j = 0; j < 8; ++j) {
      const int n = g * 8 + j;
      acc += sCr[n] * pr[j] - sCi[n] * pi[j];
    }
    acc += __shfl_xor(acc, 1);
    acc += __shfl_xor(acc, 2);
    if (g == 0) Ksh[l] = 2.f * acc;
    if (l + 64 < Lm) {
#pragma unroll
      for (int j = 0; j < 8; ++j) {
        const int n = g * 8 + j;
        const float qr = qkr[6][n], qi = qki[6][n];
        const float nr = pr[j] * qr - pi[j] * qi;
        pi[j] = pr[j] * qi + pi[j] * qr;
        pr[j] = nr;
      }
    }
  }
  __syncthreads();
  const size_t base_tiles = ((m == 0) ? 0 : (m == 1) ? (size_t)64 * NL_ * 10
                                                     : (size_t)64 * NL_ * 30) +
                            (size_t)li * 64 * NT + (size_t)h * NT;
  unsigned short* Tg = TtG + base_tiles * 512;
  for (int w = tid; w < NT * 256; w += 256) {
    const int nd = w >> 8;
    const int rem = w & 255;
    const int lane = rem >> 2;
    const int pp = rem & 3;
    const int base = nd * 16 + (lane & 15) - ((lane >> 4) << 3) - 2 * pp;
    const float f0 = (base >= 0) ? Ksh[base] : 0.f;
    const float f1 = (base - 1 >= 0) ? Ksh[base - 1] : 0.f;
    *(unsigned int*)&Tg[nd * 512 + lane * 8 + 2 * pp] =
        (unsigned int)f2bf(f0) | ((unsigned int)f2bf(f1) << 16);
  }
}

// ---------------------------------------------------------------------------
// Combined weight pack: one launch covers all 6 weight tensors.
// Blocks [0,768): out_W identity (196608 elems); [768,816): enc_W identity;
// [816,864): cd1 gather(so=192,si=3); [864,896): cd2 gather(128,2);
// [896,944): up gather(3,192); [944,992): up1 gather(3,192).
// ---------------------------------------------------------------------------
__global__ __launch_bounds__(256) void k_pack_all(
    const float* __restrict__ oW, const float* __restrict__ eW,
    const float* __restrict__ c1W, const float* __restrict__ c2W,
    const float* __restrict__ upW, const float* __restrict__ u1W,
    unsigned short* ohi, unsigned short* olo,
    unsigned short* ehi, unsigned short* elo,
    unsigned short* c1h, unsigned short* c1l,
    unsigned short* c2h, unsigned short* c2l,
    unsigned short* uph, unsigned short* upl,
    unsigned short* u1h, unsigned short* u1l) {
  const int bid = blockIdx.x;
  const int tid = threadIdx.x;
  if (bid < 768) {
    const int idx = bid * 256 + tid;
    pack_one(oW[idx], ohi, olo, idx);
    return;
  }
  const float* src;
  unsigned short *hi, *lo;
  int so, si, base;
  if (bid < 816)      { src = eW;  hi = ehi; lo = elo; so = -1; si = 0;  base = 768; }
  else if (bid < 864) { src = c1W; hi = c1h; lo = c1l; so = 192; si = 3;  base = 816; }
  else if (bid < 896) { src = c2W; hi = c2h; lo = c2l; so = 128; si = 2;  base = 864; }
  else if (bid < 944) { src = upW; hi = uph; lo = upl; so = 3;   si = 192; base = 896; }
  else                { src = u1W; hi = u1h; lo = u1l; so = 3;   si = 192; base = 944; }
  const int idx = (bid - base) * 256 + tid;
  if (so < 0) {
    pack_one(src[idx], hi, lo, idx);
  } else {
    const int k = idx >> 12;
    const int rem = idx & 4095;
    const int o = rem >> 6;
    const int i = rem & 63;
    pack_one(src[o * so + i * si + k], hi, lo, idx);
  }
}

// ---------------------------------------------------------------------------
// MFMA 1x1 encoder v3: LDS-staged, single-bf16 input (weights hi/lo).
// Block = (b, 32-l tile). OUT-OF-PLACE only.
// ---------------------------------------------------------------------------
__global__ __launch_bounds__(256) void k_enc_mfma(
    const unsigned short* __restrict__ Whi, const unsigned short* __restrict__ Wlo,
    const float* __restrict__ bvec, const float* __restrict__ in_,
    float* __restrict__ out, int Lcur) {
  constexpr int KS = 72;
  __shared__ __align__(16) unsigned short Xhi[32 * KS];
  const int tid = threadIdx.x;
  const int w = tid >> 6, lane = tid & 63, c15 = lane & 15, g4 = lane >> 4;
  const int tilesPerB = Lcur >> 5;
  const int b = blockIdx.x / tilesPerB;
  const int l0 = ((blockIdx.x % tilesPerB) << 5);
  const size_t bbase = (size_t)b * H_ * Lcur;

#pragma unroll
  for (int e = 0; e < 8; ++e) {
    const int idx = e * 256 + tid;
    const int ch = idx >> 5;
    const int c = idx & 31;
    Xhi[c * KS + ch] = f2bf(in_[bbase + (size_t)ch * Lcur + l0 + c]);
  }
  bf16x8 wh[2], wl[2];
#pragma unroll
  for (int q = 0; q < 2; ++q) {
    const int ra = (16 * w + c15) * 64 + q * 32 + 8 * g4;
    wh[q] = *(const bf16x8*)(Whi + ra);
    wl[q] = *(const bf16x8*)(Wlo + ra);
  }
  __syncthreads();

  f32x4 acc[2] = {{0.f, 0.f, 0.f, 0.f}, {0.f, 0.f, 0.f, 0.f}};
#pragma unroll
  for (int lt = 0; lt < 2; ++lt) {
    const int lc = lt * 16 + c15;
#pragma unroll
    for (int q = 0; q < 2; ++q) {
      const int crow = q * 32 + 8 * g4;
      const bf16x8 xh = *(const bf16x8*)&Xhi[lc * KS + crow];
      acc[lt] = __builtin_amdgcn_mfma_f32_16x16x32_bf16(wh[q], xh, acc[lt], 0, 0, 0);
      acc[lt] = __builtin_amdgcn_mfma_f32_16x16x32_bf16(wl[q], xh, acc[lt], 0, 0, 0);
    }
  }
#pragma unroll
  for (int lt = 0; lt < 2; ++lt) {
#pragma unroll
    for (int r = 0; r < 4; ++r) {
      const int ca = 16 * w + 4 * g4 + r;
      out[bbase + (size_t)ca * Lcur + l0 + lt * 16 + c15] = acc[lt][r] + bvec[ca];
    }
  }
}

// ---------------------------------------------------------------------------
// MFMA strided down-conv v3 (k=KW, s=2, pad=PAD), LDS-staged, bf16 input.
// ---------------------------------------------------------------------------
template <int KW, int PAD>
__global__ __launch_bounds__(256) void k_down_mfma(
    const unsigned short* __restrict__ Phi, const unsigned short* __restrict__ Plo,
    const float* __restrict__ bias, const float* __restrict__ in_,
    float* __restrict__ out, int Lin, int Lout) {
  constexpr int WCOLS = 62 + KW;
  constexpr int KS = 72;
  __shared__ __align__(16) unsigned short Xhi[WCOLS * KS];
  const int tid = threadIdx.x;
  const int w = tid >> 6, lane = tid & 63, c15 = lane & 15, g4 = lane >> 4;
  const int tilesPerB = Lout >> 5;
  const int b = blockIdx.x / tilesPerB;
  const int t0 = ((blockIdx.x % tilesPerB) << 5);
  const int c0 = 2 * t0 - PAD;
  const size_t ibase = (size_t)b * H_ * Lin;

  for (int idx = tid; idx < 64 * WCOLS; idx += 256) {
    const int ch = idx / WCOLS;
    const int c = idx % WCOLS;
    const int gc = c0 + c;
    const float v = (gc >= 0 && gc < Lin) ? in_[ibase + (size_t)ch * Lin + gc] : 0.f;
    Xhi[c * KS + ch] = f2bf(v);
  }
  bf16x8 wh[KW][2], wl[KW][2];
#pragma unroll
  for (int k = 0; k < KW; ++k)
#pragma unroll
    for (int q = 0; q < 2; ++q) {
      const int ra = (k << 12) + (16 * w + c15) * 64 + q * 32 + 8 * g4;
      wh[k][q] = *(const bf16x8*)(Phi + ra);
      wl[k][q] = *(const bf16x8*)(Plo + ra);
    }
  __syncthreads();

  f32x4 acc[2] = {{0.f, 0.f, 0.f, 0.f}, {0.f, 0.f, 0.f, 0.f}};
#pragma unroll
  for (int lt = 0; lt < 2; ++lt) {
#pragma unroll
    for (int q = 0; q < 2; ++q) {
      const int crow = q * 32 + 8 * g4;
#pragma unroll
      for (int k = 0; k < KW; ++k) {
        const int lc = 2 * (lt * 16 + c15) + k;
        const bf16x8 xh = *(const bf16x8*)&Xhi[lc * KS + crow];
        acc[lt] = __builtin_amdgcn_mfma_f32_16x16x32_bf16(wh[k][q], xh, acc[lt], 0, 0, 0);
        acc[lt] = __builtin_amdgcn_mfma_f32_16x16x32_bf16(wl[k][q], xh, acc[lt], 0, 0, 0);
      }
    }
  }
  const size_t obase = (size_t)b * H_ * Lout;
#pragma unroll
  for (int lt = 0; lt < 2; ++lt) {
#pragma unroll
    for (int r = 0; r < 4; ++r) {
      const int ca = 16 * w + 4 * g4 + r;
      out[obase + (size_t)ca * Lout + t0 + lt * 16 + c15] = acc[lt][r] + bias[ca];
    }
  }
}

// ---------------------------------------------------------------------------
// MFMA ConvTranspose1d v3 (k=3 s=2 p=1 op=1), LDS-staged, bf16 input;
// optional fused second input. NOTE: out must NOT alias in_/in2/skip.
// ---------------------------------------------------------------------------
__global__ __launch_bounds__(256) void k_convT_mfma(
    const unsigned short* __restrict__ Phi, const unsigned short* __restrict__ Plo,
    const float* __restrict__ bias, const float* __restrict__ skip,
    const float* __restrict__ in_, const float* __restrict__ in2,
    float* __restrict__ out, int Lin, int hasBias) {
  constexpr int WCOLS = 33;
  constexpr int KS = 72;
  __shared__ __align__(16) unsigned short Xhi[WCOLS * KS];
  const int tid = threadIdx.x;
  const int w = tid >> 6, lane = tid & 63, c15 = lane & 15, g4 = lane >> 4;
  const int tilesPerB = Lin >> 5;
  const int b = blockIdx.x / tilesPerB;
  const int j0 = ((blockIdx.x % tilesPerB) << 5);
  const int Lout = 2 * Lin;
  const size_t ibase = (size_t)b * H_ * Lin;

  for (int idx = tid; idx < 64 * WCOLS; idx += 256) {
    const int ch = idx / WCOLS;
    const int c = idx % WCOLS;
    const int gc = j0 + c;
    float v = 0.f;
    if (gc < Lin) {
      const size_t p = ibase + (size_t)ch * Lin + gc;
      v = in_[p];
      if (in2) v += in2[p];
    }
    Xhi[c * KS + ch] = f2bf(v);
  }
  bf16x8 wh[3][2], wl[3][2];
#pragma unroll
  for (int k = 0; k < 3; ++k)
#pragma unroll
    for (int q = 0; q < 2; ++q) {
      const int ra = (k << 12) + (16 * w + c15) * 64 + q * 32 + 8 * g4;
      wh[k][q] = *(const bf16x8*)(Phi + ra);
      wl[k][q] = *(const bf16x8*)(Plo + ra);
    }
  __syncthreads();

  f32x4 aE[2] = {{0.f, 0.f, 0.f, 0.f}, {0.f, 0.f, 0.f, 0.f}};
  f32x4 aO[2] = {{0.f, 0.f, 0.f, 0.f}, {0.f, 0.f, 0.f, 0.f}};
#pragma unroll
  for (int lt = 0; lt < 2; ++lt) {
    const int lc = lt * 16 + c15;
#pragma unroll
    for (int q = 0; q < 2; ++q) {
      const int crow = q * 32 + 8 * g4;
      const bf16x8 xjh = *(const bf16x8*)&Xhi[lc * KS + crow];
      const bf16x8 xnh = *(const bf16x8*)&Xhi[(lc + 1) * KS + crow];
      aE[lt] = __builtin_amdgcn_mfma_f32_16x16x32_bf16(wh[1][q], xjh, aE[lt], 0, 0, 0);
      aE[lt] = __builtin_amdgcn_mfma_f32_16x16x32_bf16(wl[1][q], xjh, aE[lt], 0, 0, 0);
      aO[lt] = __builtin_amdgcn_mfma_f32_16x16x32_bf16(wh[2][q], xjh, aO[lt], 0, 0, 0);
      aO[lt] = __builtin_amdgcn_mfma_f32_16x16x32_bf16(wl[2][q], xjh, aO[lt], 0, 0, 0);
      aO[lt] = __builtin_amdgcn_mfma_f32_16x16x32_bf16(wh[0][q], xnh, aO[lt], 0, 0, 0);
      aO[lt] = __builtin_amdgcn_mfma_f32_16x16x32_bf16(wl[0][q], xnh, aO[lt], 0, 0, 0);
    }
  }
  const size_t obase = (size_t)b * H_ * Lout;
#pragma unroll
  for (int lt = 0; lt < 2; ++lt) {
#pragma unroll
    for (int r = 0; r < 4; ++r) {
      const int ca = 16 * w + 4 * g4 + r;
      const float bb = hasBias ? bias[ca] : 0.f;
      const size_t pos = obase + (size_t)ca * Lout + 2 * (j0 + lt * 16 + c15);
      out[pos] = aE[lt][r] + bb + skip[pos];
      out[pos + 1] = aO[lt][r] + bb + skip[pos + 1];
    }
  }
}

// ---------------------------------------------------------------------------
// MFMA causal conv + D-skip + gelu, v8 (unchanged): bf16 output.
// ---------------------------------------------------------------------------
template <int L>
__global__ __launch_bounds__(256) void k_conv_gelu_mfma(
    const float* __restrict__ u, const unsigned short* __restrict__ Tt,
    const float* __restrict__ D, unsigned short* __restrict__ y) {
  constexpr int NT = L / 16;
  constexpr int NG = (NT + 3) / 4;
  constexpr int LP = L + 24;  // 2*LP % 16 == 0 (16B-aligned b128 frags)
  __shared__ unsigned short uhi[32 * LP];

  const int h = blockIdx.x & 63;
  const int b0 = (blockIdx.x >> 6) * 32;
  const int tid = threadIdx.x;

  {
    const int row = tid >> 3;
    const int ct = tid & 7;
    const float4* src = (const float4*)(u + ((size_t)(b0 + row) * H_ + h) * L);
#pragma unroll
    for (int c4 = ct; c4 < L / 4; c4 += 8) {
      const float4 v = src[c4];
      const unsigned int p0 = (unsigned int)f2bf(v.x) | ((unsigned int)f2bf(v.y) << 16);
      const unsigned int p1 = (unsigned int)f2bf(v.z) | ((unsigned int)f2bf(v.w) << 16);
      unsigned int* dst = (unsigned int*)&uhi[row * LP + 4 * c4];
      dst[0] = p0;
      dst[1] = p1;
    }
  }
  __syncthreads();

  const int wv = tid >> 6;
  const int lane = tid & 63;
  const float Dh = D[h];
  const int lquad = lane & 15;
  const int lhi = lane >> 4;
  const unsigned short* Th = Tt + (size_t)h * NT * 512 + lane * 8;

  for (int g = wv; g < NG; g += 4) {
    const int t0 = g * 4;
    const int ntile = (NT - t0 < 4) ? (NT - t0) : 4;
    f32x4 acc[2][4];
#pragma unroll
    for (int a = 0; a < 2; ++a)
#pragma unroll
      for (int t = 0; t < 4; ++t) acc[a][t] = (f32x4){0.f, 0.f, 0.f, 0.f};

    bf16x8 curB[4];
#pragma unroll
    for (int t = 0; t < 4; ++t) {
      const int nd0 = (t0 + t < NT) ? (t0 + t) : (NT - 1);
      curB[t] = *(const bf16x8*)(Th + (size_t)nd0 * 512);
    }

    const int nsteps = ((t0 + ntile - 1) * 16) / 32 + 1;
    for (int s = 0; s < nsteps; ++s) {
      const int j0 = 32 * s;
      const int colbase = j0 + (lhi << 3);
      const bf16x8 ah0 = *(const bf16x8*)&uhi[lquad * LP + colbase];
      const bf16x8 ah1 = *(const bf16x8*)&uhi[(16 + lquad) * LP + colbase];
#pragma unroll
      for (int t = 0; t < 4; ++t) {
        if (t >= ntile) break;
        const int d0 = (t0 + t) * 16 - j0;
        if (d0 < 0) continue;  // causal: wave-uniform skip
        acc[0][t] = __builtin_amdgcn_mfma_f32_16x16x32_bf16(ah0, curB[t], acc[0][t], 0, 0, 0);
        acc[1][t] = __builtin_amdgcn_mfma_f32_16x16x32_bf16(ah1, curB[t], acc[1][t], 0, 0, 0);
      }
#pragma unroll
      for (int t = 0; t < 4; ++t) {
        int ndn = t0 + t - 2 * (s + 1);
        ndn = ndn < 0 ? 0 : ndn;
        curB[t] = *(const bf16x8*)(Th + (size_t)ndn * 512);
      }
    }
#pragma unroll
    for (int t = 0; t < 4; ++t) {
      if (t >= ntile) break;
      const int l = (t0 + t) * 16 + lquad;
#pragma unroll
      for (int a = 0; a < 2; ++a) {
#pragma unroll
        for (int r = 0; r < 4; ++r) {
          const int row = a * 16 + (lhi << 2) + r;
          const float uv = bf2f(uhi[row * LP + l]);
          const float val = acc[a][t][r] + uv * Dh;
          y[((size_t)(b0 + row) * H_ + h) * L + l] = f2bf(gelu_f(val));
        }
      }
    }
  }
}

// ---------------------------------------------------------------------------
// MFMA out-proj (64->128) + GLU + residual + LayerNorm, v3 (unchanged).
// ---------------------------------------------------------------------------
template <int LT>
__global__ __launch_bounds__(256) void k_glu_ln_mfma2(
    const unsigned short* __restrict__ Whi, const unsigned short* __restrict__ Wlo,
    const float* __restrict__ ob, const float* __restrict__ lng,
    const float* __restrict__ lnb, const unsigned short* __restrict__ ybuf,
    const float* __restrict__ xbuf, float* __restrict__ obuf, int Lcur) {
  constexpr int LTILE = LT * 16;
  constexpr int KS = 72;
  __shared__ __align__(16) unsigned short Yhi[LTILE * KS];
  __shared__ float red[4][LTILE][2];
  const int tid = threadIdx.x;
  const int w = tid >> 6, lane = tid & 63, c15 = lane & 15, g4 = lane >> 4;
  const int tilesPerB = Lcur / LTILE;
  const int b = blockIdx.x / tilesPerB;
  const int l0 = (blockIdx.x % tilesPerB) * LTILE;
  const size_t bbase = (size_t)b * H_ * Lcur;

  constexpr int NE = (64 * LTILE) / 256;
#pragma unroll
  for (int e = 0; e < NE; ++e) {
    const int idx = e * 256 + tid;
    const int k = idx / LTILE;
    const int l = idx % LTILE;
    Yhi[l * KS + k] = ybuf[bbase + (size_t)k * Lcur + l0 + l];
  }

  bf16x8 wah[2], wal[2], wgh[2], wgl[2];
#pragma unroll
  for (int q = 0; q < 2; ++q) {
    const int crow = q * 32 + 8 * g4;
    const int ra = (16 * w + c15) * 64 + crow;
    const int rg = ((64 + 16 * w) + c15) * 64 + crow;
    wah[q] = *(const bf16x8*)(Whi + ra);
    wal[q] = *(const bf16x8*)(Wlo + ra);
    wgh[q] = *(const bf16x8*)(Whi + rg);
    wgl[q] = *(const bf16x8*)(Wlo + rg);
  }
  __syncthreads();

  float wv[LT][4];
#pragma unroll
  for (int lt = 0; lt < LT; ++lt) {
    const int ll = lt * 16 + c15;
    f32x4 accA = {0.f, 0.f, 0.f, 0.f}, accG = {0.f, 0.f, 0.f, 0.f};
#pragma unroll
    for (int q = 0; q < 2; ++q) {
      const int crow = q * 32 + 8 * g4;
      const bf16x8 yh = *(const bf16x8*)&Yhi[ll * KS + crow];
      accA = __builtin_amdgcn_mfma_f32_16x16x32_bf16(wah[q], yh, accA, 0, 0, 0);
      accA = __builtin_amdgcn_mfma_f32_16x16x32_bf16(wal[q], yh, accA, 0, 0, 0);
      accG = __builtin_amdgcn_mfma_f32_16x16x32_bf16(wgh[q], yh, accG, 0, 0, 0);
      accG = __builtin_amdgcn_mfma_f32_16x16x32_bf16(wgl[q], yh, accG, 0, 0, 0);
    }
    float s1 = 0.f, s2 = 0.f;
#pragma unroll
    for (int r = 0; r < 4; ++r) {
      const int ca = 16 * w + 4 * g4 + r;
      const float a = accA[r] + ob[ca];
      const float g = accG[r] + ob[H_ + ca];
      const float z = a / (1.f + expf(-g));
      const float xv = xbuf[bbase + (size_t)ca * Lcur + l0 + ll];
      wv[lt][r] = z + xv;
      s1 += wv[lt][r];
      s2 += wv[lt][r] * wv[lt][r];
    }
    s1 += __shfl_xor(s1, 16);
    s2 += __shfl_xor(s2, 16);
    s1 += __shfl_xor(s1, 32);
    s2 += __shfl_xor(s2, 32);
    if (g4 == 0) {
      red[w][ll][0] = s1;
      red[w][ll][1] = s2;
    }
  }
  __syncthreads();
#pragma unroll
  for (int lt = 0; lt < LT; ++lt) {
    const int ll = lt * 16 + c15;
    float t1 = 0.f, t2 = 0.f;
#pragma unroll
    for (int q = 0; q < 4; ++q) {
      t1 += red[q][ll][0];
      t2 += red[q][ll][1];
    }
    const float mean = t1 * (1.f / 64.f);
    const float var = t2 * (1.f / 64.f) - mean * mean;
    const float rstd = rsqrtf(var + 1e-5f);
#pragma unroll
    for (int r = 0; r < 4; ++r) {
      const int ca = 16 * w + 4 * g4 + r;
      obuf[bbase + (size_t)ca * Lcur + l0 + ll] =
          (wv[lt][r] - mean) * rstd * lng[ca] + lnb[ca];
    }
  }
}

}  // namespace

// ---------------------------------------------------------------------------
extern "C" void kernel_launch(void* const* d_in, const int* in_sizes, int n_in,
                              void* d_out, int out_size, void* d_ws, size_t ws_size,
                              hipStream_t stream) {
  const float* x       = (const float*)d_in[0];
  const float* enc_W   = (const float*)d_in[1];
  const float* enc_b   = (const float*)d_in[2];
  const float* ln_g    = (const float*)d_in[3];
  const float* ln_b    = (const float*)d_in[4];
  const float* s4_D    = (const float*)d_in[5];
  const float* s4_ldt  = (const float*)d_in[6];
  const float* s4_C    = (const float*)d_in[7];
  const float* s4_logA = (const float*)d_in[8];
  const float* s4_Aim  = (const float*)d_in[9];
  const float* out_W   = (const float*)d_in[10];
  const float* out_b   = (const float*)d_in[11];
  const float* cd1_W   = (const float*)d_in[12];
  const float* cd1_b   = (const float*)d_in[13];
  const float* cd2_W   = (const float*)d_in[14];
  const float* cd2_b   = (const float*)d_in[15];
  const float* up_W    = (const float*)d_in[16];
  const float* up_b    = (const float*)d_in[17];
  const float* up1_W   = (const float*)d_in[18];
  float* outp = (float*)d_out;

  // ---- workspace arena (~127.2 MB, lifetime-overlapped) ----
  unsigned short* TtG = (unsigned short*)d_ws;
  const size_t ttg_shorts = (size_t)64 * NL_ * 70 * 512;      // 18.35M
  const size_t nWsz = (size_t)NM_ * NL_ * 2 * H_ * H_;        // 1.57M
  unsigned short* oWhi = TtG + ttg_shorts;
  unsigned short* oWlo = oWhi + nWsz;
  unsigned short* eWhi = oWlo + nWsz;
  unsigned short* eWlo = eWhi + 3 * 4096;
  unsigned short* c1hi = eWlo + 3 * 4096;
  unsigned short* c1lo = c1hi + 3 * 4096;
  unsigned short* c2hi = c1lo + 3 * 4096;
  unsigned short* c2lo = c2hi + 2 * 4096;
  unsigned short* uphi = c2lo + 2 * 4096;
  unsigned short* uplo = uphi + 3 * 4096;
  unsigned short* u1hi = uplo + 3 * 4096;
  unsigned short* u1lo = u1hi + 3 * 4096;
  float* slotA = (float*)(u1lo + 3 * 4096);            // B*H*L0 floats
  float* slotB = slotA + (size_t)B_ * H_ * L0_;        // B*H*L0 floats

  // lifetime map (stream-serial, encoders all OUT-OF-PLACE):
  float* enc1  = slotA;                                // B*H*L1
  float* enc2  = slotA + (size_t)B_ * H_ * L1_;        // B*H*L2
  float* st0   = slotB;                                // B*H*L2
  float* scr0  = slotB + (size_t)B_ * H_ * L2_;        // B*H*L2 (bf16: half used)
  float* dec21 = slotB + (size_t)2 * B_ * H_ * L2_;    // B*H*L1 — disjoint from st0
  float* st1   = slotA;                                // B*H*L1 (enc1/enc2 dead)
  float* scr1  = slotA + (size_t)B_ * H_ * L1_;        // B*H*L1
  float* dec32 = slotB;                                // B*H*L0 (st0/dec21 dead)
  float* st2   = slotA;                                // B*H*L0 (st1/scr1 dead)
  float* scr2  = slotB;                                // B*H*L0 (dec32 dead post-enc)

  auto tt_layer = [&](int m, int i) -> const unsigned short* {
    const size_t NTm = (m == 0) ? 10 : (m == 1) ? 20 : 40;
    const size_t base = (m == 0) ? 0 : (m == 1) ? (size_t)64 * NL_ * 10
                                                : (size_t)64 * NL_ * 30;
    return TtG + (base + (size_t)i * 64 * NTm) * 512;
  };

  k_compute_K_tt<<<NM_ * NL_ * H_, 256, 0, stream>>>(s4_ldt, s4_C, s4_logA, s4_Aim, TtG);
  k_pack_all<<<992, 256, 0, stream>>>(out_W, enc_W, cd1_W, cd2_W, up_W, up1_W,
                                      oWhi, oWlo, eWhi, eWlo, c1hi, c1lo,
                                      c2hi, c2lo, uphi, uplo, u1hi, u1lo);

  // enc1 = conv_d1(x), enc2 = conv_d2(enc1)
  k_down_mfma<3, 1><<<B_ * (L1_ / 32), 256, 0, stream>>>(c1hi, c1lo, cd1_b, x, enc1,
                                                         L0_, L1_);
  k_down_mfma<2, 0><<<B_ * (L2_ / 32), 256, 0, stream>>>(c2hi, c2lo, cd2_b, enc1, enc2,
                                                         L1_, L2_);

  auto run_model = [&](int m, const float* input, float* state, float* scratch,
                       int Lm, float* final_out) {
    unsigned short* ybf = (unsigned short*)scratch;
    k_enc_mfma<<<B_ * (Lm / 32), 256, 0, stream>>>(eWhi + m * 4096, eWlo + m * 4096,
                                                   enc_b + (size_t)m * H_, input, state, Lm);
    for (int i = 0; i < NL_; ++i) {
      const unsigned short* Tl = tt_layer(m, i);
      const float* Dl = s4_D + ((size_t)m * NL_ + i) * H_;
      const int cgrid = (B_ / 32) * H_;
      if (Lm == L2_)
        k_conv_gelu_mfma<L2_><<<cgrid, 256, 0, stream>>>(state, Tl, Dl, ybf);
      else if (Lm == L1_)
        k_conv_gelu_mfma<L1_><<<cgrid, 256, 0, stream>>>(state, Tl, Dl, ybf);
      else
        k_conv_gelu_mfma<L0_><<<cgrid, 256, 0, stream>>>(state, Tl, Dl, ybf);
      float* obuf = (i == NL_ - 1 && final_out) ? final_out : state;
      const size_t wbase = ((size_t)m * NL_ + i) * 2 * H_ * H_;
      if (Lm == L2_)
        k_glu_ln_mfma2<2><<<B_ * (Lm / 32), 256, 0, stream>>>(
            oWhi + wbase, oWlo + wbase,
            out_b + ((size_t)m * NL_ + i) * 2 * H_,
            ln_g + ((size_t)m * NL_ + i) * H_,
            ln_b + ((size_t)m * NL_ + i) * H_,
            ybf, state, obuf, Lm);
      else
        k_glu_ln_mfma2<4><<<B_ * (Lm / 64), 256, 0, stream>>>(
            oWhi + wbase, oWlo + wbase,
            out_b + ((size_t)m * NL_ + i) * 2 * H_,
            ln_g + ((size_t)m * NL_ + i) * H_,
            ln_b + ((size_t)m * NL_ + i) * H_,
            ybf, state, obuf, Lm);
    }
  };

  // model 0 on enc2 (L=160): encoder out-of-place into st0
  run_model(0, enc2, st0, scr0, L2_, nullptr);
  // dec21 = convT(enc2 + m0out, up_W) + up_b + enc1  (fused add; disjoint)
  k_convT_mfma<<<B_ * (L2_ / 32), 256, 0, stream>>>(uphi, uplo, up_b, enc1, enc2, st0,
                                                    dec21, L2_, 1);
  // model 1 on dec21 (L=320): encoder into st1 (slotA)
  run_model(1, dec21, st1, scr1, L1_, nullptr);
  // dec32 = convT(m1-out, up1_W) + enc0 -> slotB (dec21/st0 dead)
  k_convT_mfma<<<B_ * (L1_ / 32), 256, 0, stream>>>(u1hi, u1lo, up_b, x, st1, nullptr,
                                                    dec32, L1_, 0);
  // model 2 on dec32 (L=640): encoder into st2 (slotA); final layer -> d_out
  run_model(2, dec32, st2, scr2, L0_, outp);
}

// Round 20
// 928.003 us; speedup vs baseline: 1.3429x; 1.0184x over previous
//
#include <hip/hip_runtime.h>
#include <hip/hip_bf16.h>
#include <math.h>

namespace {

constexpr int B_ = 256, H_ = 64, L0_ = 640, L1_ = 320, L2_ = 160;
constexpr int N2_ = 32, NL_ = 8, NM_ = 3;

typedef __attribute__((ext_vector_type(8))) short bf16x8;
typedef __attribute__((ext_vector_type(4))) float f32x4;

__device__ __forceinline__ unsigned short f2bf(float x) {
  __hip_bfloat16 h = __float2bfloat16(x);
  unsigned short u;
  __builtin_memcpy(&u, &h, 2);
  return u;
}
__device__ __forceinline__ float bf2f(unsigned short h) {
  return __uint_as_float(((unsigned int)h) << 16);
}
__device__ __forceinline__ float gelu_f(float x) {
  const float t = 0.7978845608028654f * (x + 0.044715f * x * x * x);
  return x * __builtin_amdgcn_rcpf(1.f + __expf(-2.f * t));
}
__device__ __forceinline__ void pack_one(float w, unsigned short* hi,
                                         unsigned short* lo, int idx) {
  const unsigned short h = f2bf(w);
  hi[idx] = h;
  lo[idx] = f2bf(w - bf2f(h));
}

// ---------------------------------------------------------------------------
// K + Toeplitz-fragment precompute (spill-free). One block per (m, layer, h).
// ---------------------------------------------------------------------------
__global__ __launch_bounds__(256) void k_compute_K_tt(
    const float* __restrict__ log_dt, const float* __restrict__ C,
    const float* __restrict__ logA, const float* __restrict__ Aim,
    unsigned short* __restrict__ TtG) {
  const int bid = blockIdx.x;
  const int m = bid / (NL_ * H_);
  const int rest = bid % (NL_ * H_);
  const int li = rest / H_;
  const int h = rest % H_;
  const int ph = (m * NL_ + li) * H_ + h;
  __shared__ float qkr[7][N2_], qki[7][N2_];
  __shared__ float sCr[N2_], sCi[N2_];
  __shared__ float Ksh[L0_];
  const int tid = threadIdx.x;
  if (tid < N2_) {
    const int n = tid;
    const float dt = expf(log_dt[ph]);
    const float Are = -expf(logA[(size_t)ph * N2_ + n]);
    const float Ai = Aim[(size_t)ph * N2_ + n];
    const float ar = dt * Are, ai = dt * Ai;
    const float er = expf(ar);
    float sn, cs;
    sincosf(ai, &sn, &cs);
    const float mr = er * cs - 1.f;
    const float mi = er * sn;
    const float den = Are * Are + Ai * Ai;
    const float qr_ = (mr * Are + mi * Ai) / den;
    const float qi_ = (mi * Are - mr * Ai) / den;
    const float C0 = C[((size_t)ph * N2_ + n) * 2 + 0];
    const float C1 = C[((size_t)ph * N2_ + n) * 2 + 1];
    sCr[n] = C0 * qr_ - C1 * qi_;
    sCi[n] = C0 * qi_ + C1 * qr_;
    float qr = er * cs, qi = er * sn;
#pragma unroll
    for (int k = 0; k < 7; ++k) {
      qkr[k][n] = qr;
      qki[k][n] = qi;
      const float nr = qr * qr - qi * qi;
      qi = 2.f * qr * qi;
      qr = nr;
    }
  }
  __syncthreads();
  const int Lm = (m == 0) ? L2_ : (m == 1) ? L1_ : L0_;
  const int NT = Lm / 16;

  const int l0 = tid >> 2;
  const int g = tid & 3;
  float pr[8], pi[8];
#pragma unroll
  for (int j = 0; j < 8; ++j) { pr[j] = 1.f; pi[j] = 0.f; }
#pragma unroll
  for (int k = 0; k < 6; ++k) {
    if ((l0 >> k) & 1) {
#pragma unroll
      for (int j = 0; j < 8; ++j) {
        const int n = g * 8 + j;
        const float qr = qkr[k][n], qi = qki[k][n];
        const float nr = pr[j] * qr - pi[j] * qi;
        pi[j] = pr[j] * qi + pi[j] * qr;
        pr[j] = nr;
      }
    }
  }
  for (int l = l0; l < Lm; l += 64) {
    float acc = 0.f;
#pragma unroll
    for (int j = 0; j < 8; ++j) {
      const int n = g * 8 + j;
      acc += sCr[n] * pr[j] - sCi[n] * pi[j];
    }
    acc += __shfl_xor(acc, 1);
    acc += __shfl_xor(acc, 2);
    if (g == 0) Ksh[l] = 2.f * acc;
    if (l + 64 < Lm) {
#pragma unroll
      for (int j = 0; j < 8; ++j) {
        const int n = g * 8 + j;
        const float qr = qkr[6][n], qi = qki[6][n];
        const float nr = pr[j] * qr - pi[j] * qi;
        pi[j] = pr[j] * qi + pi[j] * qr;
        pr[j] = nr;
      }
    }
  }
  __syncthreads();
  const size_t base_tiles = ((m == 0) ? 0 : (m == 1) ? (size_t)64 * NL_ * 10
                                                     : (size_t)64 * NL_ * 30) +
                            (size_t)li * 64 * NT + (size_t)h * NT;
  unsigned short* Tg = TtG + base_tiles * 512;
  for (int w = tid; w < NT * 256; w += 256) {
    const int nd = w >> 8;
    const int rem = w & 255;
    const int lane = rem >> 2;
    const int pp = rem & 3;
    const int base = nd * 16 + (lane & 15) - ((lane >> 4) << 3) - 2 * pp;
    const float f0 = (base >= 0) ? Ksh[base] : 0.f;
    const float f1 = (base - 1 >= 0) ? Ksh[base - 1] : 0.f;
    *(unsigned int*)&Tg[nd * 512 + lane * 8 + 2 * pp] =
        (unsigned int)f2bf(f0) | ((unsigned int)f2bf(f1) << 16);
  }
}

// ---------------------------------------------------------------------------
// Combined weight pack (one launch, all 6 weight tensors).
// ---------------------------------------------------------------------------
__global__ __launch_bounds__(256) void k_pack_all(
    const float* __restrict__ oW, const float* __restrict__ eW,
    const float* __restrict__ c1W, const float* __restrict__ c2W,
    const float* __restrict__ upW, const float* __restrict__ u1W,
    unsigned short* ohi, unsigned short* olo,
    unsigned short* ehi, unsigned short* elo,
    unsigned short* c1h, unsigned short* c1l,
    unsigned short* c2h, unsigned short* c2l,
    unsigned short* uph, unsigned short* upl,
    unsigned short* u1h, unsigned short* u1l) {
  const int bid = blockIdx.x;
  const int tid = threadIdx.x;
  if (bid < 768) {
    const int idx = bid * 256 + tid;
    pack_one(oW[idx], ohi, olo, idx);
    return;
  }
  const float* src;
  unsigned short *hi, *lo;
  int so, si, base;
  if (bid < 816)      { src = eW;  hi = ehi; lo = elo; so = -1; si = 0;  base = 768; }
  else if (bid < 864) { src = c1W; hi = c1h; lo = c1l; so = 192; si = 3;  base = 816; }
  else if (bid < 896) { src = c2W; hi = c2h; lo = c2l; so = 128; si = 2;  base = 864; }
  else if (bid < 944) { src = upW; hi = uph; lo = upl; so = 3;   si = 192; base = 896; }
  else                { src = u1W; hi = u1h; lo = u1l; so = 3;   si = 192; base = 944; }
  const int idx = (bid - base) * 256 + tid;
  if (so < 0) {
    pack_one(src[idx], hi, lo, idx);
  } else {
    const int k = idx >> 12;
    const int rem = idx & 4095;
    const int o = rem >> 6;
    const int i = rem & 63;
    pack_one(src[o * so + i * si + k], hi, lo, idx);
  }
}

// ---------------------------------------------------------------------------
// MFMA 1x1 encoder v4: f32 input, BF16 output (model state). OUT-OF-PLACE.
// ---------------------------------------------------------------------------
__global__ __launch_bounds__(256) void k_enc_mfma(
    const unsigned short* __restrict__ Whi, const unsigned short* __restrict__ Wlo,
    const float* __restrict__ bvec, const float* __restrict__ in_,
    unsigned short* __restrict__ out, int Lcur) {
  constexpr int KS = 72;
  __shared__ __align__(16) unsigned short Xhi[32 * KS];
  const int tid = threadIdx.x;
  const int w = tid >> 6, lane = tid & 63, c15 = lane & 15, g4 = lane >> 4;
  const int tilesPerB = Lcur >> 5;
  const int b = blockIdx.x / tilesPerB;
  const int l0 = ((blockIdx.x % tilesPerB) << 5);
  const size_t bbase = (size_t)b * H_ * Lcur;

#pragma unroll
  for (int e = 0; e < 8; ++e) {
    const int idx = e * 256 + tid;
    const int ch = idx >> 5;
    const int c = idx & 31;
    Xhi[c * KS + ch] = f2bf(in_[bbase + (size_t)ch * Lcur + l0 + c]);
  }
  bf16x8 wh[2], wl[2];
#pragma unroll
  for (int q = 0; q < 2; ++q) {
    const int ra = (16 * w + c15) * 64 + q * 32 + 8 * g4;
    wh[q] = *(const bf16x8*)(Whi + ra);
    wl[q] = *(const bf16x8*)(Wlo + ra);
  }
  __syncthreads();

  f32x4 acc[2] = {{0.f, 0.f, 0.f, 0.f}, {0.f, 0.f, 0.f, 0.f}};
#pragma unroll
  for (int lt = 0; lt < 2; ++lt) {
    const int lc = lt * 16 + c15;
#pragma unroll
    for (int q = 0; q < 2; ++q) {
      const int crow = q * 32 + 8 * g4;
      const bf16x8 xh = *(const bf16x8*)&Xhi[lc * KS + crow];
      acc[lt] = __builtin_amdgcn_mfma_f32_16x16x32_bf16(wh[q], xh, acc[lt], 0, 0, 0);
      acc[lt] = __builtin_amdgcn_mfma_f32_16x16x32_bf16(wl[q], xh, acc[lt], 0, 0, 0);
    }
  }
#pragma unroll
  for (int lt = 0; lt < 2; ++lt) {
#pragma unroll
    for (int r = 0; r < 4; ++r) {
      const int ca = 16 * w + 4 * g4 + r;
      out[bbase + (size_t)ca * Lcur + l0 + lt * 16 + c15] = f2bf(acc[lt][r] + bvec[ca]);
    }
  }
}

// ---------------------------------------------------------------------------
// MFMA strided down-conv v3 (unchanged; f32 in/out).
// ---------------------------------------------------------------------------
template <int KW, int PAD>
__global__ __launch_bounds__(256) void k_down_mfma(
    const unsigned short* __restrict__ Phi, const unsigned short* __restrict__ Plo,
    const float* __restrict__ bias, const float* __restrict__ in_,
    float* __restrict__ out, int Lin, int Lout) {
  constexpr int WCOLS = 62 + KW;
  constexpr int KS = 72;
  __shared__ __align__(16) unsigned short Xhi[WCOLS * KS];
  const int tid = threadIdx.x;
  const int w = tid >> 6, lane = tid & 63, c15 = lane & 15, g4 = lane >> 4;
  const int tilesPerB = Lout >> 5;
  const int b = blockIdx.x / tilesPerB;
  const int t0 = ((blockIdx.x % tilesPerB) << 5);
  const int c0 = 2 * t0 - PAD;
  const size_t ibase = (size_t)b * H_ * Lin;

  for (int idx = tid; idx < 64 * WCOLS; idx += 256) {
    const int ch = idx / WCOLS;
    const int c = idx % WCOLS;
    const int gc = c0 + c;
    const float v = (gc >= 0 && gc < Lin) ? in_[ibase + (size_t)ch * Lin + gc] : 0.f;
    Xhi[c * KS + ch] = f2bf(v);
  }
  bf16x8 wh[KW][2], wl[KW][2];
#pragma unroll
  for (int k = 0; k < KW; ++k)
#pragma unroll
    for (int q = 0; q < 2; ++q) {
      const int ra = (k << 12) + (16 * w + c15) * 64 + q * 32 + 8 * g4;
      wh[k][q] = *(const bf16x8*)(Phi + ra);
      wl[k][q] = *(const bf16x8*)(Plo + ra);
    }
  __syncthreads();

  f32x4 acc[2] = {{0.f, 0.f, 0.f, 0.f}, {0.f, 0.f, 0.f, 0.f}};
#pragma unroll
  for (int lt = 0; lt < 2; ++lt) {
#pragma unroll
    for (int q = 0; q < 2; ++q) {
      const int crow = q * 32 + 8 * g4;
#pragma unroll
      for (int k = 0; k < KW; ++k) {
        const int lc = 2 * (lt * 16 + c15) + k;
        const bf16x8 xh = *(const bf16x8*)&Xhi[lc * KS + crow];
        acc[lt] = __builtin_amdgcn_mfma_f32_16x16x32_bf16(wh[k][q], xh, acc[lt], 0, 0, 0);
        acc[lt] = __builtin_amdgcn_mfma_f32_16x16x32_bf16(wl[k][q], xh, acc[lt], 0, 0, 0);
      }
    }
  }
  const size_t obase = (size_t)b * H_ * Lout;
#pragma unroll
  for (int lt = 0; lt < 2; ++lt) {
#pragma unroll
    for (int r = 0; r < 4; ++r) {
      const int ca = 16 * w + 4 * g4 + r;
      out[obase + (size_t)ca * Lout + t0 + lt * 16 + c15] = acc[lt][r] + bias[ca];
    }
  }
}

// ---------------------------------------------------------------------------
// MFMA ConvTranspose1d v3 (unchanged; f32 in/out, optional fused in2).
// NOTE: out must NOT alias in_/in2/skip.
// ---------------------------------------------------------------------------
__global__ __launch_bounds__(256) void k_convT_mfma(
    const unsigned short* __restrict__ Phi, const unsigned short* __restrict__ Plo,
    const float* __restrict__ bias, const float* __restrict__ skip,
    const float* __restrict__ in_, const float* __restrict__ in2,
    float* __restrict__ out, int Lin, int hasBias) {
  constexpr int WCOLS = 33;
  constexpr int KS = 72;
  __shared__ __align__(16) unsigned short Xhi[WCOLS * KS];
  const int tid = threadIdx.x;
  const int w = tid >> 6, lane = tid & 63, c15 = lane & 15, g4 = lane >> 4;
  const int tilesPerB = Lin >> 5;
  const int b = blockIdx.x / tilesPerB;
  const int j0 = ((blockIdx.x % tilesPerB) << 5);
  const int Lout = 2 * Lin;
  const size_t ibase = (size_t)b * H_ * Lin;

  for (int idx = tid; idx < 64 * WCOLS; idx += 256) {
    const int ch = idx / WCOLS;
    const int c = idx % WCOLS;
    const int gc = j0 + c;
    float v = 0.f;
    if (gc < Lin) {
      const size_t p = ibase + (size_t)ch * Lin + gc;
      v = in_[p];
      if (in2) v += in2[p];
    }
    Xhi[c * KS + ch] = f2bf(v);
  }
  bf16x8 wh[3][2], wl[3][2];
#pragma unroll
  for (int k = 0; k < 3; ++k)
#pragma unroll
    for (int q = 0; q < 2; ++q) {
      const int ra = (k << 12) + (16 * w + c15) * 64 + q * 32 + 8 * g4;
      wh[k][q] = *(const bf16x8*)(Phi + ra);
      wl[k][q] = *(const bf16x8*)(Plo + ra);
    }
  __syncthreads();

  f32x4 aE[2] = {{0.f, 0.f, 0.f, 0.f}, {0.f, 0.f, 0.f, 0.f}};
  f32x4 aO[2] = {{0.f, 0.f, 0.f, 0.f}, {0.f, 0.f, 0.f, 0.f}};
#pragma unroll
  for (int lt = 0; lt < 2; ++lt) {
    const int lc = lt * 16 + c15;
#pragma unroll
    for (int q = 0; q < 2; ++q) {
      const int crow = q * 32 + 8 * g4;
      const bf16x8 xjh = *(const bf16x8*)&Xhi[lc * KS + crow];
      const bf16x8 xnh = *(const bf16x8*)&Xhi[(lc + 1) * KS + crow];
      aE[lt] = __builtin_amdgcn_mfma_f32_16x16x32_bf16(wh[1][q], xjh, aE[lt], 0, 0, 0);
      aE[lt] = __builtin_amdgcn_mfma_f32_16x16x32_bf16(wl[1][q], xjh, aE[lt], 0, 0, 0);
      aO[lt] = __builtin_amdgcn_mfma_f32_16x16x32_bf16(wh[2][q], xjh, aO[lt], 0, 0, 0);
      aO[lt] = __builtin_amdgcn_mfma_f32_16x16x32_bf16(wl[2][q], xjh, aO[lt], 0, 0, 0);
      aO[lt] = __builtin_amdgcn_mfma_f32_16x16x32_bf16(wh[0][q], xnh, aO[lt], 0, 0, 0);
      aO[lt] = __builtin_amdgcn_mfma_f32_16x16x32_bf16(wl[0][q], xnh, aO[lt], 0, 0, 0);
    }
  }
  const size_t obase = (size_t)b * H_ * Lout;
#pragma unroll
  for (int lt = 0; lt < 2; ++lt) {
#pragma unroll
    for (int r = 0; r < 4; ++r) {
      const int ca = 16 * w + 4 * g4 + r;
      const float bb = hasBias ? bias[ca] : 0.f;
      const size_t pos = obase + (size_t)ca * Lout + 2 * (j0 + lt * 16 + c15);
      out[pos] = aE[lt][r] + bb + skip[pos];
      out[pos + 1] = aO[lt][r] + bb + skip[pos + 1];
    }
  }
}

// ---------------------------------------------------------------------------
// MFMA causal conv + D-skip + gelu, v9: BF16 input (model state) + bf16 out.
// Staging is a pure uint4 copy (no conversion). Same MFMA math as v8.
// ---------------------------------------------------------------------------
template <int L>
__global__ __launch_bounds__(256) void k_conv_gelu_mfma(
    const unsigned short* __restrict__ u, const unsigned short* __restrict__ Tt,
    const float* __restrict__ D, unsigned short* __restrict__ y) {
  constexpr int NT = L / 16;
  constexpr int NG = (NT + 3) / 4;
  constexpr int LP = L + 24;  // 2*LP % 16 == 0 (16B-aligned b128 frags)
  __shared__ unsigned short uhi[32 * LP];

  const int h = blockIdx.x & 63;
  const int b0 = (blockIdx.x >> 6) * 32;
  const int tid = threadIdx.x;

  // stage u (bf16 copy): row = tid>>3 (32 rows), 8 threads/row, uint4 loads
  {
    const int row = tid >> 3;
    const int ct = tid & 7;
    const uint4* src = (const uint4*)(u + ((size_t)(b0 + row) * H_ + h) * L);
    uint4* dstrow = (uint4*)&uhi[row * LP];
#pragma unroll
    for (int c8 = ct; c8 < L / 8; c8 += 8) dstrow[c8] = src[c8];
  }
  __syncthreads();

  const int wv = tid >> 6;
  const int lane = tid & 63;
  const float Dh = D[h];
  const int lquad = lane & 15;
  const int lhi = lane >> 4;
  const unsigned short* Th = Tt + (size_t)h * NT * 512 + lane * 8;

  for (int g = wv; g < NG; g += 4) {
    const int t0 = g * 4;
    const int ntile = (NT - t0 < 4) ? (NT - t0) : 4;
    f32x4 acc[2][4];
#pragma unroll
    for (int a = 0; a < 2; ++a)
#pragma unroll
      for (int t = 0; t < 4; ++t) acc[a][t] = (f32x4){0.f, 0.f, 0.f, 0.f};

    bf16x8 curB[4];
#pragma unroll
    for (int t = 0; t < 4; ++t) {
      const int nd0 = (t0 + t < NT) ? (t0 + t) : (NT - 1);
      curB[t] = *(const bf16x8*)(Th + (size_t)nd0 * 512);
    }

    const int nsteps = ((t0 + ntile - 1) * 16) / 32 + 1;
    for (int s = 0; s < nsteps; ++s) {
      const int j0 = 32 * s;
      const int colbase = j0 + (lhi << 3);
      const bf16x8 ah0 = *(const bf16x8*)&uhi[lquad * LP + colbase];
      const bf16x8 ah1 = *(const bf16x8*)&uhi[(16 + lquad) * LP + colbase];
#pragma unroll
      for (int t = 0; t < 4; ++t) {
        if (t >= ntile) break;
        const int d0 = (t0 + t) * 16 - j0;
        if (d0 < 0) continue;  // causal: wave-uniform skip
        acc[0][t] = __builtin_amdgcn_mfma_f32_16x16x32_bf16(ah0, curB[t], acc[0][t], 0, 0, 0);
        acc[1][t] = __builtin_amdgcn_mfma_f32_16x16x32_bf16(ah1, curB[t], acc[1][t], 0, 0, 0);
      }
#pragma unroll
      for (int t = 0; t < 4; ++t) {
        int ndn = t0 + t - 2 * (s + 1);
        ndn = ndn < 0 ? 0 : ndn;
        curB[t] = *(const bf16x8*)(Th + (size_t)ndn * 512);
      }
    }
#pragma unroll
    for (int t = 0; t < 4; ++t) {
      if (t >= ntile) break;
      const int l = (t0 + t) * 16 + lquad;
#pragma unroll
      for (int a = 0; a < 2; ++a) {
#pragma unroll
        for (int r = 0; r < 4; ++r) {
          const int row = a * 16 + (lhi << 2) + r;
          const float uv = bf2f(uhi[row * LP + l]);
          const float val = acc[a][t][r] + uv * Dh;
          y[((size_t)(b0 + row) * H_ + h) * L + l] = f2bf(gelu_f(val));
        }
      }
    }
  }
}

// ---------------------------------------------------------------------------
// MFMA out-proj + GLU + residual + LayerNorm, v4: bf16 Y, bf16 residual X.
// Output: bf16 (intermediate layers, in-place on state) or f32 (final layer).
// ---------------------------------------------------------------------------
template <int LT, bool F32OUT>
__global__ __launch_bounds__(256) void k_glu_ln_mfma2(
    const unsigned short* __restrict__ Whi, const unsigned short* __restrict__ Wlo,
    const float* __restrict__ ob, const float* __restrict__ lng,
    const float* __restrict__ lnb, const unsigned short* __restrict__ ybuf,
    const unsigned short* __restrict__ xbuf, unsigned short* __restrict__ obuf16,
    float* __restrict__ obuf32, int Lcur) {
  constexpr int LTILE = LT * 16;
  constexpr int KS = 72;
  __shared__ __align__(16) unsigned short Yhi[LTILE * KS];
  __shared__ float red[4][LTILE][2];
  const int tid = threadIdx.x;
  const int w = tid >> 6, lane = tid & 63, c15 = lane & 15, g4 = lane >> 4;
  const int tilesPerB = Lcur / LTILE;
  const int b = blockIdx.x / tilesPerB;
  const int l0 = (blockIdx.x % tilesPerB) * LTILE;
  const size_t bbase = (size_t)b * H_ * Lcur;

  constexpr int NE = (64 * LTILE) / 256;
#pragma unroll
  for (int e = 0; e < NE; ++e) {
    const int idx = e * 256 + tid;
    const int k = idx / LTILE;
    const int l = idx % LTILE;
    Yhi[l * KS + k] = ybuf[bbase + (size_t)k * Lcur + l0 + l];
  }

  bf16x8 wah[2], wal[2], wgh[2], wgl[2];
#pragma unroll
  for (int q = 0; q < 2; ++q) {
    const int crow = q * 32 + 8 * g4;
    const int ra = (16 * w + c15) * 64 + crow;
    const int rg = ((64 + 16 * w) + c15) * 64 + crow;
    wah[q] = *(const bf16x8*)(Whi + ra);
    wal[q] = *(const bf16x8*)(Wlo + ra);
    wgh[q] = *(const bf16x8*)(Whi + rg);
    wgl[q] = *(const bf16x8*)(Wlo + rg);
  }
  __syncthreads();

  float wv[LT][4];
#pragma unroll
  for (int lt = 0; lt < LT; ++lt) {
    const int ll = lt * 16 + c15;
    f32x4 accA = {0.f, 0.f, 0.f, 0.f}, accG = {0.f, 0.f, 0.f, 0.f};
#pragma unroll
    for (int q = 0; q < 2; ++q) {
      const int crow = q * 32 + 8 * g4;
      const bf16x8 yh = *(const bf16x8*)&Yhi[ll * KS + crow];
      accA = __builtin_amdgcn_mfma_f32_16x16x32_bf16(wah[q], yh, accA, 0, 0, 0);
      accA = __builtin_amdgcn_mfma_f32_16x16x32_bf16(wal[q], yh, accA, 0, 0, 0);
      accG = __builtin_amdgcn_mfma_f32_16x16x32_bf16(wgh[q], yh, accG, 0, 0, 0);
      accG = __builtin_amdgcn_mfma_f32_16x16x32_bf16(wgl[q], yh, accG, 0, 0, 0);
    }
    float s1 = 0.f, s2 = 0.f;
#pragma unroll
    for (int r = 0; r < 4; ++r) {
      const int ca = 16 * w + 4 * g4 + r;
      const float a = accA[r] + ob[ca];
      const float g = accG[r] + ob[H_ + ca];
      const float z = a / (1.f + expf(-g));
      const float xv = bf2f(xbuf[bbase + (size_t)ca * Lcur + l0 + ll]);
      wv[lt][r] = z + xv;
      s1 += wv[lt][r];
      s2 += wv[lt][r] * wv[lt][r];
    }
    s1 += __shfl_xor(s1, 16);
    s2 += __shfl_xor(s2, 16);
    s1 += __shfl_xor(s1, 32);
    s2 += __shfl_xor(s2, 32);
    if (g4 == 0) {
      red[w][ll][0] = s1;
      red[w][ll][1] = s2;
    }
  }
  __syncthreads();
#pragma unroll
  for (int lt = 0; lt < LT; ++lt) {
    const int ll = lt * 16 + c15;
    float t1 = 0.f, t2 = 0.f;
#pragma unroll
    for (int q = 0; q < 4; ++q) {
      t1 += red[q][ll][0];
      t2 += red[q][ll][1];
    }
    const float mean = t1 * (1.f / 64.f);
    const float var = t2 * (1.f / 64.f) - mean * mean;
    const float rstd = rsqrtf(var + 1e-5f);
#pragma unroll
    for (int r = 0; r < 4; ++r) {
      const int ca = 16 * w + 4 * g4 + r;
      const float val = (wv[lt][r] - mean) * rstd * lng[ca] + lnb[ca];
      const size_t pos = bbase + (size_t)ca * Lcur + l0 + ll;
      if (F32OUT)
        obuf32[pos] = val;
      else
        obuf16[pos] = f2bf(val);
    }
  }
}

}  // namespace

// ---------------------------------------------------------------------------
extern "C" void kernel_launch(void* const* d_in, const int* in_sizes, int n_in,
                              void* d_out, int out_size, void* d_ws, size_t ws_size,
                              hipStream_t stream) {
  const float* x       = (const float*)d_in[0];
  const float* enc_W   = (const float*)d_in[1];
  const float* enc_b   = (const float*)d_in[2];
  const float* ln_g    = (const float*)d_in[3];
  const float* ln_b    = (const float*)d_in[4];
  const float* s4_D    = (const float*)d_in[5];
  const float* s4_ldt  = (const float*)d_in[6];
  const float* s4_C    = (const float*)d_in[7];
  const float* s4_logA = (const float*)d_in[8];
  const float* s4_Aim  = (const float*)d_in[9];
  const float* out_W   = (const float*)d_in[10];
  const float* out_b   = (const float*)d_in[11];
  const float* cd1_W   = (const float*)d_in[12];
  const float* cd1_b   = (const float*)d_in[13];
  const float* cd2_W   = (const float*)d_in[14];
  const float* cd2_b   = (const float*)d_in[15];
  const float* up_W    = (const float*)d_in[16];
  const float* up_b    = (const float*)d_in[17];
  const float* up1_W   = (const float*)d_in[18];
  float* outp = (float*)d_out;

  // ---- workspace arena ----
  unsigned short* TtG = (unsigned short*)d_ws;
  const size_t ttg_shorts = (size_t)64 * NL_ * 70 * 512;      // 18.35M
  const size_t nWsz = (size_t)NM_ * NL_ * 2 * H_ * H_;        // 1.57M
  unsigned short* oWhi = TtG + ttg_shorts;
  unsigned short* oWlo = oWhi + nWsz;
  unsigned short* eWhi = oWlo + nWsz;
  unsigned short* eWlo = eWhi + 3 * 4096;
  unsigned short* c1hi = eWlo + 3 * 4096;
  unsigned short* c1lo = c1hi + 3 * 4096;
  unsigned short* c2hi = c1lo + 3 * 4096;
  unsigned short* c2lo = c2hi + 2 * 4096;
  unsigned short* uphi = c2lo + 2 * 4096;
  unsigned short* uplo = uphi + 3 * 4096;
  unsigned short* u1hi = uplo + 3 * 4096;
  unsigned short* u1lo = u1hi + 3 * 4096;
  float* slotA = (float*)(u1lo + 3 * 4096);            // B*H*L0 floats
  float* slotB = slotA + (size_t)B_ * H_ * L0_;        // B*H*L0 floats
  const size_t BHL2 = (size_t)B_ * H_ * L2_;           // unit (L1=2u, L0=4u)

  // lifetime map (stream-serial; verified step-by-step):
  //  phase 0: enc1=A[0,2u) f32, enc2=A[2u,3u) f32
  //  model 0: st0=B[0,0.5u) bf16, ybf0=B[1u,1.5u) bf16, m0out=A[3u,4u) f32
  //  convT#1: reads enc2,m0out,enc1 (A) -> dec21=B[0,2u) f32 (st0/ybf0 dead)
  //  model 1: st1=B[2u,3u) bf16, ybf1=B[3u,4u) bf16, m1out=A[0,2u) f32
  //           (enc1/enc2/m0out dead after convT#1)
  //  convT#2: reads m1out (A), x -> dec32=B[0,4u) f32 (dec21/st1/ybf1 dead)
  //  model 2: st2=A[0,2u) bf16, ybf2=A[2u,4u) bf16 (m1out dead), out=d_out
  float* enc1  = slotA;
  float* enc2  = slotA + 2 * BHL2;
  unsigned short* st0 = (unsigned short*)slotB;
  unsigned short* ybf0 = (unsigned short*)(slotB + BHL2);
  float* m0out = slotA + 3 * BHL2;
  float* dec21 = slotB;
  unsigned short* st1 = (unsigned short*)(slotB + 2 * BHL2);
  unsigned short* ybf1 = (unsigned short*)(slotB + 3 * BHL2);
  float* m1out = slotA;
  float* dec32 = slotB;
  unsigned short* st2 = (unsigned short*)slotA;
  unsigned short* ybf2 = (unsigned short*)(slotA + 2 * BHL2);

  auto tt_layer = [&](int m, int i) -> const unsigned short* {
    const size_t NTm = (m == 0) ? 10 : (m == 1) ? 20 : 40;
    const size_t base = (m == 0) ? 0 : (m == 1) ? (size_t)64 * NL_ * 10
                                                : (size_t)64 * NL_ * 30;
    return TtG + (base + (size_t)i * 64 * NTm) * 512;
  };

  k_compute_K_tt<<<NM_ * NL_ * H_, 256, 0, stream>>>(s4_ldt, s4_C, s4_logA, s4_Aim, TtG);
  k_pack_all<<<992, 256, 0, stream>>>(out_W, enc_W, cd1_W, cd2_W, up_W, up1_W,
                                      oWhi, oWlo, eWhi, eWlo, c1hi, c1lo,
                                      c2hi, c2lo, uphi, uplo, u1hi, u1lo);

  // enc1 = conv_d1(x), enc2 = conv_d2(enc1)
  k_down_mfma<3, 1><<<B_ * (L1_ / 32), 256, 0, stream>>>(c1hi, c1lo, cd1_b, x, enc1,
                                                         L0_, L1_);
  k_down_mfma<2, 0><<<B_ * (L2_ / 32), 256, 0, stream>>>(c2hi, c2lo, cd2_b, enc1, enc2,
                                                         L1_, L2_);

  auto run_model = [&](int m, const float* input, unsigned short* state,
                       unsigned short* ybf, int Lm, float* fout) {
    k_enc_mfma<<<B_ * (Lm / 32), 256, 0, stream>>>(eWhi + m * 4096, eWlo + m * 4096,
                                                   enc_b + (size_t)m * H_, input, state, Lm);
    for (int i = 0; i < NL_; ++i) {
      const unsigned short* Tl = tt_layer(m, i);
      const float* Dl = s4_D + ((size_t)m * NL_ + i) * H_;
      const int cgrid = (B_ / 32) * H_;
      if (Lm == L2_)
        k_conv_gelu_mfma<L2_><<<cgrid, 256, 0, stream>>>(state, Tl, Dl, ybf);
      else if (Lm == L1_)
        k_conv_gelu_mfma<L1_><<<cgrid, 256, 0, stream>>>(state, Tl, Dl, ybf);
      else
        k_conv_gelu_mfma<L0_><<<cgrid, 256, 0, stream>>>(state, Tl, Dl, ybf);
      const bool last = (i == NL_ - 1);
      const size_t wbase = ((size_t)m * NL_ + i) * 2 * H_ * H_;
      const float* obp = out_b + ((size_t)m * NL_ + i) * 2 * H_;
      const float* lgp = ln_g + ((size_t)m * NL_ + i) * H_;
      const float* lbp = ln_b + ((size_t)m * NL_ + i) * H_;
      if (Lm == L2_) {
        if (last)
          k_glu_ln_mfma2<2, true><<<B_ * (Lm / 32), 256, 0, stream>>>(
              oWhi + wbase, oWlo + wbase, obp, lgp, lbp, ybf, state, nullptr, fout, Lm);
        else
          k_glu_ln_mfma2<2, false><<<B_ * (Lm / 32), 256, 0, stream>>>(
              oWhi + wbase, oWlo + wbase, obp, lgp, lbp, ybf, state, state, nullptr, Lm);
      } else {
        if (last)
          k_glu_ln_mfma2<4, true><<<B_ * (Lm / 64), 256, 0, stream>>>(
              oWhi + wbase, oWlo + wbase, obp, lgp, lbp, ybf, state, nullptr, fout, Lm);
        else
          k_glu_ln_mfma2<4, false><<<B_ * (Lm / 64), 256, 0, stream>>>(
              oWhi + wbase, oWlo + wbase, obp, lgp, lbp, ybf, state, state, nullptr, Lm);
      }
    }
  };

  // model 0 on enc2 (L=160) -> m0out (f32)
  run_model(0, enc2, st0, ybf0, L2_, m0out);
  // dec21 = convT(enc2 + m0out, up_W) + up_b + enc1
  k_convT_mfma<<<B_ * (L2_ / 32), 256, 0, stream>>>(uphi, uplo, up_b, enc1, enc2, m0out,
                                                    dec21, L2_, 1);
  // model 1 on dec21 (L=320) -> m1out (f32)
  run_model(1, dec21, st1, ybf1, L1_, m1out);
  // dec32 = convT(m1out, up1_W) + enc0
  k_convT_mfma<<<B_ * (L1_ / 32), 256, 0, stream>>>(u1hi, u1lo, up_b, x, m1out, nullptr,
                                                    dec32, L1_, 0);
  // model 2 on dec32 (L=640) -> d_out (f32)
  run_model(2, dec32, st2, ybf2, L0_, outp);
}

// Round 21
// 919.390 us; speedup vs baseline: 1.3555x; 1.0094x over previous
//
#include <hip/hip_runtime.h>
#include <hip/hip_bf16.h>
#include <math.h>

namespace {

constexpr int B_ = 256, H_ = 64, L0_ = 640, L1_ = 320, L2_ = 160;
constexpr int N2_ = 32, NL_ = 8, NM_ = 3;

typedef __attribute__((ext_vector_type(8))) short bf16x8;
typedef __attribute__((ext_vector_type(4))) float f32x4;

__device__ __forceinline__ unsigned short f2bf(float x) {
  __hip_bfloat16 h = __float2bfloat16(x);
  unsigned short u;
  __builtin_memcpy(&u, &h, 2);
  return u;
}
__device__ __forceinline__ float bf2f(unsigned short h) {
  return __uint_as_float(((unsigned int)h) << 16);
}
__device__ __forceinline__ float gelu_f(float x) {
  const float t = 0.7978845608028654f * (x + 0.044715f * x * x * x);
  return x * __builtin_amdgcn_rcpf(1.f + __expf(-2.f * t));
}
__device__ __forceinline__ void pack_one(float w, unsigned short* hi,
                                         unsigned short* lo, int idx) {
  const unsigned short h = f2bf(w);
  hi[idx] = h;
  lo[idx] = f2bf(w - bf2f(h));
}

// ---------------------------------------------------------------------------
// K + Toeplitz-fragment precompute (spill-free). One block per (m, layer, h).
// ---------------------------------------------------------------------------
__global__ __launch_bounds__(256) void k_compute_K_tt(
    const float* __restrict__ log_dt, const float* __restrict__ C,
    const float* __restrict__ logA, const float* __restrict__ Aim,
    unsigned short* __restrict__ TtG) {
  const int bid = blockIdx.x;
  const int m = bid / (NL_ * H_);
  const int rest = bid % (NL_ * H_);
  const int li = rest / H_;
  const int h = rest % H_;
  const int ph = (m * NL_ + li) * H_ + h;
  __shared__ float qkr[7][N2_], qki[7][N2_];
  __shared__ float sCr[N2_], sCi[N2_];
  __shared__ float Ksh[L0_];
  const int tid = threadIdx.x;
  if (tid < N2_) {
    const int n = tid;
    const float dt = expf(log_dt[ph]);
    const float Are = -expf(logA[(size_t)ph * N2_ + n]);
    const float Ai = Aim[(size_t)ph * N2_ + n];
    const float ar = dt * Are, ai = dt * Ai;
    const float er = expf(ar);
    float sn, cs;
    sincosf(ai, &sn, &cs);
    const float mr = er * cs - 1.f;
    const float mi = er * sn;
    const float den = Are * Are + Ai * Ai;
    const float qr_ = (mr * Are + mi * Ai) / den;
    const float qi_ = (mi * Are - mr * Ai) / den;
    const float C0 = C[((size_t)ph * N2_ + n) * 2 + 0];
    const float C1 = C[((size_t)ph * N2_ + n) * 2 + 1];
    sCr[n] = C0 * qr_ - C1 * qi_;
    sCi[n] = C0 * qi_ + C1 * qr_;
    float qr = er * cs, qi = er * sn;
#pragma unroll
    for (int k = 0; k < 7; ++k) {
      qkr[k][n] = qr;
      qki[k][n] = qi;
      const float nr = qr * qr - qi * qi;
      qi = 2.f * qr * qi;
      qr = nr;
    }
  }
  __syncthreads();
  const int Lm = (m == 0) ? L2_ : (m == 1) ? L1_ : L0_;
  const int NT = Lm / 16;

  const int l0 = tid >> 2;
  const int g = tid & 3;
  float pr[8], pi[8];
#pragma unroll
  for (int j = 0; j < 8; ++j) { pr[j] = 1.f; pi[j] = 0.f; }
#pragma unroll
  for (int k = 0; k < 6; ++k) {
    if ((l0 >> k) & 1) {
#pragma unroll
      for (int j = 0; j < 8; ++j) {
        const int n = g * 8 + j;
        const float qr = qkr[k][n], qi = qki[k][n];
        const float nr = pr[j] * qr - pi[j] * qi;
        pi[j] = pr[j] * qi + pi[j] * qr;
        pr[j] = nr;
      }
    }
  }
  for (int l = l0; l < Lm; l += 64) {
    float acc = 0.f;
#pragma unroll
    for (int j = 0; j < 8; ++j) {
      const int n = g * 8 + j;
      acc += sCr[n] * pr[j] - sCi[n] * pi[j];
    }
    acc += __shfl_xor(acc, 1);
    acc += __shfl_xor(acc, 2);
    if (g == 0) Ksh[l] = 2.f * acc;
    if (l + 64 < Lm) {
#pragma unroll
      for (int j = 0; j < 8; ++j) {
        const int n = g * 8 + j;
        const float qr = qkr[6][n], qi = qki[6][n];
        const float nr = pr[j] * qr - pi[j] * qi;
        pi[j] = pr[j] * qi + pi[j] * qr;
        pr[j] = nr;
      }
    }
  }
  __syncthreads();
  const size_t base_tiles = ((m == 0) ? 0 : (m == 1) ? (size_t)64 * NL_ * 10
                                                     : (size_t)64 * NL_ * 30) +
                            (size_t)li * 64 * NT + (size_t)h * NT;
  unsigned short* Tg = TtG + base_tiles * 512;
  for (int w = tid; w < NT * 256; w += 256) {
    const int nd = w >> 8;
    const int rem = w & 255;
    const int lane = rem >> 2;
    const int pp = rem & 3;
    const int base = nd * 16 + (lane & 15) - ((lane >> 4) << 3) - 2 * pp;
    const float f0 = (base >= 0) ? Ksh[base] : 0.f;
    const float f1 = (base - 1 >= 0) ? Ksh[base - 1] : 0.f;
    *(unsigned int*)&Tg[nd * 512 + lane * 8 + 2 * pp] =
        (unsigned int)f2bf(f0) | ((unsigned int)f2bf(f1) << 16);
  }
}

// ---------------------------------------------------------------------------
// Combined weight pack (one launch, all 6 weight tensors).
// ---------------------------------------------------------------------------
__global__ __launch_bounds__(256) void k_pack_all(
    const float* __restrict__ oW, const float* __restrict__ eW,
    const float* __restrict__ c1W, const float* __restrict__ c2W,
    const float* __restrict__ upW, const float* __restrict__ u1W,
    unsigned short* ohi, unsigned short* olo,
    unsigned short* ehi, unsigned short* elo,
    unsigned short* c1h, unsigned short* c1l,
    unsigned short* c2h, unsigned short* c2l,
    unsigned short* uph, unsigned short* upl,
    unsigned short* u1h, unsigned short* u1l) {
  const int bid = blockIdx.x;
  const int tid = threadIdx.x;
  if (bid < 768) {
    const int idx = bid * 256 + tid;
    pack_one(oW[idx], ohi, olo, idx);
    return;
  }
  const float* src;
  unsigned short *hi, *lo;
  int so, si, base;
  if (bid < 816)      { src = eW;  hi = ehi; lo = elo; so = -1; si = 0;  base = 768; }
  else if (bid < 864) { src = c1W; hi = c1h; lo = c1l; so = 192; si = 3;  base = 816; }
  else if (bid < 896) { src = c2W; hi = c2h; lo = c2l; so = 128; si = 2;  base = 864; }
  else if (bid < 944) { src = upW; hi = uph; lo = upl; so = 3;   si = 192; base = 896; }
  else                { src = u1W; hi = u1h; lo = u1l; so = 3;   si = 192; base = 944; }
  const int idx = (bid - base) * 256 + tid;
  if (so < 0) {
    pack_one(src[idx], hi, lo, idx);
  } else {
    const int k = idx >> 12;
    const int rem = idx & 4095;
    const int o = rem >> 6;
    const int i = rem & 63;
    pack_one(src[o * so + i * si + k], hi, lo, idx);
  }
}

// ---------------------------------------------------------------------------
// MFMA 1x1 encoder v5: float4-staged, f32 input, BF16 output. OUT-OF-PLACE.
// ---------------------------------------------------------------------------
__global__ __launch_bounds__(256) void k_enc_mfma(
    const unsigned short* __restrict__ Whi, const unsigned short* __restrict__ Wlo,
    const float* __restrict__ bvec, const float* __restrict__ in_,
    unsigned short* __restrict__ out, int Lcur) {
  constexpr int KS = 72;
  __shared__ __align__(16) unsigned short Xhi[32 * KS];
  const int tid = threadIdx.x;
  const int w = tid >> 6, lane = tid & 63, c15 = lane & 15, g4 = lane >> 4;
  const int tilesPerB = Lcur >> 5;
  const int b = blockIdx.x / tilesPerB;
  const int l0 = ((blockIdx.x % tilesPerB) << 5);
  const size_t bbase = (size_t)b * H_ * Lcur;

  // stage: 512 float4 (64ch x 8 vec) — aligned (l0, Lcur multiples of 32)
#pragma unroll
  for (int e = 0; e < 2; ++e) {
    const int idx = e * 256 + tid;
    const int ch = idx >> 3;
    const int c4 = idx & 7;
    const float4 v = *(const float4*)(in_ + bbase + (size_t)ch * Lcur + l0 + 4 * c4);
    const float vv[4] = {v.x, v.y, v.z, v.w};
#pragma unroll
    for (int q2 = 0; q2 < 4; ++q2) Xhi[(4 * c4 + q2) * KS + ch] = f2bf(vv[q2]);
  }
  bf16x8 wh[2], wl[2];
#pragma unroll
  for (int q = 0; q < 2; ++q) {
    const int ra = (16 * w + c15) * 64 + q * 32 + 8 * g4;
    wh[q] = *(const bf16x8*)(Whi + ra);
    wl[q] = *(const bf16x8*)(Wlo + ra);
  }
  __syncthreads();

  f32x4 acc[2] = {{0.f, 0.f, 0.f, 0.f}, {0.f, 0.f, 0.f, 0.f}};
#pragma unroll
  for (int lt = 0; lt < 2; ++lt) {
    const int lc = lt * 16 + c15;
#pragma unroll
    for (int q = 0; q < 2; ++q) {
      const int crow = q * 32 + 8 * g4;
      const bf16x8 xh = *(const bf16x8*)&Xhi[lc * KS + crow];
      acc[lt] = __builtin_amdgcn_mfma_f32_16x16x32_bf16(wh[q], xh, acc[lt], 0, 0, 0);
      acc[lt] = __builtin_amdgcn_mfma_f32_16x16x32_bf16(wl[q], xh, acc[lt], 0, 0, 0);
    }
  }
#pragma unroll
  for (int lt = 0; lt < 2; ++lt) {
#pragma unroll
    for (int r = 0; r < 4; ++r) {
      const int ca = 16 * w + 4 * g4 + r;
      out[bbase + (size_t)ca * Lcur + l0 + lt * 16 + c15] = f2bf(acc[lt][r] + bvec[ca]);
    }
  }
}

// ---------------------------------------------------------------------------
// MFMA strided down-conv v4 (k=KW, s=2, pad=PAD): float4-staged, f32 in/out.
// Row-per-4-threads staging from aligned base a0 = c0 & ~3; NF4=17 covers
// both KW=2 (64 cols) and KW=3 (65 cols, misaligned by 3).
// ---------------------------------------------------------------------------
template <int KW, int PAD>
__global__ __launch_bounds__(256) void k_down_mfma(
    const unsigned short* __restrict__ Phi, const unsigned short* __restrict__ Plo,
    const float* __restrict__ bias, const float* __restrict__ in_,
    float* __restrict__ out, int Lin, int Lout) {
  constexpr int WCOLS = 62 + KW;
  constexpr int KS = 72;
  __shared__ __align__(16) unsigned short Xhi[WCOLS * KS];
  const int tid = threadIdx.x;
  const int w = tid >> 6, lane = tid & 63, c15 = lane & 15, g4 = lane >> 4;
  const int tilesPerB = Lout >> 5;
  const int b = blockIdx.x / tilesPerB;
  const int t0 = ((blockIdx.x % tilesPerB) << 5);
  const int c0 = 2 * t0 - PAD;
  const size_t ibase = (size_t)b * H_ * Lin;

  {
    const int row = tid >> 2;   // channel 0..63
    const int ct = tid & 3;
    const int a0 = c0 & ~3;
    const float* src = in_ + ibase + (size_t)row * Lin;
#pragma unroll
    for (int j = ct; j < 17; j += 4) {
      const int g0 = a0 + 4 * j;
      float4 v;
      if (g0 >= 0 && g0 + 3 < Lin) {
        v = *(const float4*)(src + g0);
      } else {
        v.x = (g0 >= 0 && g0 < Lin) ? src[g0] : 0.f;
        v.y = (g0 + 1 >= 0 && g0 + 1 < Lin) ? src[g0 + 1] : 0.f;
        v.z = (g0 + 2 >= 0 && g0 + 2 < Lin) ? src[g0 + 2] : 0.f;
        v.w = (g0 + 3 >= 0 && g0 + 3 < Lin) ? src[g0 + 3] : 0.f;
      }
      const float vv[4] = {v.x, v.y, v.z, v.w};
#pragma unroll
      for (int e = 0; e < 4; ++e) {
        const int c = g0 + e - c0;
        if (c >= 0 && c < WCOLS) Xhi[c * KS + row] = f2bf(vv[e]);
      }
    }
  }
  bf16x8 wh[KW][2], wl[KW][2];
#pragma unroll
  for (int k = 0; k < KW; ++k)
#pragma unroll
    for (int q = 0; q < 2; ++q) {
      const int ra = (k << 12) + (16 * w + c15) * 64 + q * 32 + 8 * g4;
      wh[k][q] = *(const bf16x8*)(Phi + ra);
      wl[k][q] = *(const bf16x8*)(Plo + ra);
    }
  __syncthreads();

  f32x4 acc[2] = {{0.f, 0.f, 0.f, 0.f}, {0.f, 0.f, 0.f, 0.f}};
#pragma unroll
  for (int lt = 0; lt < 2; ++lt) {
#pragma unroll
    for (int q = 0; q < 2; ++q) {
      const int crow = q * 32 + 8 * g4;
#pragma unroll
      for (int k = 0; k < KW; ++k) {
        const int lc = 2 * (lt * 16 + c15) + k;
        const bf16x8 xh = *(const bf16x8*)&Xhi[lc * KS + crow];
        acc[lt] = __builtin_amdgcn_mfma_f32_16x16x32_bf16(wh[k][q], xh, acc[lt], 0, 0, 0);
        acc[lt] = __builtin_amdgcn_mfma_f32_16x16x32_bf16(wl[k][q], xh, acc[lt], 0, 0, 0);
      }
    }
  }
  const size_t obase = (size_t)b * H_ * Lout;
#pragma unroll
  for (int lt = 0; lt < 2; ++lt) {
#pragma unroll
    for (int r = 0; r < 4; ++r) {
      const int ca = 16 * w + 4 * g4 + r;
      out[obase + (size_t)ca * Lout + t0 + lt * 16 + c15] = acc[lt][r] + bias[ca];
    }
  }
}

// ---------------------------------------------------------------------------
// MFMA ConvTranspose1d v4 (k=3 s=2 p=1 op=1): float4-staged; optional fused
// second input (f32 add before bf16 quantize). out must NOT alias inputs.
// ---------------------------------------------------------------------------
__global__ __launch_bounds__(256) void k_convT_mfma(
    const unsigned short* __restrict__ Phi, const unsigned short* __restrict__ Plo,
    const float* __restrict__ bias, const float* __restrict__ skip,
    const float* __restrict__ in_, const float* __restrict__ in2,
    float* __restrict__ out, int Lin, int hasBias) {
  constexpr int WCOLS = 33;
  constexpr int KS = 72;
  __shared__ __align__(16) unsigned short Xhi[WCOLS * KS];
  const int tid = threadIdx.x;
  const int w = tid >> 6, lane = tid & 63, c15 = lane & 15, g4 = lane >> 4;
  const int tilesPerB = Lin >> 5;
  const int b = blockIdx.x / tilesPerB;
  const int j0 = ((blockIdx.x % tilesPerB) << 5);
  const int Lout = 2 * Lin;
  const size_t ibase = (size_t)b * H_ * Lin;

  {
    const int row = tid >> 2;   // channel 0..63
    const int ct = tid & 3;
    const float* src = in_ + ibase + (size_t)row * Lin;
    const float* src2 = in2 ? in2 + ibase + (size_t)row * Lin : nullptr;
#pragma unroll
    for (int j = ct; j < 8; j += 4) {
      const int cc = 4 * j;
      const int g0 = j0 + cc;  // aligned; g0+3 <= j0+31 < Lin
      float4 v = *(const float4*)(src + g0);
      if (src2) {
        const float4 v2 = *(const float4*)(src2 + g0);
        v.x += v2.x; v.y += v2.y; v.z += v2.z; v.w += v2.w;
      }
      const float vv[4] = {v.x, v.y, v.z, v.w};
#pragma unroll
      for (int e = 0; e < 4; ++e) Xhi[(cc + e) * KS + row] = f2bf(vv[e]);
    }
    if (ct == 0) {
      const int gc = j0 + 32;
      float v = 0.f;
      if (gc < Lin) {
        v = src[gc];
        if (src2) v += src2[gc];
      }
      Xhi[32 * KS + row] = f2bf(v);
    }
  }
  bf16x8 wh[3][2], wl[3][2];
#pragma unroll
  for (int k = 0; k < 3; ++k)
#pragma unroll
    for (int q = 0; q < 2; ++q) {
      const int ra = (k << 12) + (16 * w + c15) * 64 + q * 32 + 8 * g4;
      wh[k][q] = *(const bf16x8*)(Phi + ra);
      wl[k][q] = *(const bf16x8*)(Plo + ra);
    }
  __syncthreads();

  f32x4 aE[2] = {{0.f, 0.f, 0.f, 0.f}, {0.f, 0.f, 0.f, 0.f}};
  f32x4 aO[2] = {{0.f, 0.f, 0.f, 0.f}, {0.f, 0.f, 0.f, 0.f}};
#pragma unroll
  for (int lt = 0; lt < 2; ++lt) {
    const int lc = lt * 16 + c15;
#pragma unroll
    for (int q = 0; q < 2; ++q) {
      const int crow = q * 32 + 8 * g4;
      const bf16x8 xjh = *(const bf16x8*)&Xhi[lc * KS + crow];
      const bf16x8 xnh = *(const bf16x8*)&Xhi[(lc + 1) * KS + crow];
      aE[lt] = __builtin_amdgcn_mfma_f32_16x16x32_bf16(wh[1][q], xjh, aE[lt], 0, 0, 0);
      aE[lt] = __builtin_amdgcn_mfma_f32_16x16x32_bf16(wl[1][q], xjh, aE[lt], 0, 0, 0);
      aO[lt] = __builtin_amdgcn_mfma_f32_16x16x32_bf16(wh[2][q], xjh, aO[lt], 0, 0, 0);
      aO[lt] = __builtin_amdgcn_mfma_f32_16x16x32_bf16(wl[2][q], xjh, aO[lt], 0, 0, 0);
      aO[lt] = __builtin_amdgcn_mfma_f32_16x16x32_bf16(wh[0][q], xnh, aO[lt], 0, 0, 0);
      aO[lt] = __builtin_amdgcn_mfma_f32_16x16x32_bf16(wl[0][q], xnh, aO[lt], 0, 0, 0);
    }
  }
  const size_t obase = (size_t)b * H_ * Lout;
#pragma unroll
  for (int lt = 0; lt < 2; ++lt) {
#pragma unroll
    for (int r = 0; r < 4; ++r) {
      const int ca = 16 * w + 4 * g4 + r;
      const float bb = hasBias ? bias[ca] : 0.f;
      const size_t pos = obase + (size_t)ca * Lout + 2 * (j0 + lt * 16 + c15);
      out[pos] = aE[lt][r] + bb + skip[pos];
      out[pos + 1] = aO[lt][r] + bb + skip[pos + 1];
    }
  }
}

// ---------------------------------------------------------------------------
// MFMA causal conv + D-skip + gelu, v9 (unchanged): bf16 in/out.
// ---------------------------------------------------------------------------
template <int L>
__global__ __launch_bounds__(256) void k_conv_gelu_mfma(
    const unsigned short* __restrict__ u, const unsigned short* __restrict__ Tt,
    const float* __restrict__ D, unsigned short* __restrict__ y) {
  constexpr int NT = L / 16;
  constexpr int NG = (NT + 3) / 4;
  constexpr int LP = L + 24;
  __shared__ unsigned short uhi[32 * LP];

  const int h = blockIdx.x & 63;
  const int b0 = (blockIdx.x >> 6) * 32;
  const int tid = threadIdx.x;

  {
    const int row = tid >> 3;
    const int ct = tid & 7;
    const uint4* src = (const uint4*)(u + ((size_t)(b0 + row) * H_ + h) * L);
    uint4* dstrow = (uint4*)&uhi[row * LP];
#pragma unroll
    for (int c8 = ct; c8 < L / 8; c8 += 8) dstrow[c8] = src[c8];
  }
  __syncthreads();

  const int wv = tid >> 6;
  const int lane = tid & 63;
  const float Dh = D[h];
  const int lquad = lane & 15;
  const int lhi = lane >> 4;
  const unsigned short* Th = Tt + (size_t)h * NT * 512 + lane * 8;

  for (int g = wv; g < NG; g += 4) {
    const int t0 = g * 4;
    const int ntile = (NT - t0 < 4) ? (NT - t0) : 4;
    f32x4 acc[2][4];
#pragma unroll
    for (int a = 0; a < 2; ++a)
#pragma unroll
      for (int t = 0; t < 4; ++t) acc[a][t] = (f32x4){0.f, 0.f, 0.f, 0.f};

    bf16x8 curB[4];
#pragma unroll
    for (int t = 0; t < 4; ++t) {
      const int nd0 = (t0 + t < NT) ? (t0 + t) : (NT - 1);
      curB[t] = *(const bf16x8*)(Th + (size_t)nd0 * 512);
    }

    const int nsteps = ((t0 + ntile - 1) * 16) / 32 + 1;
    for (int s = 0; s < nsteps; ++s) {
      const int j0 = 32 * s;
      const int colbase = j0 + (lhi << 3);
      const bf16x8 ah0 = *(const bf16x8*)&uhi[lquad * LP + colbase];
      const bf16x8 ah1 = *(const bf16x8*)&uhi[(16 + lquad) * LP + colbase];
#pragma unroll
      for (int t = 0; t < 4; ++t) {
        if (t >= ntile) break;
        const int d0 = (t0 + t) * 16 - j0;
        if (d0 < 0) continue;  // causal: wave-uniform skip
        acc[0][t] = __builtin_amdgcn_mfma_f32_16x16x32_bf16(ah0, curB[t], acc[0][t], 0, 0, 0);
        acc[1][t] = __builtin_amdgcn_mfma_f32_16x16x32_bf16(ah1, curB[t], acc[1][t], 0, 0, 0);
      }
#pragma unroll
      for (int t = 0; t < 4; ++t) {
        int ndn = t0 + t - 2 * (s + 1);
        ndn = ndn < 0 ? 0 : ndn;
        curB[t] = *(const bf16x8*)(Th + (size_t)ndn * 512);
      }
    }
#pragma unroll
    for (int t = 0; t < 4; ++t) {
      if (t >= ntile) break;
      const int l = (t0 + t) * 16 + lquad;
#pragma unroll
      for (int a = 0; a < 2; ++a) {
#pragma unroll
        for (int r = 0; r < 4; ++r) {
          const int row = a * 16 + (lhi << 2) + r;
          const float uv = bf2f(uhi[row * LP + l]);
          const float val = acc[a][t][r] + uv * Dh;
          y[((size_t)(b0 + row) * H_ + h) * L + l] = f2bf(gelu_f(val));
        }
      }
    }
  }
}

// ---------------------------------------------------------------------------
// MFMA out-proj + GLU + residual + LayerNorm, v4 (unchanged): bf16 Y/X,
// bf16 or f32 output.
// ---------------------------------------------------------------------------
template <int LT, bool F32OUT>
__global__ __launch_bounds__(256) void k_glu_ln_mfma2(
    const unsigned short* __restrict__ Whi, const unsigned short* __restrict__ Wlo,
    const float* __restrict__ ob, const float* __restrict__ lng,
    const float* __restrict__ lnb, const unsigned short* __restrict__ ybuf,
    const unsigned short* __restrict__ xbuf, unsigned short* __restrict__ obuf16,
    float* __restrict__ obuf32, int Lcur) {
  constexpr int LTILE = LT * 16;
  constexpr int KS = 72;
  __shared__ __align__(16) unsigned short Yhi[LTILE * KS];
  __shared__ float red[4][LTILE][2];
  const int tid = threadIdx.x;
  const int w = tid >> 6, lane = tid & 63, c15 = lane & 15, g4 = lane >> 4;
  const int tilesPerB = Lcur / LTILE;
  const int b = blockIdx.x / tilesPerB;
  const int l0 = (blockIdx.x % tilesPerB) * LTILE;
  const size_t bbase = (size_t)b * H_ * Lcur;

  constexpr int NE = (64 * LTILE) / 256;
#pragma unroll
  for (int e = 0; e < NE; ++e) {
    const int idx = e * 256 + tid;
    const int k = idx / LTILE;
    const int l = idx % LTILE;
    Yhi[l * KS + k] = ybuf[bbase + (size_t)k * Lcur + l0 + l];
  }

  bf16x8 wah[2], wal[2], wgh[2], wgl[2];
#pragma unroll
  for (int q = 0; q < 2; ++q) {
    const int crow = q * 32 + 8 * g4;
    const int ra = (16 * w + c15) * 64 + crow;
    const int rg = ((64 + 16 * w) + c15) * 64 + crow;
    wah[q] = *(const bf16x8*)(Whi + ra);
    wal[q] = *(const bf16x8*)(Wlo + ra);
    wgh[q] = *(const bf16x8*)(Whi + rg);
    wgl[q] = *(const bf16x8*)(Wlo + rg);
  }
  __syncthreads();

  float wv[LT][4];
#pragma unroll
  for (int lt = 0; lt < LT; ++lt) {
    const int ll = lt * 16 + c15;
    f32x4 accA = {0.f, 0.f, 0.f, 0.f}, accG = {0.f, 0.f, 0.f, 0.f};
#pragma unroll
    for (int q = 0; q < 2; ++q) {
      const int crow = q * 32 + 8 * g4;
      const bf16x8 yh = *(const bf16x8*)&Yhi[ll * KS + crow];
      accA = __builtin_amdgcn_mfma_f32_16x16x32_bf16(wah[q], yh, accA, 0, 0, 0);
      accA = __builtin_amdgcn_mfma_f32_16x16x32_bf16(wal[q], yh, accA, 0, 0, 0);
      accG = __builtin_amdgcn_mfma_f32_16x16x32_bf16(wgh[q], yh, accG, 0, 0, 0);
      accG = __builtin_amdgcn_mfma_f32_16x16x32_bf16(wgl[q], yh, accG, 0, 0, 0);
    }
    float s1 = 0.f, s2 = 0.f;
#pragma unroll
    for (int r = 0; r < 4; ++r) {
      const int ca = 16 * w + 4 * g4 + r;
      const float a = accA[r] + ob[ca];
      const float g = accG[r] + ob[H_ + ca];
      const float z = a / (1.f + expf(-g));
      const float xv = bf2f(xbuf[bbase + (size_t)ca * Lcur + l0 + ll]);
      wv[lt][r] = z + xv;
      s1 += wv[lt][r];
      s2 += wv[lt][r] * wv[lt][r];
    }
    s1 += __shfl_xor(s1, 16);
    s2 += __shfl_xor(s2, 16);
    s1 += __shfl_xor(s1, 32);
    s2 += __shfl_xor(s2, 32);
    if (g4 == 0) {
      red[w][ll][0] = s1;
      red[w][ll][1] = s2;
    }
  }
  __syncthreads();
#pragma unroll
  for (int lt = 0; lt < LT; ++lt) {
    const int ll = lt * 16 + c15;
    float t1 = 0.f, t2 = 0.f;
#pragma unroll
    for (int q = 0; q < 4; ++q) {
      t1 += red[q][ll][0];
      t2 += red[q][ll][1];
    }
    const float mean = t1 * (1.f / 64.f);
    const float var = t2 * (1.f / 64.f) - mean * mean;
    const float rstd = rsqrtf(var + 1e-5f);
#pragma unroll
    for (int r = 0; r < 4; ++r) {
      const int ca = 16 * w + 4 * g4 + r;
      const float val = (wv[lt][r] - mean) * rstd * lng[ca] + lnb[ca];
      const size_t pos = bbase + (size_t)ca * Lcur + l0 + ll;
      if (F32OUT)
        obuf32[pos] = val;
      else
        obuf16[pos] = f2bf(val);
    }
  }
}

}  // namespace

// ---------------------------------------------------------------------------
extern "C" void kernel_launch(void* const* d_in, const int* in_sizes, int n_in,
                              void* d_out, int out_size, void* d_ws, size_t ws_size,
                              hipStream_t stream) {
  const float* x       = (const float*)d_in[0];
  const float* enc_W   = (const float*)d_in[1];
  const float* enc_b   = (const float*)d_in[2];
  const float* ln_g    = (const float*)d_in[3];
  const float* ln_b    = (const float*)d_in[4];
  const float* s4_D    = (const float*)d_in[5];
  const float* s4_ldt  = (const float*)d_in[6];
  const float* s4_C    = (const float*)d_in[7];
  const float* s4_logA = (const float*)d_in[8];
  const float* s4_Aim  = (const float*)d_in[9];
  const float* out_W   = (const float*)d_in[10];
  const float* out_b   = (const float*)d_in[11];
  const float* cd1_W   = (const float*)d_in[12];
  const float* cd1_b   = (const float*)d_in[13];
  const float* cd2_W   = (const float*)d_in[14];
  const float* cd2_b   = (const float*)d_in[15];
  const float* up_W    = (const float*)d_in[16];
  const float* up_b    = (const float*)d_in[17];
  const float* up1_W   = (const float*)d_in[18];
  float* outp = (float*)d_out;

  // ---- workspace arena ----
  unsigned short* TtG = (unsigned short*)d_ws;
  const size_t ttg_shorts = (size_t)64 * NL_ * 70 * 512;      // 18.35M
  const size_t nWsz = (size_t)NM_ * NL_ * 2 * H_ * H_;        // 1.57M
  unsigned short* oWhi = TtG + ttg_shorts;
  unsigned short* oWlo = oWhi + nWsz;
  unsigned short* eWhi = oWlo + nWsz;
  unsigned short* eWlo = eWhi + 3 * 4096;
  unsigned short* c1hi = eWlo + 3 * 4096;
  unsigned short* c1lo = c1hi + 3 * 4096;
  unsigned short* c2hi = c1lo + 3 * 4096;
  unsigned short* c2lo = c2hi + 2 * 4096;
  unsigned short* uphi = c2lo + 2 * 4096;
  unsigned short* uplo = uphi + 3 * 4096;
  unsigned short* u1hi = uplo + 3 * 4096;
  unsigned short* u1lo = u1hi + 3 * 4096;
  float* slotA = (float*)(u1lo + 3 * 4096);            // B*H*L0 floats
  float* slotB = slotA + (size_t)B_ * H_ * L0_;        // B*H*L0 floats
  const size_t BHL2 = (size_t)B_ * H_ * L2_;           // unit (L1=2u, L0=4u)

  // lifetime map (stream-serial; verified step-by-step):
  //  phase 0: enc1=A[0,2u) f32, enc2=A[2u,3u) f32
  //  model 0: st0=B[0,0.5u) bf16, ybf0=B[1u,1.5u) bf16, m0out=A[3u,4u) f32
  //  convT#1: reads enc2,m0out,enc1 (A) -> dec21=B[0,2u) f32 (st0/ybf0 dead)
  //  model 1: st1=B[2u,3u) bf16, ybf1=B[3u,4u) bf16, m1out=A[0,2u) f32
  //  convT#2: reads m1out (A), x -> dec32=B[0,4u) f32 (dec21/st1/ybf1 dead)
  //  model 2: st2=A[0,2u) bf16, ybf2=A[2u,4u) bf16 (m1out dead), out=d_out
  float* enc1  = slotA;
  float* enc2  = slotA + 2 * BHL2;
  unsigned short* st0 = (unsigned short*)slotB;
  unsigned short* ybf0 = (unsigned short*)(slotB + BHL2);
  float* m0out = slotA + 3 * BHL2;
  float* dec21 = slotB;
  unsigned short* st1 = (unsigned short*)(slotB + 2 * BHL2);
  unsigned short* ybf1 = (unsigned short*)(slotB + 3 * BHL2);
  float* m1out = slotA;
  float* dec32 = slotB;
  unsigned short* st2 = (unsigned short*)slotA;
  unsigned short* ybf2 = (unsigned short*)(slotA + 2 * BHL2);

  auto tt_layer = [&](int m, int i) -> const unsigned short* {
    const size_t NTm = (m == 0) ? 10 : (m == 1) ? 20 : 40;
    const size_t base = (m == 0) ? 0 : (m == 1) ? (size_t)64 * NL_ * 10
                                                : (size_t)64 * NL_ * 30;
    return TtG + (base + (size_t)i * 64 * NTm) * 512;
  };

  k_compute_K_tt<<<NM_ * NL_ * H_, 256, 0, stream>>>(s4_ldt, s4_C, s4_logA, s4_Aim, TtG);
  k_pack_all<<<992, 256, 0, stream>>>(out_W, enc_W, cd1_W, cd2_W, up_W, up1_W,
                                      oWhi, oWlo, eWhi, eWlo, c1hi, c1lo,
                                      c2hi, c2lo, uphi, uplo, u1hi, u1lo);

  // enc1 = conv_d1(x), enc2 = conv_d2(enc1)
  k_down_mfma<3, 1><<<B_ * (L1_ / 32), 256, 0, stream>>>(c1hi, c1lo, cd1_b, x, enc1,
                                                         L0_, L1_);
  k_down_mfma<2, 0><<<B_ * (L2_ / 32), 256, 0, stream>>>(c2hi, c2lo, cd2_b, enc1, enc2,
                                                         L1_, L2_);

  auto run_model = [&](int m, const float* input, unsigned short* state,
                       unsigned short* ybf, int Lm, float* fout) {
    k_enc_mfma<<<B_ * (Lm / 32), 256, 0, stream>>>(eWhi + m * 4096, eWlo + m * 4096,
                                                   enc_b + (size_t)m * H_, input, state, Lm);
    for (int i = 0; i < NL_; ++i) {
      const unsigned short* Tl = tt_layer(m, i);
      const float* Dl = s4_D + ((size_t)m * NL_ + i) * H_;
      const int cgrid = (B_ / 32) * H_;
      if (Lm == L2_)
        k_conv_gelu_mfma<L2_><<<cgrid, 256, 0, stream>>>(state, Tl, Dl, ybf);
      else if (Lm == L1_)
        k_conv_gelu_mfma<L1_><<<cgrid, 256, 0, stream>>>(state, Tl, Dl, ybf);
      else
        k_conv_gelu_mfma<L0_><<<cgrid, 256, 0, stream>>>(state, Tl, Dl, ybf);
      const bool last = (i == NL_ - 1);
      const size_t wbase = ((size_t)m * NL_ + i) * 2 * H_ * H_;
      const float* obp = out_b + ((size_t)m * NL_ + i) * 2 * H_;
      const float* lgp = ln_g + ((size_t)m * NL_ + i) * H_;
      const float* lbp = ln_b + ((size_t)m * NL_ + i) * H_;
      if (Lm == L2_) {
        if (last)
          k_glu_ln_mfma2<2, true><<<B_ * (Lm / 32), 256, 0, stream>>>(
              oWhi + wbase, oWlo + wbase, obp, lgp, lbp, ybf, state, nullptr, fout, Lm);
        else
          k_glu_ln_mfma2<2, false><<<B_ * (Lm / 32), 256, 0, stream>>>(
              oWhi + wbase, oWlo + wbase, obp, lgp, lbp, ybf, state, state, nullptr, Lm);
      } else {
        if (last)
          k_glu_ln_mfma2<4, true><<<B_ * (Lm / 64), 256, 0, stream>>>(
              oWhi + wbase, oWlo + wbase, obp, lgp, lbp, ybf, state, nullptr, fout, Lm);
        else
          k_glu_ln_mfma2<4, false><<<B_ * (Lm / 64), 256, 0, stream>>>(
              oWhi + wbase, oWlo + wbase, obp, lgp, lbp, ybf, state, state, nullptr, Lm);
      }
    }
  };

  // model 0 on enc2 (L=160) -> m0out (f32)
  run_model(0, enc2, st0, ybf0, L2_, m0out);
  // dec21 = convT(enc2 + m0out, up_W) + up_b + enc1
  k_convT_mfma<<<B_ * (L2_ / 32), 256, 0, stream>>>(uphi, uplo, up_b, enc1, enc2, m0out,
                                                    dec21, L2_, 1);
  // model 1 on dec21 (L=320) -> m1out (f32)
  run_model(1, dec21, st1, ybf1, L1_, m1out);
  // dec32 = convT(m1out, up1_W) + enc0
  k_convT_mfma<<<B_ * (L1_ / 32), 256, 0, stream>>>(u1hi, u1lo, up_b, x, m1out, nullptr,
                                                    dec32, L1_, 0);
  // model 2 on dec32 (L=640) -> d_out (f32)
  run_model(2, dec32, st2, ybf2, L0_, outp);
}

// Round 22
// 905.675 us; speedup vs baseline: 1.3761x; 1.0151x over previous
//
#include <hip/hip_runtime.h>
#include <hip/hip_bf16.h>
#include <math.h>

namespace {

constexpr int B_ = 256, H_ = 64, L0_ = 640, L1_ = 320, L2_ = 160;
constexpr int N2_ = 32, NL_ = 8, NM_ = 3;

typedef __attribute__((ext_vector_type(8))) short bf16x8;
typedef __attribute__((ext_vector_type(4))) float f32x4;

__device__ __forceinline__ unsigned short f2bf(float x) {
  __hip_bfloat16 h = __float2bfloat16(x);
  unsigned short u;
  __builtin_memcpy(&u, &h, 2);
  return u;
}
__device__ __forceinline__ float bf2f(unsigned short h) {
  return __uint_as_float(((unsigned int)h) << 16);
}
__device__ __forceinline__ float gelu_f(float x) {
  const float t = 0.7978845608028654f * (x + 0.044715f * x * x * x);
  return x * __builtin_amdgcn_rcpf(1.f + __expf(-2.f * t));
}
__device__ __forceinline__ void pack_one(float w, unsigned short* hi,
                                         unsigned short* lo, int idx) {
  const unsigned short h = f2bf(w);
  hi[idx] = h;
  lo[idx] = f2bf(w - bf2f(h));
}

// ---------------------------------------------------------------------------
// K + Toeplitz-fragment precompute (spill-free). One block per (m, layer, h).
// ---------------------------------------------------------------------------
__global__ __launch_bounds__(256) void k_compute_K_tt(
    const float* __restrict__ log_dt, const float* __restrict__ C,
    const float* __restrict__ logA, const float* __restrict__ Aim,
    unsigned short* __restrict__ TtG) {
  const int bid = blockIdx.x;
  const int m = bid / (NL_ * H_);
  const int rest = bid % (NL_ * H_);
  const int li = rest / H_;
  const int h = rest % H_;
  const int ph = (m * NL_ + li) * H_ + h;
  __shared__ float qkr[7][N2_], qki[7][N2_];
  __shared__ float sCr[N2_], sCi[N2_];
  __shared__ float Ksh[L0_];
  const int tid = threadIdx.x;
  if (tid < N2_) {
    const int n = tid;
    const float dt = expf(log_dt[ph]);
    const float Are = -expf(logA[(size_t)ph * N2_ + n]);
    const float Ai = Aim[(size_t)ph * N2_ + n];
    const float ar = dt * Are, ai = dt * Ai;
    const float er = expf(ar);
    float sn, cs;
    sincosf(ai, &sn, &cs);
    const float mr = er * cs - 1.f;
    const float mi = er * sn;
    const float den = Are * Are + Ai * Ai;
    const float qr_ = (mr * Are + mi * Ai) / den;
    const float qi_ = (mi * Are - mr * Ai) / den;
    const float C0 = C[((size_t)ph * N2_ + n) * 2 + 0];
    const float C1 = C[((size_t)ph * N2_ + n) * 2 + 1];
    sCr[n] = C0 * qr_ - C1 * qi_;
    sCi[n] = C0 * qi_ + C1 * qr_;
    float qr = er * cs, qi = er * sn;
#pragma unroll
    for (int k = 0; k < 7; ++k) {
      qkr[k][n] = qr;
      qki[k][n] = qi;
      const float nr = qr * qr - qi * qi;
      qi = 2.f * qr * qi;
      qr = nr;
    }
  }
  __syncthreads();
  const int Lm = (m == 0) ? L2_ : (m == 1) ? L1_ : L0_;
  const int NT = Lm / 16;

  const int l0 = tid >> 2;
  const int g = tid & 3;
  float pr[8], pi[8];
#pragma unroll
  for (int j = 0; j < 8; ++j) { pr[j] = 1.f; pi[j] = 0.f; }
#pragma unroll
  for (int k = 0; k < 6; ++k) {
    if ((l0 >> k) & 1) {
#pragma unroll
      for (int j = 0; j < 8; ++j) {
        const int n = g * 8 + j;
        const float qr = qkr[k][n], qi = qki[k][n];
        const float nr = pr[j] * qr - pi[j] * qi;
        pi[j] = pr[j] * qi + pi[j] * qr;
        pr[j] = nr;
      }
    }
  }
  for (int l = l0; l < Lm; l += 64) {
    float acc = 0.f;
#pragma unroll
    for (int j = 0; j < 8; ++j) {
      const int n = g * 8 + j;
      acc += sCr[n] * pr[j] - sCi[n] * pi[j];
    }
    acc += __shfl_xor(acc, 1);
    acc += __shfl_xor(acc, 2);
    if (g == 0) Ksh[l] = 2.f * acc;
    if (l + 64 < Lm) {
#pragma unroll
      for (int j = 0; j < 8; ++j) {
        const int n = g * 8 + j;
        const float qr = qkr[6][n], qi = qki[6][n];
        const float nr = pr[j] * qr - pi[j] * qi;
        pi[j] = pr[j] * qi + pi[j] * qr;
        pr[j] = nr;
      }
    }
  }
  __syncthreads();
  const size_t base_tiles = ((m == 0) ? 0 : (m == 1) ? (size_t)64 * NL_ * 10
                                                     : (size_t)64 * NL_ * 30) +
                            (size_t)li * 64 * NT + (size_t)h * NT;
  unsigned short* Tg = TtG + base_tiles * 512;
  for (int w = tid; w < NT * 256; w += 256) {
    const int nd = w >> 8;
    const int rem = w & 255;
    const int lane = rem >> 2;
    const int pp = rem & 3;
    const int base = nd * 16 + (lane & 15) - ((lane >> 4) << 3) - 2 * pp;
    const float f0 = (base >= 0) ? Ksh[base] : 0.f;
    const float f1 = (base - 1 >= 0) ? Ksh[base - 1] : 0.f;
    *(unsigned int*)&Tg[nd * 512 + lane * 8 + 2 * pp] =
        (unsigned int)f2bf(f0) | ((unsigned int)f2bf(f1) << 16);
  }
}

// ---------------------------------------------------------------------------
// Combined weight pack (one launch, all 6 weight tensors).
// ---------------------------------------------------------------------------
__global__ __launch_bounds__(256) void k_pack_all(
    const float* __restrict__ oW, const float* __restrict__ eW,
    const float* __restrict__ c1W, const float* __restrict__ c2W,
    const float* __restrict__ upW, const float* __restrict__ u1W,
    unsigned short* ohi, unsigned short* olo,
    unsigned short* ehi, unsigned short* elo,
    unsigned short* c1h, unsigned short* c1l,
    unsigned short* c2h, unsigned short* c2l,
    unsigned short* uph, unsigned short* upl,
    unsigned short* u1h, unsigned short* u1l) {
  const int bid = blockIdx.x;
  const int tid = threadIdx.x;
  if (bid < 768) {
    const int idx = bid * 256 + tid;
    pack_one(oW[idx], ohi, olo, idx);
    return;
  }
  const float* src;
  unsigned short *hi, *lo;
  int so, si, base;
  if (bid < 816)      { src = eW;  hi = ehi; lo = elo; so = -1; si = 0;  base = 768; }
  else if (bid < 864) { src = c1W; hi = c1h; lo = c1l; so = 192; si = 3;  base = 816; }
  else if (bid < 896) { src = c2W; hi = c2h; lo = c2l; so = 128; si = 2;  base = 864; }
  else if (bid < 944) { src = upW; hi = uph; lo = upl; so = 3;   si = 192; base = 896; }
  else                { src = u1W; hi = u1h; lo = u1l; so = 3;   si = 192; base = 944; }
  const int idx = (bid - base) * 256 + tid;
  if (so < 0) {
    pack_one(src[idx], hi, lo, idx);
  } else {
    const int k = idx >> 12;
    const int rem = idx & 4095;
    const int o = rem >> 6;
    const int i = rem & 63;
    pack_one(src[o * so + i * si + k], hi, lo, idx);
  }
}

// ---------------------------------------------------------------------------
// MFMA 1x1 encoder v5: float4-staged, f32 input, BF16 output. OUT-OF-PLACE.
// ---------------------------------------------------------------------------
__global__ __launch_bounds__(256) void k_enc_mfma(
    const unsigned short* __restrict__ Whi, const unsigned short* __restrict__ Wlo,
    const float* __restrict__ bvec, const float* __restrict__ in_,
    unsigned short* __restrict__ out, int Lcur) {
  constexpr int KS = 72;
  __shared__ __align__(16) unsigned short Xhi[32 * KS];
  const int tid = threadIdx.x;
  const int w = tid >> 6, lane = tid & 63, c15 = lane & 15, g4 = lane >> 4;
  const int tilesPerB = Lcur >> 5;
  const int b = blockIdx.x / tilesPerB;
  const int l0 = ((blockIdx.x % tilesPerB) << 5);
  const size_t bbase = (size_t)b * H_ * Lcur;

#pragma unroll
  for (int e = 0; e < 2; ++e) {
    const int idx = e * 256 + tid;
    const int ch = idx >> 3;
    const int c4 = idx & 7;
    const float4 v = *(const float4*)(in_ + bbase + (size_t)ch * Lcur + l0 + 4 * c4);
    const float vv[4] = {v.x, v.y, v.z, v.w};
#pragma unroll
    for (int q2 = 0; q2 < 4; ++q2) Xhi[(4 * c4 + q2) * KS + ch] = f2bf(vv[q2]);
  }
  bf16x8 wh[2], wl[2];
#pragma unroll
  for (int q = 0; q < 2; ++q) {
    const int ra = (16 * w + c15) * 64 + q * 32 + 8 * g4;
    wh[q] = *(const bf16x8*)(Whi + ra);
    wl[q] = *(const bf16x8*)(Wlo + ra);
  }
  __syncthreads();

  f32x4 acc[2] = {{0.f, 0.f, 0.f, 0.f}, {0.f, 0.f, 0.f, 0.f}};
#pragma unroll
  for (int lt = 0; lt < 2; ++lt) {
    const int lc = lt * 16 + c15;
#pragma unroll
    for (int q = 0; q < 2; ++q) {
      const int crow = q * 32 + 8 * g4;
      const bf16x8 xh = *(const bf16x8*)&Xhi[lc * KS + crow];
      acc[lt] = __builtin_amdgcn_mfma_f32_16x16x32_bf16(wh[q], xh, acc[lt], 0, 0, 0);
      acc[lt] = __builtin_amdgcn_mfma_f32_16x16x32_bf16(wl[q], xh, acc[lt], 0, 0, 0);
    }
  }
#pragma unroll
  for (int lt = 0; lt < 2; ++lt) {
#pragma unroll
    for (int r = 0; r < 4; ++r) {
      const int ca = 16 * w + 4 * g4 + r;
      out[bbase + (size_t)ca * Lcur + l0 + lt * 16 + c15] = f2bf(acc[lt][r] + bvec[ca]);
    }
  }
}

// ---------------------------------------------------------------------------
// MFMA strided down-conv v4 (k=KW, s=2, pad=PAD): float4-staged, f32 in/out.
// ---------------------------------------------------------------------------
template <int KW, int PAD>
__global__ __launch_bounds__(256) void k_down_mfma(
    const unsigned short* __restrict__ Phi, const unsigned short* __restrict__ Plo,
    const float* __restrict__ bias, const float* __restrict__ in_,
    float* __restrict__ out, int Lin, int Lout) {
  constexpr int WCOLS = 62 + KW;
  constexpr int KS = 72;
  __shared__ __align__(16) unsigned short Xhi[WCOLS * KS];
  const int tid = threadIdx.x;
  const int w = tid >> 6, lane = tid & 63, c15 = lane & 15, g4 = lane >> 4;
  const int tilesPerB = Lout >> 5;
  const int b = blockIdx.x / tilesPerB;
  const int t0 = ((blockIdx.x % tilesPerB) << 5);
  const int c0 = 2 * t0 - PAD;
  const size_t ibase = (size_t)b * H_ * Lin;

  {
    const int row = tid >> 2;   // channel 0..63
    const int ct = tid & 3;
    const int a0 = c0 & ~3;
    const float* src = in_ + ibase + (size_t)row * Lin;
#pragma unroll
    for (int j = ct; j < 17; j += 4) {
      const int g0 = a0 + 4 * j;
      float4 v;
      if (g0 >= 0 && g0 + 3 < Lin) {
        v = *(const float4*)(src + g0);
      } else {
        v.x = (g0 >= 0 && g0 < Lin) ? src[g0] : 0.f;
        v.y = (g0 + 1 >= 0 && g0 + 1 < Lin) ? src[g0 + 1] : 0.f;
        v.z = (g0 + 2 >= 0 && g0 + 2 < Lin) ? src[g0 + 2] : 0.f;
        v.w = (g0 + 3 >= 0 && g0 + 3 < Lin) ? src[g0 + 3] : 0.f;
      }
      const float vv[4] = {v.x, v.y, v.z, v.w};
#pragma unroll
      for (int e = 0; e < 4; ++e) {
        const int c = g0 + e - c0;
        if (c >= 0 && c < WCOLS) Xhi[c * KS + row] = f2bf(vv[e]);
      }
    }
  }
  bf16x8 wh[KW][2], wl[KW][2];
#pragma unroll
  for (int k = 0; k < KW; ++k)
#pragma unroll
    for (int q = 0; q < 2; ++q) {
      const int ra = (k << 12) + (16 * w + c15) * 64 + q * 32 + 8 * g4;
      wh[k][q] = *(const bf16x8*)(Phi + ra);
      wl[k][q] = *(const bf16x8*)(Plo + ra);
    }
  __syncthreads();

  f32x4 acc[2] = {{0.f, 0.f, 0.f, 0.f}, {0.f, 0.f, 0.f, 0.f}};
#pragma unroll
  for (int lt = 0; lt < 2; ++lt) {
#pragma unroll
    for (int q = 0; q < 2; ++q) {
      const int crow = q * 32 + 8 * g4;
#pragma unroll
      for (int k = 0; k < KW; ++k) {
        const int lc = 2 * (lt * 16 + c15) + k;
        const bf16x8 xh = *(const bf16x8*)&Xhi[lc * KS + crow];
        acc[lt] = __builtin_amdgcn_mfma_f32_16x16x32_bf16(wh[k][q], xh, acc[lt], 0, 0, 0);
        acc[lt] = __builtin_amdgcn_mfma_f32_16x16x32_bf16(wl[k][q], xh, acc[lt], 0, 0, 0);
      }
    }
  }
  const size_t obase = (size_t)b * H_ * Lout;
#pragma unroll
  for (int lt = 0; lt < 2; ++lt) {
#pragma unroll
    for (int r = 0; r < 4; ++r) {
      const int ca = 16 * w + 4 * g4 + r;
      out[obase + (size_t)ca * Lout + t0 + lt * 16 + c15] = acc[lt][r] + bias[ca];
    }
  }
}

// ---------------------------------------------------------------------------
// MFMA ConvTranspose1d v4 (k=3 s=2 p=1 op=1): float4-staged; optional fused
// second input (f32 add before bf16 quantize). out must NOT alias inputs.
// ---------------------------------------------------------------------------
__global__ __launch_bounds__(256) void k_convT_mfma(
    const unsigned short* __restrict__ Phi, const unsigned short* __restrict__ Plo,
    const float* __restrict__ bias, const float* __restrict__ skip,
    const float* __restrict__ in_, const float* __restrict__ in2,
    float* __restrict__ out, int Lin, int hasBias) {
  constexpr int WCOLS = 33;
  constexpr int KS = 72;
  __shared__ __align__(16) unsigned short Xhi[WCOLS * KS];
  const int tid = threadIdx.x;
  const int w = tid >> 6, lane = tid & 63, c15 = lane & 15, g4 = lane >> 4;
  const int tilesPerB = Lin >> 5;
  const int b = blockIdx.x / tilesPerB;
  const int j0 = ((blockIdx.x % tilesPerB) << 5);
  const int Lout = 2 * Lin;
  const size_t ibase = (size_t)b * H_ * Lin;

  {
    const int row = tid >> 2;   // channel 0..63
    const int ct = tid & 3;
    const float* src = in_ + ibase + (size_t)row * Lin;
    const float* src2 = in2 ? in2 + ibase + (size_t)row * Lin : nullptr;
#pragma unroll
    for (int j = ct; j < 8; j += 4) {
      const int cc = 4 * j;
      const int g0 = j0 + cc;
      float4 v = *(const float4*)(src + g0);
      if (src2) {
        const float4 v2 = *(const float4*)(src2 + g0);
        v.x += v2.x; v.y += v2.y; v.z += v2.z; v.w += v2.w;
      }
      const float vv[4] = {v.x, v.y, v.z, v.w};
#pragma unroll
      for (int e = 0; e < 4; ++e) Xhi[(cc + e) * KS + row] = f2bf(vv[e]);
    }
    if (ct == 0) {
      const int gc = j0 + 32;
      float v = 0.f;
      if (gc < Lin) {
        v = src[gc];
        if (src2) v += src2[gc];
      }
      Xhi[32 * KS + row] = f2bf(v);
    }
  }
  bf16x8 wh[3][2], wl[3][2];
#pragma unroll
  for (int k = 0; k < 3; ++k)
#pragma unroll
    for (int q = 0; q < 2; ++q) {
      const int ra = (k << 12) + (16 * w + c15) * 64 + q * 32 + 8 * g4;
      wh[k][q] = *(const bf16x8*)(Phi + ra);
      wl[k][q] = *(const bf16x8*)(Plo + ra);
    }
  __syncthreads();

  f32x4 aE[2] = {{0.f, 0.f, 0.f, 0.f}, {0.f, 0.f, 0.f, 0.f}};
  f32x4 aO[2] = {{0.f, 0.f, 0.f, 0.f}, {0.f, 0.f, 0.f, 0.f}};
#pragma unroll
  for (int lt = 0; lt < 2; ++lt) {
    const int lc = lt * 16 + c15;
#pragma unroll
    for (int q = 0; q < 2; ++q) {
      const int crow = q * 32 + 8 * g4;
      const bf16x8 xjh = *(const bf16x8*)&Xhi[lc * KS + crow];
      const bf16x8 xnh = *(const bf16x8*)&Xhi[(lc + 1) * KS + crow];
      aE[lt] = __builtin_amdgcn_mfma_f32_16x16x32_bf16(wh[1][q], xjh, aE[lt], 0, 0, 0);
      aE[lt] = __builtin_amdgcn_mfma_f32_16x16x32_bf16(wl[1][q], xjh, aE[lt], 0, 0, 0);
      aO[lt] = __builtin_amdgcn_mfma_f32_16x16x32_bf16(wh[2][q], xjh, aO[lt], 0, 0, 0);
      aO[lt] = __builtin_amdgcn_mfma_f32_16x16x32_bf16(wl[2][q], xjh, aO[lt], 0, 0, 0);
      aO[lt] = __builtin_amdgcn_mfma_f32_16x16x32_bf16(wh[0][q], xnh, aO[lt], 0, 0, 0);
      aO[lt] = __builtin_amdgcn_mfma_f32_16x16x32_bf16(wl[0][q], xnh, aO[lt], 0, 0, 0);
    }
  }
  const size_t obase = (size_t)b * H_ * Lout;
#pragma unroll
  for (int lt = 0; lt < 2; ++lt) {
#pragma unroll
    for (int r = 0; r < 4; ++r) {
      const int ca = 16 * w + 4 * g4 + r;
      const float bb = hasBias ? bias[ca] : 0.f;
      const size_t pos = obase + (size_t)ca * Lout + 2 * (j0 + lt * 16 + c15);
      out[pos] = aE[lt][r] + bb + skip[pos];
      out[pos + 1] = aO[lt][r] + bb + skip[pos + 1];
    }
  }
}

// ---------------------------------------------------------------------------
// MFMA causal conv + D-skip + gelu, v9 (unchanged): bf16 in/out.
// ---------------------------------------------------------------------------
template <int L>
__global__ __launch_bounds__(256) void k_conv_gelu_mfma(
    const unsigned short* __restrict__ u, const unsigned short* __restrict__ Tt,
    const float* __restrict__ D, unsigned short* __restrict__ y) {
  constexpr int NT = L / 16;
  constexpr int NG = (NT + 3) / 4;
  constexpr int LP = L + 24;
  __shared__ unsigned short uhi[32 * LP];

  const int h = blockIdx.x & 63;
  const int b0 = (blockIdx.x >> 6) * 32;
  const int tid = threadIdx.x;

  {
    const int row = tid >> 3;
    const int ct = tid & 7;
    const uint4* src = (const uint4*)(u + ((size_t)(b0 + row) * H_ + h) * L);
    uint4* dstrow = (uint4*)&uhi[row * LP];
#pragma unroll
    for (int c8 = ct; c8 < L / 8; c8 += 8) dstrow[c8] = src[c8];
  }
  __syncthreads();

  const int wv = tid >> 6;
  const int lane = tid & 63;
  const float Dh = D[h];
  const int lquad = lane & 15;
  const int lhi = lane >> 4;
  const unsigned short* Th = Tt + (size_t)h * NT * 512 + lane * 8;

  for (int g = wv; g < NG; g += 4) {
    const int t0 = g * 4;
    const int ntile = (NT - t0 < 4) ? (NT - t0) : 4;
    f32x4 acc[2][4];
#pragma unroll
    for (int a = 0; a < 2; ++a)
#pragma unroll
      for (int t = 0; t < 4; ++t) acc[a][t] = (f32x4){0.f, 0.f, 0.f, 0.f};

    bf16x8 curB[4];
#pragma unroll
    for (int t = 0; t < 4; ++t) {
      const int nd0 = (t0 + t < NT) ? (t0 + t) : (NT - 1);
      curB[t] = *(const bf16x8*)(Th + (size_t)nd0 * 512);
    }

    const int nsteps = ((t0 + ntile - 1) * 16) / 32 + 1;
    for (int s = 0; s < nsteps; ++s) {
      const int j0 = 32 * s;
      const int colbase = j0 + (lhi << 3);
      const bf16x8 ah0 = *(const bf16x8*)&uhi[lquad * LP + colbase];
      const bf16x8 ah1 = *(const bf16x8*)&uhi[(16 + lquad) * LP + colbase];
#pragma unroll
      for (int t = 0; t < 4; ++t) {
        if (t >= ntile) break;
        const int d0 = (t0 + t) * 16 - j0;
        if (d0 < 0) continue;  // causal: wave-uniform skip
        acc[0][t] = __builtin_amdgcn_mfma_f32_16x16x32_bf16(ah0, curB[t], acc[0][t], 0, 0, 0);
        acc[1][t] = __builtin_amdgcn_mfma_f32_16x16x32_bf16(ah1, curB[t], acc[1][t], 0, 0, 0);
      }
#pragma unroll
      for (int t = 0; t < 4; ++t) {
        int ndn = t0 + t - 2 * (s + 1);
        ndn = ndn < 0 ? 0 : ndn;
        curB[t] = *(const bf16x8*)(Th + (size_t)ndn * 512);
      }
    }
#pragma unroll
    for (int t = 0; t < 4; ++t) {
      if (t >= ntile) break;
      const int l = (t0 + t) * 16 + lquad;
#pragma unroll
      for (int a = 0; a < 2; ++a) {
#pragma unroll
        for (int r = 0; r < 4; ++r) {
          const int row = a * 16 + (lhi << 2) + r;
          const float uv = bf2f(uhi[row * LP + l]);
          const float val = acc[a][t][r] + uv * Dh;
          y[((size_t)(b0 + row) * H_ + h) * L + l] = f2bf(gelu_f(val));
        }
      }
    }
  }
}

// ---------------------------------------------------------------------------
// MFMA out-proj + GLU + residual + LayerNorm, v5: uint4-vectorized Y staging
// (bit-identical values; 16 scalar loads -> 2 uint4 loads per thread).
// ---------------------------------------------------------------------------
template <int LT, bool F32OUT>
__global__ __launch_bounds__(256) void k_glu_ln_mfma2(
    const unsigned short* __restrict__ Whi, const unsigned short* __restrict__ Wlo,
    const float* __restrict__ ob, const float* __restrict__ lng,
    const float* __restrict__ lnb, const unsigned short* __restrict__ ybuf,
    const unsigned short* __restrict__ xbuf, unsigned short* __restrict__ obuf16,
    float* __restrict__ obuf32, int Lcur) {
  constexpr int LTILE = LT * 16;
  constexpr int KS = 72;
  __shared__ __align__(16) unsigned short Yhi[LTILE * KS];
  __shared__ float red[4][LTILE][2];
  const int tid = threadIdx.x;
  const int w = tid >> 6, lane = tid & 63, c15 = lane & 15, g4 = lane >> 4;
  const int tilesPerB = Lcur / LTILE;
  const int b = blockIdx.x / tilesPerB;
  const int l0 = (blockIdx.x % tilesPerB) * LTILE;
  const size_t bbase = (size_t)b * H_ * Lcur;

  // stage Y: uint4 loads along l (aligned: l0 % 32 == 0, Lcur % 32 == 0)
  constexpr int VPT = (64 * LTILE / 8) / 256;  // uint4 per thread (1 or 2)
  constexpr int LV = LTILE / 8;                // uint4 per row
#pragma unroll
  for (int e = 0; e < VPT; ++e) {
    const int idx = e * 256 + tid;
    const int k = idx / LV;
    const int lv = idx % LV;
    const int l = lv * 8;
    unsigned short tmp[8];
    *(uint4*)tmp = *(const uint4*)(ybuf + bbase + (size_t)k * Lcur + l0 + l);
#pragma unroll
    for (int j = 0; j < 8; ++j) Yhi[(l + j) * KS + k] = tmp[j];
  }

  bf16x8 wah[2], wal[2], wgh[2], wgl[2];
#pragma unroll
  for (int q = 0; q < 2; ++q) {
    const int crow = q * 32 + 8 * g4;
    const int ra = (16 * w + c15) * 64 + crow;
    const int rg = ((64 + 16 * w) + c15) * 64 + crow;
    wah[q] = *(const bf16x8*)(Whi + ra);
    wal[q] = *(const bf16x8*)(Wlo + ra);
    wgh[q] = *(const bf16x8*)(Whi + rg);
    wgl[q] = *(const bf16x8*)(Wlo + rg);
  }
  __syncthreads();

  float wv[LT][4];
#pragma unroll
  for (int lt = 0; lt < LT; ++lt) {
    const int ll = lt * 16 + c15;
    f32x4 accA = {0.f, 0.f, 0.f, 0.f}, accG = {0.f, 0.f, 0.f, 0.f};
#pragma unroll
    for (int q = 0; q < 2; ++q) {
      const int crow = q * 32 + 8 * g4;
      const bf16x8 yh = *(const bf16x8*)&Yhi[ll * KS + crow];
      accA = __builtin_amdgcn_mfma_f32_16x16x32_bf16(wah[q], yh, accA, 0, 0, 0);
      accA = __builtin_amdgcn_mfma_f32_16x16x32_bf16(wal[q], yh, accA, 0, 0, 0);
      accG = __builtin_amdgcn_mfma_f32_16x16x32_bf16(wgh[q], yh, accG, 0, 0, 0);
      accG = __builtin_amdgcn_mfma_f32_16x16x32_bf16(wgl[q], yh, accG, 0, 0, 0);
    }
    float s1 = 0.f, s2 = 0.f;
#pragma unroll
    for (int r = 0; r < 4; ++r) {
      const int ca = 16 * w + 4 * g4 + r;
      const float a = accA[r] + ob[ca];
      const float g = accG[r] + ob[H_ + ca];
      const float z = a / (1.f + expf(-g));
      const float xv = bf2f(xbuf[bbase + (size_t)ca * Lcur + l0 + ll]);
      wv[lt][r] = z + xv;
      s1 += wv[lt][r];
      s2 += wv[lt][r] * wv[lt][r];
    }
    s1 += __shfl_xor(s1, 16);
    s2 += __shfl_xor(s2, 16);
    s1 += __shfl_xor(s1, 32);
    s2 += __shfl_xor(s2, 32);
    if (g4 == 0) {
      red[w][ll][0] = s1;
      red[w][ll][1] = s2;
    }
  }
  __syncthreads();
#pragma unroll
  for (int lt = 0; lt < LT; ++lt) {
    const int ll = lt * 16 + c15;
    float t1 = 0.f, t2 = 0.f;
#pragma unroll
    for (int q = 0; q < 4; ++q) {
      t1 += red[q][ll][0];
      t2 += red[q][ll][1];
    }
    const float mean = t1 * (1.f / 64.f);
    const float var = t2 * (1.f / 64.f) - mean * mean;
    const float rstd = rsqrtf(var + 1e-5f);
#pragma unroll
    for (int r = 0; r < 4; ++r) {
      const int ca = 16 * w + 4 * g4 + r;
      const float val = (wv[lt][r] - mean) * rstd * lng[ca] + lnb[ca];
      const size_t pos = bbase + (size_t)ca * Lcur + l0 + ll;
      if (F32OUT)
        obuf32[pos] = val;
      else
        obuf16[pos] = f2bf(val);
    }
  }
}

}  // namespace

// ---------------------------------------------------------------------------
extern "C" void kernel_launch(void* const* d_in, const int* in_sizes, int n_in,
                              void* d_out, int out_size, void* d_ws, size_t ws_size,
                              hipStream_t stream) {
  const float* x       = (const float*)d_in[0];
  const float* enc_W   = (const float*)d_in[1];
  const float* enc_b   = (const float*)d_in[2];
  const float* ln_g    = (const float*)d_in[3];
  const float* ln_b    = (const float*)d_in[4];
  const float* s4_D    = (const float*)d_in[5];
  const float* s4_ldt  = (const float*)d_in[6];
  const float* s4_C    = (const float*)d_in[7];
  const float* s4_logA = (const float*)d_in[8];
  const float* s4_Aim  = (const float*)d_in[9];
  const float* out_W   = (const float*)d_in[10];
  const float* out_b   = (const float*)d_in[11];
  const float* cd1_W   = (const float*)d_in[12];
  const float* cd1_b   = (const float*)d_in[13];
  const float* cd2_W   = (const float*)d_in[14];
  const float* cd2_b   = (const float*)d_in[15];
  const float* up_W    = (const float*)d_in[16];
  const float* up_b    = (const float*)d_in[17];
  const float* up1_W   = (const float*)d_in[18];
  float* outp = (float*)d_out;

  // ---- workspace arena ----
  unsigned short* TtG = (unsigned short*)d_ws;
  const size_t ttg_shorts = (size_t)64 * NL_ * 70 * 512;      // 18.35M
  const size_t nWsz = (size_t)NM_ * NL_ * 2 * H_ * H_;        // 1.57M
  unsigned short* oWhi = TtG + ttg_shorts;
  unsigned short* oWlo = oWhi + nWsz;
  unsigned short* eWhi = oWlo + nWsz;
  unsigned short* eWlo = eWhi + 3 * 4096;
  unsigned short* c1hi = eWlo + 3 * 4096;
  unsigned short* c1lo = c1hi + 3 * 4096;
  unsigned short* c2hi = c1lo + 3 * 4096;
  unsigned short* c2lo = c2hi + 2 * 4096;
  unsigned short* uphi = c2lo + 2 * 4096;
  unsigned short* uplo = uphi + 3 * 4096;
  unsigned short* u1hi = uplo + 3 * 4096;
  unsigned short* u1lo = u1hi + 3 * 4096;
  float* slotA = (float*)(u1lo + 3 * 4096);            // B*H*L0 floats
  float* slotB = slotA + (size_t)B_ * H_ * L0_;        // B*H*L0 floats
  const size_t BHL2 = (size_t)B_ * H_ * L2_;           // unit (L1=2u, L0=4u)

  // lifetime map (stream-serial; verified step-by-step):
  //  phase 0: enc1=A[0,2u) f32, enc2=A[2u,3u) f32
  //  model 0: st0=B[0,0.5u) bf16, ybf0=B[1u,1.5u) bf16, m0out=A[3u,4u) f32
  //  convT#1: reads enc2,m0out,enc1 (A) -> dec21=B[0,2u) f32 (st0/ybf0 dead)
  //  model 1: st1=B[2u,3u) bf16, ybf1=B[3u,4u) bf16, m1out=A[0,2u) f32
  //  convT#2: reads m1out (A), x -> dec32=B[0,4u) f32 (dec21/st1/ybf1 dead)
  //  model 2: st2=A[0,2u) bf16, ybf2=A[2u,4u) bf16 (m1out dead), out=d_out
  float* enc1  = slotA;
  float* enc2  = slotA + 2 * BHL2;
  unsigned short* st0 = (unsigned short*)slotB;
  unsigned short* ybf0 = (unsigned short*)(slotB + BHL2);
  float* m0out = slotA + 3 * BHL2;
  float* dec21 = slotB;
  unsigned short* st1 = (unsigned short*)(slotB + 2 * BHL2);
  unsigned short* ybf1 = (unsigned short*)(slotB + 3 * BHL2);
  float* m1out = slotA;
  float* dec32 = slotB;
  unsigned short* st2 = (unsigned short*)slotA;
  unsigned short* ybf2 = (unsigned short*)(slotA + 2 * BHL2);

  auto tt_layer = [&](int m, int i) -> const unsigned short* {
    const size_t NTm = (m == 0) ? 10 : (m == 1) ? 20 : 40;
    const size_t base = (m == 0) ? 0 : (m == 1) ? (size_t)64 * NL_ * 10
                                                : (size_t)64 * NL_ * 30;
    return TtG + (base + (size_t)i * 64 * NTm) * 512;
  };

  k_compute_K_tt<<<NM_ * NL_ * H_, 256, 0, stream>>>(s4_ldt, s4_C, s4_logA, s4_Aim, TtG);
  k_pack_all<<<992, 256, 0, stream>>>(out_W, enc_W, cd1_W, cd2_W, up_W, up1_W,
                                      oWhi, oWlo, eWhi, eWlo, c1hi, c1lo,
                                      c2hi, c2lo, uphi, uplo, u1hi, u1lo);

  // enc1 = conv_d1(x), enc2 = conv_d2(enc1)
  k_down_mfma<3, 1><<<B_ * (L1_ / 32), 256, 0, stream>>>(c1hi, c1lo, cd1_b, x, enc1,
                                                         L0_, L1_);
  k_down_mfma<2, 0><<<B_ * (L2_ / 32), 256, 0, stream>>>(c2hi, c2lo, cd2_b, enc1, enc2,
                                                         L1_, L2_);

  auto run_model = [&](int m, const float* input, unsigned short* state,
                       unsigned short* ybf, int Lm, float* fout) {
    k_enc_mfma<<<B_ * (Lm / 32), 256, 0, stream>>>(eWhi + m * 4096, eWlo + m * 4096,
                                                   enc_b + (size_t)m * H_, input, state, Lm);
    for (int i = 0; i < NL_; ++i) {
      const unsigned short* Tl = tt_layer(m, i);
      const float* Dl = s4_D + ((size_t)m * NL_ + i) * H_;
      const int cgrid = (B_ / 32) * H_;
      if (Lm == L2_)
        k_conv_gelu_mfma<L2_><<<cgrid, 256, 0, stream>>>(state, Tl, Dl, ybf);
      else if (Lm == L1_)
        k_conv_gelu_mfma<L1_><<<cgrid, 256, 0, stream>>>(state, Tl, Dl, ybf);
      else
        k_conv_gelu_mfma<L0_><<<cgrid, 256, 0, stream>>>(state, Tl, Dl, ybf);
      const bool last = (i == NL_ - 1);
      const size_t wbase = ((size_t)m * NL_ + i) * 2 * H_ * H_;
      const float* obp = out_b + ((size_t)m * NL_ + i) * 2 * H_;
      const float* lgp = ln_g + ((size_t)m * NL_ + i) * H_;
      const float* lbp = ln_b + ((size_t)m * NL_ + i) * H_;
      if (Lm == L2_) {
        if (last)
          k_glu_ln_mfma2<2, true><<<B_ * (Lm / 32), 256, 0, stream>>>(
              oWhi + wbase, oWlo + wbase, obp, lgp, lbp, ybf, state, nullptr, fout, Lm);
        else
          k_glu_ln_mfma2<2, false><<<B_ * (Lm / 32), 256, 0, stream>>>(
              oWhi + wbase, oWlo + wbase, obp, lgp, lbp, ybf, state, state, nullptr, Lm);
      } else {
        if (last)
          k_glu_ln_mfma2<4, true><<<B_ * (Lm / 64), 256, 0, stream>>>(
              oWhi + wbase, oWlo + wbase, obp, lgp, lbp, ybf, state, nullptr, fout, Lm);
        else
          k_glu_ln_mfma2<4, false><<<B_ * (Lm / 64), 256, 0, stream>>>(
              oWhi + wbase, oWlo + wbase, obp, lgp, lbp, ybf, state, state, nullptr, Lm);
      }
    }
  };

  // model 0 on enc2 (L=160) -> m0out (f32)
  run_model(0, enc2, st0, ybf0, L2_, m0out);
  // dec21 = convT(enc2 + m0out, up_W) + up_b + enc1
  k_convT_mfma<<<B_ * (L2_ / 32), 256, 0, stream>>>(uphi, uplo, up_b, enc1, enc2, m0out,
                                                    dec21, L2_, 1);
  // model 1 on dec21 (L=320) -> m1out (f32)
  run_model(1, dec21, st1, ybf1, L1_, m1out);
  // dec32 = convT(m1out, up1_W) + enc0
  k_convT_mfma<<<B_ * (L1_ / 32), 256, 0, stream>>>(u1hi, u1lo, up_b, x, m1out, nullptr,
                                                    dec32, L1_, 0);
  // model 2 on dec32 (L=640) -> d_out (f32)
  run_model(2, dec32, st2, ybf2, L0_, outp);
}